// Round 9
// baseline (1294.014 us; speedup 1.0000x reference)
//
#include <hip/hip_runtime.h>
#include <hip/hip_bf16.h>

#define NATOMS 10000
#define NEDGES 320000
#define H 128
#define NRBF 50
#define NELEM (NATOMS * H)
#define NT 8192

typedef unsigned short u16;
typedef unsigned int u32;

__device__ __forceinline__ float bfu(u16 u) { return __uint_as_float(((u32)u) << 16); }
__device__ __forceinline__ float ldf(const void* p, int i, int bf) {
    return bf ? bfu(((const u16*)p)[i]) : ((const float*)p)[i];
}
__device__ __forceinline__ float silu_f(float v) { return v / (1.f + __expf(-v)); }
__device__ __forceinline__ float cutoff_f(float w) {
    float c = 0.5f * (__cosf(w * 0.62831853072f) + 1.f);
    return (w < 5.f) ? c : 0.f;
}
__device__ __forceinline__ float tlerp(const float* __restrict__ T, float w, int f) {
    float u = w * ((float)(NT - 1) / 5.0f);
    int ix = (int)u; ix = min(ix, NT - 2);
    float fr = u - (float)ix;
    float ta = T[ix * H + f], tb = T[ix * H + H + f];
    return fmaf(fr, tb - ta, ta);
}

// ---- dtype detect: means[49]==1.0 by construction.
__global__ void k_detect(const void* means, int* flag) {
    if (threadIdx.x == 0) {
        u32 w = ((const u32*)means)[24];
        *flag = ((w >> 16) == 0x3F80u) ? 1 : 0;
    }
}

__global__ __launch_bounds__(256) void k_embed(const int* __restrict__ z, const void* emb,
                                               float* __restrict__ x0, const int* flagp) {
    int bf = *flagp;
    int i = blockIdx.x * 256 + threadIdx.x;
    if (i < NELEM) {
        int n = i >> 7, f = i & 127;
        x0[i] = ldf(emb, z[n] * H + f, bf);
    }
}

__global__ __launch_bounds__(256) void k_store(const float* __restrict__ x, void* out,
                                               const int* flagp) {
    int bf = *flagp;
    int i = blockIdx.x * 256 + threadIdx.x;
    if (i < NELEM) {
        float v = x[i];
        if (bf) {
            u32 u = __float_as_uint(v);
            ((u16*)out)[i] = (u16)((u + 0x7FFFu + ((u >> 16) & 1u)) >> 16);
        } else {
            ((float*)out)[i] = v;
        }
    }
}

// ---- node GEMM, K=128 (proven rounds 3-8, unchanged) ----
__global__ __launch_bounds__(1024) void k_node_gemm(const float* __restrict__ in,
                                                    const void* W, int woff, int wstride,
                                                    const void* bias, float* __restrict__ out,
                                                    int mode, const int* flagp) {
    __shared__ __align__(16) float sW[H * 132];
    __shared__ __align__(16) float sIn[16][132];
    __shared__ float sB[H];
    int tid = threadIdx.x;
    int bf = *flagp;
    for (int i = tid; i < H * H; i += 1024) {
        int f2 = i >> 7, k = i & 127;
        sW[f2 * 132 + k] = ldf(W, woff + f2 * wstride + k, bf);
    }
    if (tid < H) sB[tid] = bias ? ldf(bias, tid, bf) : 0.f;
    __syncthreads();
    int g = tid >> 7, f = tid & 127;
    for (int base = blockIdx.x * 16; base < NATOMS; base += gridDim.x * 16) {
        int n0 = base + 2 * g, n1 = n0 + 1;
        sIn[2 * g][f] = in[n0 * H + f];
        sIn[2 * g + 1][f] = in[n1 * H + f];
        __syncthreads();
        float a0 = 0.f, a1 = 0.f;
        #pragma unroll
        for (int k = 0; k < H; k += 4) {
            float4 w4 = *(const float4*)&sW[f * 132 + k];
            float4 i0 = *(const float4*)&sIn[2 * g][k];
            float4 i1 = *(const float4*)&sIn[2 * g + 1][k];
            a0 = fmaf(w4.x, i0.x, a0); a0 = fmaf(w4.y, i0.y, a0);
            a0 = fmaf(w4.z, i0.z, a0); a0 = fmaf(w4.w, i0.w, a0);
            a1 = fmaf(w4.x, i1.x, a1); a1 = fmaf(w4.y, i1.y, a1);
            a1 = fmaf(w4.z, i1.z, a1); a1 = fmaf(w4.w, i1.w, a1);
        }
        float v0 = a0 + sB[f], v1 = a1 + sB[f];
        if (mode == 1) { v0 = silu_f(v0); v1 = silu_f(v1); }
        if (mode == 2) { out[n0 * H + f] += v0; out[n1 * H + f] += v1; }
        else           { out[n0 * H + f] = v0;  out[n1 * H + f] = v1; }
        __syncthreads();
    }
}

// ---- table GEMM: T[i,:] <- (T[i,:] @ w1.T + b1) * C(w_i), in-place (proven r8) ----
__global__ __launch_bounds__(1024) void k_table_gemm(float* __restrict__ T,
                                                     const void* W, int woff,
                                                     const void* bias, int boff,
                                                     const int* flagp) {
    __shared__ __align__(16) float sW[H * 132];
    __shared__ __align__(16) float sIn[16][132];
    __shared__ float sB[H];
    int tid = threadIdx.x;
    int bf = *flagp;
    for (int i = tid; i < H * H; i += 1024) {
        int f2 = i >> 7, k = i & 127;
        sW[f2 * 132 + k] = ldf(W, woff + f2 * H + k, bf);
    }
    if (tid < H) sB[tid] = ldf(bias, boff + tid, bf);
    __syncthreads();
    int g = tid >> 7, f = tid & 127;
    for (int base = blockIdx.x * 16; base < NT; base += gridDim.x * 16) {
        int n0 = base + 2 * g, n1 = n0 + 1;       // NT % 16 == 0
        sIn[2 * g][f] = T[n0 * H + f];
        sIn[2 * g + 1][f] = T[n1 * H + f];
        __syncthreads();
        float a0 = 0.f, a1 = 0.f;
        #pragma unroll
        for (int k = 0; k < H; k += 4) {
            float4 w4 = *(const float4*)&sW[f * 132 + k];
            float4 i0 = *(const float4*)&sIn[2 * g][k];
            float4 i1 = *(const float4*)&sIn[2 * g + 1][k];
            a0 = fmaf(w4.x, i0.x, a0); a0 = fmaf(w4.y, i0.y, a0);
            a0 = fmaf(w4.z, i0.z, a0); a0 = fmaf(w4.w, i0.w, a0);
            a1 = fmaf(w4.x, i1.x, a1); a1 = fmaf(w4.y, i1.y, a1);
            a1 = fmaf(w4.z, i1.z, a1); a1 = fmaf(w4.w, i1.w, a1);
        }
        float w0v = (float)n0 * (5.0f / (NT - 1));
        float w1v = (float)n1 * (5.0f / (NT - 1));
        T[n0 * H + f] = (a0 + sB[f]) * cutoff_f(w0v);
        T[n1 * H + f] = (a1 + sB[f]) * cutoff_f(w1v);
        __syncthreads();
    }
}

// ---- w-tables (proven)
// mode 1: T[i,f]=silu(C*g_f+b_f)   mode 0: T[i,f]=(C*g_f+b_f)*C
__global__ __launch_bounds__(256) void k_build_table(const void* means, const void* betas,
                                                     const void* W, int woff,
                                                     const void* B, int boff,
                                                     float* __restrict__ T, int mode,
                                                     const int* flagp) {
    __shared__ float sW[H * 52];
    __shared__ float sM[NRBF], sBe[NRBF];
    int tid = threadIdx.x;
    int bf = *flagp;
    for (int i = tid; i < H * NRBF; i += 256) {
        int f2 = i / NRBF, k = i - f2 * NRBF;
        sW[f2 * 52 + k] = ldf(W, woff + i, bf);
    }
    if (tid < NRBF) { sM[tid] = ldf(means, tid, bf); sBe[tid] = ldf(betas, tid, bf); }
    __syncthreads();
    int idx = blockIdx.x * 256 + tid;
    int i = idx >> 7, f = idx & 127;
    float w = (float)i * (5.0f / (NT - 1));
    float x = expf(-w);
    float c = 0.5f * (cosf(w * 0.62831853071795864f) + 1.f);
    if (!(w < 5.f)) c = 0.f;
    float g = 0.f;
    for (int k = 0; k < NRBF; ++k) {
        float t = x - sM[k];
        g += sW[f * 52 + k] * expf(-sBe[k] * t * t);
    }
    float b = ldf(B, boff + f, bf);
    float pre = c * g + b;
    T[i * H + f] = (mode == 1) ? silu_f(pre) : pre * c;
}

// ---- counting sort by src (proven rounds 4/5/7) ----
__global__ __launch_bounds__(256) void k_hist(const int* __restrict__ src, int* __restrict__ deg) {
    int e = blockIdx.x * 256 + threadIdx.x;
    if (e < NEDGES) atomicAdd(&deg[src[e]], 1);
}

__global__ __launch_bounds__(1024) void k_scan(const int* __restrict__ deg, int* __restrict__ rs) {
    __shared__ int buf[1024];
    __shared__ int carry;
    int tid = threadIdx.x;
    if (tid == 0) carry = 0;
    __syncthreads();
    for (int c = 0; c < 10; ++c) {
        int i = c * 1024 + tid;
        int v = (i < NATOMS) ? deg[i] : 0;
        buf[tid] = v;
        __syncthreads();
        for (int off = 1; off < 1024; off <<= 1) {
            int t = (tid >= off) ? buf[tid - off] : 0;
            __syncthreads();
            buf[tid] += t;
            __syncthreads();
        }
        int base = carry;
        if (i < NATOMS) rs[i] = base + buf[tid] - v;
        __syncthreads();
        if (tid == 0) carry = base + buf[1023];
        __syncthreads();
    }
}

__global__ __launch_bounds__(256) void k_scatter_perm(const int* __restrict__ src,
                                                      const int* __restrict__ dst,
                                                      const void* ew,
                                                      const int* __restrict__ rs,
                                                      int* __restrict__ cnt,
                                                      int* __restrict__ srcs,
                                                      int* __restrict__ dsts,
                                                      float* __restrict__ ews,
                                                      const int* flagp) {
    int e = blockIdx.x * 256 + threadIdx.x;
    if (e < NEDGES) {
        int s = src[e];
        int p = rs[s] + atomicAdd(&cnt[s], 1);
        srcs[p] = s;
        dsts[p] = dst[e];
        ews[p] = ldf(ew, e, *flagp);
    }
}

// ---- edge apply over SORTED edges: run-accumulate, one atomic per src-run.
// Exact k_ne_edge4 shape (proven non-pathological): 256 thr, no LDS, scalars only.
__global__ __launch_bounds__(256) void k_edge_apply_sorted(const int* __restrict__ srcs,
                                                           const int* __restrict__ dsts,
                                                           const float* __restrict__ ews,
                                                           const float* __restrict__ T,
                                                           const float* __restrict__ vin,
                                                           float* __restrict__ acc,
                                                           int mask_self) {
    int tid = threadIdx.x;
    int g = tid >> 7, f = tid & 127;
    int gid = blockIdx.x * 2 + g;          // 1024 blocks -> 2048 groups x 160 edges
    int r0 = gid * 160;
    int rEnd = min(r0 + 160, NEDGES);
    int cur = -1; float racc = 0.f;
    for (int e = r0; e < rEnd; ++e) {      // bounds uniform per group
        int s = srcs[e], d = dsts[e];
        if (mask_self && s == d) continue;
        float Wv = tlerp(T, ews[e], f);
        if (s != cur) {
            if (cur >= 0) atomicAdd(&acc[cur * H + f], racc);
            cur = s; racc = 0.f;
        }
        racc = fmaf(Wv, vin[d * H + f], racc);
    }
    if (cur >= 0) atomicAdd(&acc[cur * H + f], racc);
}

extern "C" void kernel_launch(void* const* d_in, const int* in_sizes, int n_in,
                              void* d_out, int out_size, void* d_ws, size_t ws_size,
                              hipStream_t stream) {
    const int* z  = (const int*)d_in[0];
    const int* ei = (const int*)d_in[1];
    const void* ew        = d_in[2];
    const void* emb       = d_in[3];
    const void* means     = d_in[4];
    const void* betas     = d_in[5];
    const void* ne_proj_w = d_in[6];
    const void* ne_proj_b = d_in[7];
    const void* ne_comb_w = d_in[8];
    const void* ne_comb_b = d_in[9];
    const void* mlp_w0    = d_in[10];
    const void* mlp_b0    = d_in[11];
    const void* mlp_w1    = d_in[12];
    const void* mlp_b1    = d_in[13];
    const void* lin1_w    = d_in[14];
    const void* lin2_w    = d_in[15];
    const void* lin2_b    = d_in[16];
    const void* lin_w     = d_in[17];
    const void* lin_b     = d_in[18];

    const int* srcp = ei;
    const int* dstp = ei + NEDGES;

    // layout: 23.52 MB total (proven to fit, round 4/5/7 fast path ran)
    float* buf0 = (float*)d_ws;            // x0, then h
    float* buf1 = buf0 + NELEM;            // scatter accumulator
    float* x    = buf1 + NELEM;            // persistent fp32 node state
    int*   flag = (int*)(x + NELEM);
    int*   deg  = flag + 16;
    int*   cnt  = deg + 10240;
    int*   rs   = cnt + 10240;
    int*   srcs = rs + 10240;
    int*   dsts = srcs + NEDGES;
    float* ews  = (float*)(dsts + NEDGES);
    float* T    = ews + NEDGES;            // 8192 x 128 fp32 table (4.19 MB)

    const int gElem = (NELEM + 255) / 256;
    const int gEdge = (NEDGES + 255) / 256;

    k_detect<<<1, 64, 0, stream>>>(means, flag);
    k_embed<<<gElem, 256, 0, stream>>>(z, emb, buf0, flag);

    // counting sort by src (once, reused by all 4 edge passes)
    hipMemsetAsync(deg, 0, 2 * 10240 * sizeof(int), stream);
    k_hist<<<gEdge, 256, 0, stream>>>(srcp, deg);
    k_scan<<<1, 1024, 0, stream>>>(deg, rs);
    k_scatter_perm<<<gEdge, 256, 0, stream>>>(srcp, dstp, ew, rs, cnt,
                                              srcs, dsts, ews, flag);

    // NeighborEmbedding: fully-baked table + sorted run-accumulate apply
    hipMemsetAsync(buf1, 0, (size_t)NELEM * sizeof(float), stream);
    k_build_table<<<NT * H / 256, 256, 0, stream>>>(means, betas, ne_proj_w, 0,
                                                    ne_proj_b, 0, T, 0, flag);
    k_edge_apply_sorted<<<1024, 256, 0, stream>>>(srcs, dsts, ews, T, buf0, buf1, 1);
    k_node_gemm<<<512, 1024, 0, stream>>>(buf0, ne_comb_w, 0,   256, ne_comb_b, x, 0, flag);
    k_node_gemm<<<512, 1024, 0, stream>>>(buf1, ne_comb_w, 128, 256, nullptr,   x, 2, flag);

    for (int L = 0; L < 3; ++L) {
        // h = x @ l1w.T
        k_node_gemm<<<512, 1024, 0, stream>>>(x, lin1_w, L * H * H, 128, nullptr, buf0, 0, flag);
        hipMemsetAsync(buf1, 0, (size_t)NELEM * sizeof(float), stream);
        // full filter table: silu-row table, then (T @ w1.T + b1)*C in-place
        k_build_table<<<NT * H / 256, 256, 0, stream>>>(means, betas, mlp_w0, L * H * NRBF,
                                                        mlp_b0, L * H, T, 1, flag);
        k_table_gemm<<<512, 1024, 0, stream>>>(T, mlp_w1, L * H * H, mlp_b1, L * H, flag);
        // edge pass: a[src] += T(w) ⊙ h[dst], sorted + run-accumulated
        k_edge_apply_sorted<<<1024, 256, 0, stream>>>(srcs, dsts, ews, T, buf0, buf1, 0);
        // h = silu(a @ l2w.T + b2);  x += h @ lw.T + lb
        k_node_gemm<<<512, 1024, 0, stream>>>(buf1, lin2_w, L * H * H, 128, lin2_b, buf0, 1, flag);
        k_node_gemm<<<512, 1024, 0, stream>>>(buf0, lin_w,  L * H * H, 128, lin_b,  x,    2, flag);
    }

    k_store<<<gElem, 256, 0, stream>>>(x, d_out, flag);
}

// Round 10
// 901.587 us; speedup vs baseline: 1.4353x; 1.4353x over previous
//
#include <hip/hip_runtime.h>
#include <hip/hip_bf16.h>

#define NATOMS 10000
#define NEDGES 320000
#define H 128
#define NRBF 50
#define NELEM (NATOMS * H)
#define NT 8192

typedef unsigned short u16;
typedef unsigned int u32;

__device__ __forceinline__ float bfu(u16 u) { return __uint_as_float(((u32)u) << 16); }
__device__ __forceinline__ float ldf(const void* p, int i, int bf) {
    return bf ? bfu(((const u16*)p)[i]) : ((const float*)p)[i];
}
__device__ __forceinline__ float silu_f(float v) { return v / (1.f + __expf(-v)); }
__device__ __forceinline__ float cutoff_f(float w) {
    float c = 0.5f * (__cosf(w * 0.62831853072f) + 1.f);
    return (w < 5.f) ? c : 0.f;
}

// ---- dtype detect: means[49]==1.0 by construction.
__global__ void k_detect(const void* means, int* flag) {
    if (threadIdx.x == 0) {
        u32 w = ((const u32*)means)[24];
        *flag = ((w >> 16) == 0x3F80u) ? 1 : 0;
    }
}

__global__ __launch_bounds__(256) void k_embed(const int* __restrict__ z, const void* emb,
                                               float* __restrict__ x0, const int* flagp) {
    int bf = *flagp;
    int i = blockIdx.x * 256 + threadIdx.x;
    if (i < NELEM) {
        int n = i >> 7, f = i & 127;
        x0[i] = ldf(emb, z[n] * H + f, bf);
    }
}

__global__ __launch_bounds__(256) void k_store(const float* __restrict__ x, void* out,
                                               const int* flagp) {
    int bf = *flagp;
    int i = blockIdx.x * 256 + threadIdx.x;
    if (i < NELEM) {
        float v = x[i];
        if (bf) {
            u32 u = __float_as_uint(v);
            ((u16*)out)[i] = (u16)((u + 0x7FFFu + ((u >> 16) & 1u)) >> 16);
        } else {
            ((float*)out)[i] = v;
        }
    }
}

// ---- staging helper: W row-major (wstride per row), into sW padded 132.
// Vectorized: bf16 as u32 pairs, fp32 as float2. All call sites have
// (woff + f2*wstride) even.
__device__ __forceinline__ void stage_weights(const void* W, int woff, int wstride,
                                              float* sW, int tid, int nthr, int bf) {
    if (bf) {
        const u32* W32 = (const u32*)W;
        for (int i = tid; i < (H * H) / 2; i += nthr) {
            int f2 = i >> 6, kk = i & 63;
            u32 wp = W32[((woff + f2 * wstride) >> 1) + kk];
            sW[f2 * 132 + 2 * kk]     = bfu((u16)(wp & 0xffffu));
            sW[f2 * 132 + 2 * kk + 1] = bfu((u16)(wp >> 16));
        }
    } else {
        const float2* Wf = (const float2*)W;
        for (int i = tid; i < (H * H) / 2; i += nthr) {
            int f2 = i >> 6, kk = i & 63;
            float2 v = Wf[((woff + f2 * wstride) >> 1) + kk];
            sW[f2 * 132 + 2 * kk]     = v.x;
            sW[f2 * 132 + 2 * kk + 1] = v.y;
        }
    }
}

// ---- node GEMM, K=128 (proven shape; staging vectorized) ----
__global__ __launch_bounds__(1024) void k_node_gemm(const float* __restrict__ in,
                                                    const void* W, int woff, int wstride,
                                                    const void* bias, float* __restrict__ out,
                                                    int mode, const int* flagp) {
    __shared__ __align__(16) float sW[H * 132];
    __shared__ __align__(16) float sIn[16][132];
    __shared__ float sB[H];
    int tid = threadIdx.x;
    int bf = *flagp;
    stage_weights(W, woff, wstride, sW, tid, 1024, bf);
    if (tid < H) sB[tid] = bias ? ldf(bias, tid, bf) : 0.f;
    __syncthreads();
    int g = tid >> 7, f = tid & 127;
    for (int base = blockIdx.x * 16; base < NATOMS; base += gridDim.x * 16) {
        int n0 = base + 2 * g, n1 = n0 + 1;
        sIn[2 * g][f] = in[n0 * H + f];
        sIn[2 * g + 1][f] = in[n1 * H + f];
        __syncthreads();
        float a0 = 0.f, a1 = 0.f;
        #pragma unroll
        for (int k = 0; k < H; k += 4) {
            float4 w4 = *(const float4*)&sW[f * 132 + k];
            float4 i0 = *(const float4*)&sIn[2 * g][k];
            float4 i1 = *(const float4*)&sIn[2 * g + 1][k];
            a0 = fmaf(w4.x, i0.x, a0); a0 = fmaf(w4.y, i0.y, a0);
            a0 = fmaf(w4.z, i0.z, a0); a0 = fmaf(w4.w, i0.w, a0);
            a1 = fmaf(w4.x, i1.x, a1); a1 = fmaf(w4.y, i1.y, a1);
            a1 = fmaf(w4.z, i1.z, a1); a1 = fmaf(w4.w, i1.w, a1);
        }
        float v0 = a0 + sB[f], v1 = a1 + sB[f];
        if (mode == 1) { v0 = silu_f(v0); v1 = silu_f(v1); }
        if (mode == 2) { out[n0 * H + f] += v0; out[n1 * H + f] += v1; }
        else           { out[n0 * H + f] = v0;  out[n1 * H + f] = v1; }
        __syncthreads();
    }
}

// ---- table GEMM: T[i,:] <- (T[i,:] @ w1.T + b1) * C(w_i), in-place (proven r8) ----
__global__ __launch_bounds__(1024) void k_table_gemm(float* __restrict__ T,
                                                     const void* W, int woff,
                                                     const void* bias, int boff,
                                                     const int* flagp) {
    __shared__ __align__(16) float sW[H * 132];
    __shared__ __align__(16) float sIn[16][132];
    __shared__ float sB[H];
    int tid = threadIdx.x;
    int bf = *flagp;
    stage_weights(W, woff, H, sW, tid, 1024, bf);
    if (tid < H) sB[tid] = ldf(bias, boff + tid, bf);
    __syncthreads();
    int g = tid >> 7, f = tid & 127;
    for (int base = blockIdx.x * 16; base < NT; base += gridDim.x * 16) {
        int n0 = base + 2 * g, n1 = n0 + 1;       // NT % 16 == 0
        sIn[2 * g][f] = T[n0 * H + f];
        sIn[2 * g + 1][f] = T[n1 * H + f];
        __syncthreads();
        float a0 = 0.f, a1 = 0.f;
        #pragma unroll
        for (int k = 0; k < H; k += 4) {
            float4 w4 = *(const float4*)&sW[f * 132 + k];
            float4 i0 = *(const float4*)&sIn[2 * g][k];
            float4 i1 = *(const float4*)&sIn[2 * g + 1][k];
            a0 = fmaf(w4.x, i0.x, a0); a0 = fmaf(w4.y, i0.y, a0);
            a0 = fmaf(w4.z, i0.z, a0); a0 = fmaf(w4.w, i0.w, a0);
            a1 = fmaf(w4.x, i1.x, a1); a1 = fmaf(w4.y, i1.y, a1);
            a1 = fmaf(w4.z, i1.z, a1); a1 = fmaf(w4.w, i1.w, a1);
        }
        float w0v = (float)n0 * (5.0f / (NT - 1));
        float w1v = (float)n1 * (5.0f / (NT - 1));
        T[n0 * H + f] = (a0 + sB[f]) * cutoff_f(w0v);
        T[n1 * H + f] = (a1 + sB[f]) * cutoff_f(w1v);
        __syncthreads();
    }
}

// ---- w-tables (proven)
// mode 1: T[i,f]=silu(C*g_f+b_f)   mode 0: T[i,f]=(C*g_f+b_f)*C
__global__ __launch_bounds__(256) void k_build_table(const void* means, const void* betas,
                                                     const void* W, int woff,
                                                     const void* B, int boff,
                                                     float* __restrict__ T, int mode,
                                                     const int* flagp) {
    __shared__ float sW[H * 52];
    __shared__ float sM[NRBF], sBe[NRBF];
    int tid = threadIdx.x;
    int bf = *flagp;
    for (int i = tid; i < H * NRBF; i += 256) {
        int f2 = i / NRBF, k = i - f2 * NRBF;
        sW[f2 * 52 + k] = ldf(W, woff + i, bf);
    }
    if (tid < NRBF) { sM[tid] = ldf(means, tid, bf); sBe[tid] = ldf(betas, tid, bf); }
    __syncthreads();
    int idx = blockIdx.x * 256 + tid;
    int i = idx >> 7, f = idx & 127;
    float w = (float)i * (5.0f / (NT - 1));
    float x = expf(-w);
    float c = 0.5f * (cosf(w * 0.62831853071795864f) + 1.f);
    if (!(w < 5.f)) c = 0.f;
    float g = 0.f;
    for (int k = 0; k < NRBF; ++k) {
        float t = x - sM[k];
        g += sW[f * 52 + k] * expf(-sBe[k] * t * t);
    }
    float b = ldf(B, boff + f, bf);
    float pre = c * g + b;
    T[i * H + f] = (mode == 1) ? silu_f(pre) : pre * c;
}

// ---- counting sort by src (proven rounds 4/5/7/9) ----
__global__ __launch_bounds__(256) void k_hist(const int* __restrict__ src, int* __restrict__ deg) {
    int e = blockIdx.x * 256 + threadIdx.x;
    if (e < NEDGES) atomicAdd(&deg[src[e]], 1);
}

__global__ __launch_bounds__(1024) void k_scan(const int* __restrict__ deg, int* __restrict__ rs) {
    __shared__ int buf[1024];
    __shared__ int carry;
    int tid = threadIdx.x;
    if (tid == 0) carry = 0;
    __syncthreads();
    for (int c = 0; c < 10; ++c) {
        int i = c * 1024 + tid;
        int v = (i < NATOMS) ? deg[i] : 0;
        buf[tid] = v;
        __syncthreads();
        for (int off = 1; off < 1024; off <<= 1) {
            int t = (tid >= off) ? buf[tid - off] : 0;
            __syncthreads();
            buf[tid] += t;
            __syncthreads();
        }
        int base = carry;
        if (i < NATOMS) rs[i] = base + buf[tid] - v;
        __syncthreads();
        if (tid == 0) carry = base + buf[1023];
        __syncthreads();
    }
}

__global__ __launch_bounds__(256) void k_scatter_perm(const int* __restrict__ src,
                                                      const int* __restrict__ dst,
                                                      const void* ew,
                                                      const int* __restrict__ rs,
                                                      int* __restrict__ cnt,
                                                      int* __restrict__ srcs,
                                                      int* __restrict__ dsts,
                                                      float* __restrict__ ews,
                                                      const int* flagp) {
    int e = blockIdx.x * 256 + threadIdx.x;
    if (e < NEDGES) {
        int s = src[e];
        int p = rs[s] + atomicAdd(&cnt[s], 1);
        srcs[p] = s;
        dsts[p] = dst[e];
        ews[p] = ldf(ew, e, *flagp);
    }
}

// ---- edge apply over SORTED edges, one WAVE per edge-row (float2 lanes),
// chunk 40, run-accumulate, one atomic flush per src-run. No LDS, no barriers.
__global__ __launch_bounds__(256) void k_edge_apply2(const int* __restrict__ srcs,
                                                     const int* __restrict__ dsts,
                                                     const float* __restrict__ ews,
                                                     const float* __restrict__ T,
                                                     const float* __restrict__ vin,
                                                     float* __restrict__ acc,
                                                     int mask_self) {
    int tid = threadIdx.x;
    int g = tid >> 6;                 // 4 waves per block
    int lane = tid & 63;
    int gid = blockIdx.x * 4 + g;     // 2000 blocks -> 8000 groups x 40 edges
    int r0 = gid * 40;
    int rEnd = min(r0 + 40, NEDGES);
    const float2* T2 = (const float2*)T;
    const float2* v2 = (const float2*)vin;
    int cur = -1;
    float rx = 0.f, ry = 0.f;
    for (int e = r0; e < rEnd; ++e) {     // e wave-uniform
        int s = srcs[e], d = dsts[e];
        if (mask_self && s == d) continue;
        float u = ews[e] * ((float)(NT - 1) / 5.0f);
        int ix = (int)u; ix = min(ix, NT - 2);
        float fr = u - (float)ix;
        float2 ta = T2[ix * 64 + lane];
        float2 tb = T2[ix * 64 + 64 + lane];
        float wx = fmaf(fr, tb.x - ta.x, ta.x);
        float wy = fmaf(fr, tb.y - ta.y, ta.y);
        if (s != cur) {
            if (cur >= 0) {
                atomicAdd(&acc[cur * H + 2 * lane], rx);
                atomicAdd(&acc[cur * H + 2 * lane + 1], ry);
            }
            cur = s; rx = 0.f; ry = 0.f;
        }
        float2 hv = v2[d * 64 + lane];
        rx = fmaf(wx, hv.x, rx);
        ry = fmaf(wy, hv.y, ry);
    }
    if (cur >= 0) {
        atomicAdd(&acc[cur * H + 2 * lane], rx);
        atomicAdd(&acc[cur * H + 2 * lane + 1], ry);
    }
}

extern "C" void kernel_launch(void* const* d_in, const int* in_sizes, int n_in,
                              void* d_out, int out_size, void* d_ws, size_t ws_size,
                              hipStream_t stream) {
    const int* z  = (const int*)d_in[0];
    const int* ei = (const int*)d_in[1];
    const void* ew        = d_in[2];
    const void* emb       = d_in[3];
    const void* means     = d_in[4];
    const void* betas     = d_in[5];
    const void* ne_proj_w = d_in[6];
    const void* ne_proj_b = d_in[7];
    const void* ne_comb_w = d_in[8];
    const void* ne_comb_b = d_in[9];
    const void* mlp_w0    = d_in[10];
    const void* mlp_b0    = d_in[11];
    const void* mlp_w1    = d_in[12];
    const void* mlp_b1    = d_in[13];
    const void* lin1_w    = d_in[14];
    const void* lin2_w    = d_in[15];
    const void* lin2_b    = d_in[16];
    const void* lin_w     = d_in[17];
    const void* lin_b     = d_in[18];

    const int* srcp = ei;
    const int* dstp = ei + NEDGES;

    // layout: 23.52 MB total (proven to fit)
    float* buf0 = (float*)d_ws;            // x0, then h
    float* buf1 = buf0 + NELEM;            // scatter accumulator
    float* x    = buf1 + NELEM;            // persistent fp32 node state
    int*   flag = (int*)(x + NELEM);
    int*   deg  = flag + 16;
    int*   cnt  = deg + 10240;
    int*   rs   = cnt + 10240;
    int*   srcs = rs + 10240;
    int*   dsts = srcs + NEDGES;
    float* ews  = (float*)(dsts + NEDGES);
    float* T    = ews + NEDGES;            // 8192 x 128 fp32 table (4.19 MB)

    const int gElem = (NELEM + 255) / 256;
    const int gEdge = (NEDGES + 255) / 256;

    k_detect<<<1, 64, 0, stream>>>(means, flag);
    k_embed<<<gElem, 256, 0, stream>>>(z, emb, buf0, flag);

    // counting sort by src (once, reused by all 4 edge passes)
    hipMemsetAsync(deg, 0, 2 * 10240 * sizeof(int), stream);
    k_hist<<<gEdge, 256, 0, stream>>>(srcp, deg);
    k_scan<<<1, 1024, 0, stream>>>(deg, rs);
    k_scatter_perm<<<gEdge, 256, 0, stream>>>(srcp, dstp, ew, rs, cnt,
                                              srcs, dsts, ews, flag);

    // NeighborEmbedding: fully-baked table + sorted run-accumulate apply
    hipMemsetAsync(buf1, 0, (size_t)NELEM * sizeof(float), stream);
    k_build_table<<<NT * H / 256, 256, 0, stream>>>(means, betas, ne_proj_w, 0,
                                                    ne_proj_b, 0, T, 0, flag);
    k_edge_apply2<<<2000, 256, 0, stream>>>(srcs, dsts, ews, T, buf0, buf1, 1);
    k_node_gemm<<<512, 1024, 0, stream>>>(buf0, ne_comb_w, 0,   256, ne_comb_b, x, 0, flag);
    k_node_gemm<<<512, 1024, 0, stream>>>(buf1, ne_comb_w, 128, 256, nullptr,   x, 2, flag);

    for (int L = 0; L < 3; ++L) {
        // h = x @ l1w.T
        k_node_gemm<<<512, 1024, 0, stream>>>(x, lin1_w, L * H * H, 128, nullptr, buf0, 0, flag);
        hipMemsetAsync(buf1, 0, (size_t)NELEM * sizeof(float), stream);
        // full filter table: silu-row table, then (T @ w1.T + b1)*C in-place
        k_build_table<<<NT * H / 256, 256, 0, stream>>>(means, betas, mlp_w0, L * H * NRBF,
                                                        mlp_b0, L * H, T, 1, flag);
        k_table_gemm<<<512, 1024, 0, stream>>>(T, mlp_w1, L * H * H, mlp_b1, L * H, flag);
        // edge pass: a[src] += T(w) ⊙ h[dst], sorted + run-accumulated
        k_edge_apply2<<<2000, 256, 0, stream>>>(srcs, dsts, ews, T, buf0, buf1, 0);
        // h = silu(a @ l2w.T + b2);  x += h @ lw.T + lb
        k_node_gemm<<<512, 1024, 0, stream>>>(buf1, lin2_w, L * H * H, 128, lin2_b, buf0, 1, flag);
        k_node_gemm<<<512, 1024, 0, stream>>>(buf0, lin_w,  L * H * H, 128, lin_b,  x,    2, flag);
    }

    k_store<<<gElem, 256, 0, stream>>>(x, d_out, flag);
}

// Round 12
// 721.176 us; speedup vs baseline: 1.7943x; 1.2502x over previous
//
#include <hip/hip_runtime.h>
#include <hip/hip_bf16.h>

#define NATOMS 10000
#define NEDGES 320000
#define H 128
#define NRBF 50
#define NELEM (NATOMS * H)
#define NT 4096

typedef unsigned short u16;
typedef unsigned int u32;

__device__ __forceinline__ float bfu(u16 u) { return __uint_as_float(((u32)u) << 16); }
__device__ __forceinline__ float ldf(const void* p, int i, int bf) {
    return bf ? bfu(((const u16*)p)[i]) : ((const float*)p)[i];
}
__device__ __forceinline__ float silu_f(float v) { return v / (1.f + __expf(-v)); }
__device__ __forceinline__ float cutoff_f(float w) {
    float c = 0.5f * (__cosf(w * 0.62831853072f) + 1.f);
    return (w < 5.f) ? c : 0.f;
}

// ---- dtype detect: means[49]==1.0 by construction.
__global__ void k_detect(const void* means, int* flag) {
    if (threadIdx.x == 0) {
        u32 w = ((const u32*)means)[24];
        *flag = ((w >> 16) == 0x3F80u) ? 1 : 0;
    }
}

__global__ __launch_bounds__(256) void k_embed(const int* __restrict__ z, const void* emb,
                                               float* __restrict__ x0, const int* flagp) {
    int bf = *flagp;
    int i = blockIdx.x * 256 + threadIdx.x;
    if (i < NELEM) {
        int n = i >> 7, f = i & 127;
        x0[i] = ldf(emb, z[n] * H + f, bf);
    }
}

__global__ __launch_bounds__(256) void k_store(const float* __restrict__ x, void* out,
                                               const int* flagp) {
    int bf = *flagp;
    int i = blockIdx.x * 256 + threadIdx.x;
    if (i < NELEM) {
        float v = x[i];
        if (bf) {
            u32 u = __float_as_uint(v);
            ((u16*)out)[i] = (u16)((u + 0x7FFFu + ((u >> 16) & 1u)) >> 16);
        } else {
            ((float*)out)[i] = v;
        }
    }
}

// ---- staging helper (proven r10): W row-major into sW padded 132, vectorized.
__device__ __forceinline__ void stage_weights(const void* W, int woff, int wstride,
                                              float* sW, int tid, int nthr, int bf) {
    if (bf) {
        const u32* W32 = (const u32*)W;
        for (int i = tid; i < (H * H) / 2; i += nthr) {
            int f2 = i >> 6, kk = i & 63;
            u32 wp = W32[((woff + f2 * wstride) >> 1) + kk];
            sW[f2 * 132 + 2 * kk]     = bfu((u16)(wp & 0xffffu));
            sW[f2 * 132 + 2 * kk + 1] = bfu((u16)(wp >> 16));
        }
    } else {
        const float2* Wf = (const float2*)W;
        for (int i = tid; i < (H * H) / 2; i += nthr) {
            int f2 = i >> 6, kk = i & 63;
            float2 v = Wf[((woff + f2 * wstride) >> 1) + kk];
            sW[f2 * 132 + 2 * kk]     = v.x;
            sW[f2 * 132 + 2 * kk + 1] = v.y;
        }
    }
}

// ---- node GEMM, K=128 (proven rounds 3-10, unchanged) ----
__global__ __launch_bounds__(1024) void k_node_gemm(const float* __restrict__ in,
                                                    const void* W, int woff, int wstride,
                                                    const void* bias, float* __restrict__ out,
                                                    int mode, const int* flagp) {
    __shared__ __align__(16) float sW[H * 132];
    __shared__ __align__(16) float sIn[16][132];
    __shared__ float sB[H];
    int tid = threadIdx.x;
    int bf = *flagp;
    stage_weights(W, woff, wstride, sW, tid, 1024, bf);
    if (tid < H) sB[tid] = bias ? ldf(bias, tid, bf) : 0.f;
    __syncthreads();
    int g = tid >> 7, f = tid & 127;
    for (int base = blockIdx.x * 16; base < NATOMS; base += gridDim.x * 16) {
        int n0 = base + 2 * g, n1 = n0 + 1;
        sIn[2 * g][f] = in[n0 * H + f];
        sIn[2 * g + 1][f] = in[n1 * H + f];
        __syncthreads();
        float a0 = 0.f, a1 = 0.f;
        #pragma unroll
        for (int k = 0; k < H; k += 4) {
            float4 w4 = *(const float4*)&sW[f * 132 + k];
            float4 i0 = *(const float4*)&sIn[2 * g][k];
            float4 i1 = *(const float4*)&sIn[2 * g + 1][k];
            a0 = fmaf(w4.x, i0.x, a0); a0 = fmaf(w4.y, i0.y, a0);
            a0 = fmaf(w4.z, i0.z, a0); a0 = fmaf(w4.w, i0.w, a0);
            a1 = fmaf(w4.x, i1.x, a1); a1 = fmaf(w4.y, i1.y, a1);
            a1 = fmaf(w4.z, i1.z, a1); a1 = fmaf(w4.w, i1.w, a1);
        }
        float v0 = a0 + sB[f], v1 = a1 + sB[f];
        if (mode == 1) { v0 = silu_f(v0); v1 = silu_f(v1); }
        if (mode == 2) { out[n0 * H + f] += v0; out[n1 * H + f] += v1; }
        else           { out[n0 * H + f] = v0;  out[n1 * H + f] = v1; }
        __syncthreads();
    }
}

// ---- table GEMM: T[i,:] <- (T[i,:] @ w1.T + b1) * C(w_i), in-place (proven r8) ----
__global__ __launch_bounds__(1024) void k_table_gemm(float* __restrict__ T,
                                                     const void* W, int woff,
                                                     const void* bias, int boff,
                                                     const int* flagp) {
    __shared__ __align__(16) float sW[H * 132];
    __shared__ __align__(16) float sIn[16][132];
    __shared__ float sB[H];
    int tid = threadIdx.x;
    int bf = *flagp;
    stage_weights(W, woff, H, sW, tid, 1024, bf);
    if (tid < H) sB[tid] = ldf(bias, boff + tid, bf);
    __syncthreads();
    int g = tid >> 7, f = tid & 127;
    for (int base = blockIdx.x * 16; base < NT; base += gridDim.x * 16) {
        int n0 = base + 2 * g, n1 = n0 + 1;       // NT % 16 == 0
        sIn[2 * g][f] = T[n0 * H + f];
        sIn[2 * g + 1][f] = T[n1 * H + f];
        __syncthreads();
        float a0 = 0.f, a1 = 0.f;
        #pragma unroll
        for (int k = 0; k < H; k += 4) {
            float4 w4 = *(const float4*)&sW[f * 132 + k];
            float4 i0 = *(const float4*)&sIn[2 * g][k];
            float4 i1 = *(const float4*)&sIn[2 * g + 1][k];
            a0 = fmaf(w4.x, i0.x, a0); a0 = fmaf(w4.y, i0.y, a0);
            a0 = fmaf(w4.z, i0.z, a0); a0 = fmaf(w4.w, i0.w, a0);
            a1 = fmaf(w4.x, i1.x, a1); a1 = fmaf(w4.y, i1.y, a1);
            a1 = fmaf(w4.z, i1.z, a1); a1 = fmaf(w4.w, i1.w, a1);
        }
        float w0v = (float)n0 * (5.0f / (NT - 1));
        float w1v = (float)n1 * (5.0f / (NT - 1));
        T[n0 * H + f] = (a0 + sB[f]) * cutoff_f(w0v);
        T[n1 * H + f] = (a1 + sB[f]) * cutoff_f(w1v);
        __syncthreads();
    }
}

// ---- w-table build v2 FIXED: each 128-thread group walks 8 consecutive rows
// of its block's 16-row slice (r11 bug: only 2 of 16 rows were written).
// Per-row RBF hoisted to LDS; weight row stride 53 (odd word -> 2-way free).
// mode 1: T[i,f]=silu(C*g_f+b_f)   mode 0: T[i,f]=(C*g_f+b_f)*C
__global__ __launch_bounds__(256) void k_build_table2(const void* means, const void* betas,
                                                      const void* W, int woff,
                                                      const void* B, int boff,
                                                      float* __restrict__ T, int mode,
                                                      const int* flagp) {
    __shared__ float sW[H * 53];
    __shared__ float sM[NRBF], sBe[NRBF];
    __shared__ float sR[2][56];
    int tid = threadIdx.x;
    int bf = *flagp;
    for (int i = tid; i < H * NRBF; i += 256) {
        int f2 = i / NRBF, k = i - f2 * NRBF;
        sW[f2 * 53 + k] = ldf(W, woff + i, bf);
    }
    if (tid < NRBF) { sM[tid] = ldf(means, tid, bf); sBe[tid] = ldf(betas, tid, bf); }
    __syncthreads();
    int g = tid >> 7, f = tid & 127;
    float bv = ldf(B, boff + f, bf);
    int base = blockIdx.x * 16;               // 256 blocks x 16 rows = NT
    #pragma unroll 1
    for (int r = 0; r < 8; ++r) {
        int row = base + g * 8 + r;           // group 0: base..base+7, group 1: base+8..base+15
        float w = (float)row * (5.0f / (NT - 1));
        if (f < NRBF) {
            float t = expf(-w) - sM[f];
            sR[g][f] = expf(-sBe[f] * t * t);
        }
        __syncthreads();
        float acc = 0.f;
        #pragma unroll
        for (int k = 0; k < NRBF; ++k)
            acc = fmaf(sW[f * 53 + k], sR[g][k], acc);
        float c = 0.5f * (cosf(w * 0.62831853071795864f) + 1.f);
        if (!(w < 5.f)) c = 0.f;
        float pre = c * acc + bv;
        T[row * H + f] = (mode == 1) ? silu_f(pre) : pre * c;
        __syncthreads();
    }
}

// ---- counting sort by src (proven rounds 4/5/7/9) ----
__global__ __launch_bounds__(256) void k_hist(const int* __restrict__ src, int* __restrict__ deg) {
    int e = blockIdx.x * 256 + threadIdx.x;
    if (e < NEDGES) atomicAdd(&deg[src[e]], 1);
}

__global__ __launch_bounds__(1024) void k_scan(const int* __restrict__ deg, int* __restrict__ rs) {
    __shared__ int buf[1024];
    __shared__ int carry;
    int tid = threadIdx.x;
    if (tid == 0) carry = 0;
    __syncthreads();
    for (int c = 0; c < 10; ++c) {
        int i = c * 1024 + tid;
        int v = (i < NATOMS) ? deg[i] : 0;
        buf[tid] = v;
        __syncthreads();
        for (int off = 1; off < 1024; off <<= 1) {
            int t = (tid >= off) ? buf[tid - off] : 0;
            __syncthreads();
            buf[tid] += t;
            __syncthreads();
        }
        int base = carry;
        if (i < NATOMS) rs[i] = base + buf[tid] - v;
        __syncthreads();
        if (tid == 0) carry = base + buf[1023];
        __syncthreads();
    }
}

__global__ __launch_bounds__(256) void k_scatter_perm(const int* __restrict__ src,
                                                      const int* __restrict__ dst,
                                                      const void* ew,
                                                      const int* __restrict__ rs,
                                                      int* __restrict__ cnt,
                                                      int* __restrict__ srcs,
                                                      int* __restrict__ dsts,
                                                      float* __restrict__ ews,
                                                      const int* flagp) {
    int e = blockIdx.x * 256 + threadIdx.x;
    if (e < NEDGES) {
        int s = src[e];
        int p = rs[s] + atomicAdd(&cnt[s], 1);
        srcs[p] = s;
        dsts[p] = dst[e];
        ews[p] = ldf(ew, e, *flagp);
    }
}

// ---- edge apply over SORTED edges, one WAVE per edge (float2 lanes),
// chunk 40, run-accumulate, one atomic flush per src-run (proven r10) ----
__global__ __launch_bounds__(256) void k_edge_apply2(const int* __restrict__ srcs,
                                                     const int* __restrict__ dsts,
                                                     const float* __restrict__ ews,
                                                     const float* __restrict__ T,
                                                     const float* __restrict__ vin,
                                                     float* __restrict__ acc,
                                                     int mask_self) {
    int tid = threadIdx.x;
    int g = tid >> 6;                 // 4 waves per block
    int lane = tid & 63;
    int gid = blockIdx.x * 4 + g;     // 2000 blocks -> 8000 groups x 40 edges
    int r0 = gid * 40;
    int rEnd = min(r0 + 40, NEDGES);
    const float2* T2 = (const float2*)T;
    const float2* v2 = (const float2*)vin;
    int cur = -1;
    float rx = 0.f, ry = 0.f;
    for (int e = r0; e < rEnd; ++e) {     // e wave-uniform
        int s = srcs[e], d = dsts[e];
        if (mask_self && s == d) continue;
        float u = ews[e] * ((float)(NT - 1) / 5.0f);
        int ix = (int)u; ix = min(ix, NT - 2);
        float fr = u - (float)ix;
        float2 ta = T2[ix * 64 + lane];
        float2 tb = T2[ix * 64 + 64 + lane];
        float wx = fmaf(fr, tb.x - ta.x, ta.x);
        float wy = fmaf(fr, tb.y - ta.y, ta.y);
        if (s != cur) {
            if (cur >= 0) {
                atomicAdd(&acc[cur * H + 2 * lane], rx);
                atomicAdd(&acc[cur * H + 2 * lane + 1], ry);
            }
            cur = s; rx = 0.f; ry = 0.f;
        }
        float2 hv = v2[d * 64 + lane];
        rx = fmaf(wx, hv.x, rx);
        ry = fmaf(wy, hv.y, ry);
    }
    if (cur >= 0) {
        atomicAdd(&acc[cur * H + 2 * lane], rx);
        atomicAdd(&acc[cur * H + 2 * lane + 1], ry);
    }
}

extern "C" void kernel_launch(void* const* d_in, const int* in_sizes, int n_in,
                              void* d_out, int out_size, void* d_ws, size_t ws_size,
                              hipStream_t stream) {
    const int* z  = (const int*)d_in[0];
    const int* ei = (const int*)d_in[1];
    const void* ew        = d_in[2];
    const void* emb       = d_in[3];
    const void* means     = d_in[4];
    const void* betas     = d_in[5];
    const void* ne_proj_w = d_in[6];
    const void* ne_proj_b = d_in[7];
    const void* ne_comb_w = d_in[8];
    const void* ne_comb_b = d_in[9];
    const void* mlp_w0    = d_in[10];
    const void* mlp_b0    = d_in[11];
    const void* mlp_w1    = d_in[12];
    const void* mlp_b1    = d_in[13];
    const void* lin1_w    = d_in[14];
    const void* lin2_w    = d_in[15];
    const void* lin2_b    = d_in[16];
    const void* lin_w     = d_in[17];
    const void* lin_b     = d_in[18];

    const int* srcp = ei;
    const int* dstp = ei + NEDGES;

    float* buf0 = (float*)d_ws;            // x0, then h
    float* buf1 = buf0 + NELEM;            // scatter accumulator
    float* x    = buf1 + NELEM;            // persistent fp32 node state
    int*   flag = (int*)(x + NELEM);
    int*   deg  = flag + 16;
    int*   cnt  = deg + 10240;
    int*   rs   = cnt + 10240;
    int*   srcs = rs + 10240;
    int*   dsts = srcs + NEDGES;
    float* ews  = (float*)(dsts + NEDGES);
    float* T    = ews + NEDGES;            // NT x 128 fp32 table (2.1 MB at NT=4096)

    const int gElem = (NELEM + 255) / 256;
    const int gEdge = (NEDGES + 255) / 256;

    k_detect<<<1, 64, 0, stream>>>(means, flag);
    k_embed<<<gElem, 256, 0, stream>>>(z, emb, buf0, flag);

    // counting sort by src (once, reused by all 4 edge passes)
    hipMemsetAsync(deg, 0, 2 * 10240 * sizeof(int), stream);
    k_hist<<<gEdge, 256, 0, stream>>>(srcp, deg);
    k_scan<<<1, 1024, 0, stream>>>(deg, rs);
    k_scatter_perm<<<gEdge, 256, 0, stream>>>(srcp, dstp, ew, rs, cnt,
                                              srcs, dsts, ews, flag);

    // NeighborEmbedding: fully-baked table + sorted run-accumulate apply
    hipMemsetAsync(buf1, 0, (size_t)NELEM * sizeof(float), stream);
    k_build_table2<<<NT / 16, 256, 0, stream>>>(means, betas, ne_proj_w, 0,
                                                ne_proj_b, 0, T, 0, flag);
    k_edge_apply2<<<2000, 256, 0, stream>>>(srcs, dsts, ews, T, buf0, buf1, 1);
    k_node_gemm<<<512, 1024, 0, stream>>>(buf0, ne_comb_w, 0,   256, ne_comb_b, x, 0, flag);
    k_node_gemm<<<512, 1024, 0, stream>>>(buf1, ne_comb_w, 128, 256, nullptr,   x, 2, flag);

    for (int L = 0; L < 3; ++L) {
        // h = x @ l1w.T
        k_node_gemm<<<512, 1024, 0, stream>>>(x, lin1_w, L * H * H, 128, nullptr, buf0, 0, flag);
        hipMemsetAsync(buf1, 0, (size_t)NELEM * sizeof(float), stream);
        // full filter table: silu-row table, then (T @ w1.T + b1)*C in-place
        k_build_table2<<<NT / 16, 256, 0, stream>>>(means, betas, mlp_w0, L * H * NRBF,
                                                    mlp_b0, L * H, T, 1, flag);
        k_table_gemm<<<256, 1024, 0, stream>>>(T, mlp_w1, L * H * H, mlp_b1, L * H, flag);
        // edge pass: a[src] += T(w) ⊙ h[dst], sorted + run-accumulated
        k_edge_apply2<<<2000, 256, 0, stream>>>(srcs, dsts, ews, T, buf0, buf1, 0);
        // h = silu(a @ l2w.T + b2);  x += h @ lw.T + lb
        k_node_gemm<<<512, 1024, 0, stream>>>(buf1, lin2_w, L * H * H, 128, lin2_b, buf0, 1, flag);
        k_node_gemm<<<512, 1024, 0, stream>>>(buf0, lin_w,  L * H * H, 128, lin_b,  x,    2, flag);
    }

    k_store<<<gElem, 256, 0, stream>>>(x, d_out, flag);
}

// Round 13
// 690.369 us; speedup vs baseline: 1.8744x; 1.0446x over previous
//
#include <hip/hip_runtime.h>
#include <hip/hip_bf16.h>

#define NATOMS 10000
#define NEDGES 320000
#define H 128
#define NRBF 50
#define NELEM (NATOMS * H)
#define NT 4096

typedef unsigned short u16;
typedef unsigned int u32;

__device__ __forceinline__ float bfu(u16 u) { return __uint_as_float(((u32)u) << 16); }
__device__ __forceinline__ float ldf(const void* p, int i, int bf) {
    return bf ? bfu(((const u16*)p)[i]) : ((const float*)p)[i];
}
__device__ __forceinline__ float silu_f(float v) { return v / (1.f + __expf(-v)); }
__device__ __forceinline__ float cutoff_f(float w) {
    float c = 0.5f * (__cosf(w * 0.62831853072f) + 1.f);
    return (w < 5.f) ? c : 0.f;
}

// ---- dtype detect: means[49]==1.0 by construction.
__global__ void k_detect(const void* means, int* flag) {
    if (threadIdx.x == 0) {
        u32 w = ((const u32*)means)[24];
        *flag = ((w >> 16) == 0x3F80u) ? 1 : 0;
    }
}

__global__ __launch_bounds__(256) void k_embed(const int* __restrict__ z, const void* emb,
                                               float* __restrict__ x0, const int* flagp) {
    int bf = *flagp;
    int i = blockIdx.x * 256 + threadIdx.x;
    if (i < NELEM) {
        int n = i >> 7, f = i & 127;
        x0[i] = ldf(emb, z[n] * H + f, bf);
    }
}

__global__ __launch_bounds__(256) void k_store(const float* __restrict__ x, void* out,
                                               const int* flagp) {
    int bf = *flagp;
    int i = blockIdx.x * 256 + threadIdx.x;
    if (i < NELEM) {
        float v = x[i];
        if (bf) {
            u32 u = __float_as_uint(v);
            ((u16*)out)[i] = (u16)((u + 0x7FFFu + ((u >> 16) & 1u)) >> 16);
        } else {
            ((float*)out)[i] = v;
        }
    }
}

// ---- staging helper (proven r10): W row-major into sW padded 132, vectorized.
__device__ __forceinline__ void stage_weights(const void* W, int woff, int wstride,
                                              float* sW, int tid, int nthr, int bf) {
    if (bf) {
        const u32* W32 = (const u32*)W;
        for (int i = tid; i < (H * H) / 2; i += nthr) {
            int f2 = i >> 6, kk = i & 63;
            u32 wp = W32[((woff + f2 * wstride) >> 1) + kk];
            sW[f2 * 132 + 2 * kk]     = bfu((u16)(wp & 0xffffu));
            sW[f2 * 132 + 2 * kk + 1] = bfu((u16)(wp >> 16));
        }
    } else {
        const float2* Wf = (const float2*)W;
        for (int i = tid; i < (H * H) / 2; i += nthr) {
            int f2 = i >> 6, kk = i & 63;
            float2 v = Wf[((woff + f2 * wstride) >> 1) + kk];
            sW[f2 * 132 + 2 * kk]     = v.x;
            sW[f2 * 132 + 2 * kk + 1] = v.y;
        }
    }
}

// ---- node GEMM, K=128 (proven rounds 3-12, unchanged) ----
__global__ __launch_bounds__(1024) void k_node_gemm(const float* __restrict__ in,
                                                    const void* W, int woff, int wstride,
                                                    const void* bias, float* __restrict__ out,
                                                    int mode, const int* flagp) {
    __shared__ __align__(16) float sW[H * 132];
    __shared__ __align__(16) float sIn[16][132];
    __shared__ float sB[H];
    int tid = threadIdx.x;
    int bf = *flagp;
    stage_weights(W, woff, wstride, sW, tid, 1024, bf);
    if (tid < H) sB[tid] = bias ? ldf(bias, tid, bf) : 0.f;
    __syncthreads();
    int g = tid >> 7, f = tid & 127;
    for (int base = blockIdx.x * 16; base < NATOMS; base += gridDim.x * 16) {
        int n0 = base + 2 * g, n1 = n0 + 1;
        sIn[2 * g][f] = in[n0 * H + f];
        sIn[2 * g + 1][f] = in[n1 * H + f];
        __syncthreads();
        float a0 = 0.f, a1 = 0.f;
        #pragma unroll
        for (int k = 0; k < H; k += 4) {
            float4 w4 = *(const float4*)&sW[f * 132 + k];
            float4 i0 = *(const float4*)&sIn[2 * g][k];
            float4 i1 = *(const float4*)&sIn[2 * g + 1][k];
            a0 = fmaf(w4.x, i0.x, a0); a0 = fmaf(w4.y, i0.y, a0);
            a0 = fmaf(w4.z, i0.z, a0); a0 = fmaf(w4.w, i0.w, a0);
            a1 = fmaf(w4.x, i1.x, a1); a1 = fmaf(w4.y, i1.y, a1);
            a1 = fmaf(w4.z, i1.z, a1); a1 = fmaf(w4.w, i1.w, a1);
        }
        float v0 = a0 + sB[f], v1 = a1 + sB[f];
        if (mode == 1) { v0 = silu_f(v0); v1 = silu_f(v1); }
        if (mode == 2) { out[n0 * H + f] += v0; out[n1 * H + f] += v1; }
        else           { out[n0 * H + f] = v0;  out[n1 * H + f] = v1; }
        __syncthreads();
    }
}

// ---- FUSED filter table: build silu(RBF) row in LDS, immediately GEMM vs w1,
// write final Wf table. Combines proven k_build_table2 + k_table_gemm structures.
// 256 blocks x 16 rows = NT. One pass, no intermediate T write/read.
__global__ __launch_bounds__(1024) void k_filter_table(const void* means, const void* betas,
                                                       const void* W0, int w0off,
                                                       const void* B0, int b0off,
                                                       const void* W1, int w1off,
                                                       const void* B1, int b1off,
                                                       float* __restrict__ T,
                                                       const int* flagp) {
    __shared__ __align__(16) float sW1[H * 132];
    __shared__ float sW0[H * 53];
    __shared__ __align__(16) float sIn[16][132];
    __shared__ float sR[16][56];
    __shared__ float sM[NRBF], sBe[NRBF];
    int tid = threadIdx.x;
    int bf = *flagp;
    stage_weights(W1, w1off, H, sW1, tid, 1024, bf);
    for (int i = tid; i < H * NRBF; i += 1024) {
        int f2 = i / NRBF, k = i - f2 * NRBF;
        sW0[f2 * 53 + k] = ldf(W0, w0off + i, bf);
    }
    if (tid < NRBF) { sM[tid] = ldf(means, tid, bf); sBe[tid] = ldf(betas, tid, bf); }
    __syncthreads();
    int g = tid >> 7, f = tid & 127;
    float b0r = ldf(B0, b0off + f, bf);
    float b1r = ldf(B1, b1off + f, bf);
    int base = blockIdx.x * 16;
    int n0 = base + 2 * g, n1 = n0 + 1;
    float wv0 = (float)n0 * (5.0f / (NT - 1));
    float wv1 = (float)n1 * (5.0f / (NT - 1));
    // phase 1: per-row RBF values (lanes f<50 -> row n0, lanes 64..113 -> row n1)
    if (f < NRBF) {
        float t = expf(-wv0) - sM[f];
        sR[2 * g][f] = expf(-sBe[f] * t * t);
    } else if (f >= 64 && f < 64 + NRBF) {
        float t = expf(-wv1) - sM[f - 64];
        sR[2 * g + 1][f - 64] = expf(-sBe[f - 64] * t * t);
    }
    __syncthreads();
    // phase 2: t = silu(C * (w0 @ r) + b0) for both rows -> sIn
    float c0 = 0.5f * (cosf(wv0 * 0.62831853071795864f) + 1.f); if (!(wv0 < 5.f)) c0 = 0.f;
    float c1 = 0.5f * (cosf(wv1 * 0.62831853071795864f) + 1.f); if (!(wv1 < 5.f)) c1 = 0.f;
    float s0 = 0.f, s1 = 0.f;
    #pragma unroll
    for (int k = 0; k < NRBF; ++k) {
        float wk = sW0[f * 53 + k];
        s0 = fmaf(wk, sR[2 * g][k], s0);
        s1 = fmaf(wk, sR[2 * g + 1][k], s1);
    }
    sIn[2 * g][f] = silu_f(fmaf(c0, s0, b0r));
    sIn[2 * g + 1][f] = silu_f(fmaf(c1, s1, b0r));
    __syncthreads();
    // phase 3: GEMM vs w1, epilogue (a + b1)*C, write final table rows
    float a0 = 0.f, a1 = 0.f;
    #pragma unroll
    for (int k = 0; k < H; k += 4) {
        float4 w4 = *(const float4*)&sW1[f * 132 + k];
        float4 i0 = *(const float4*)&sIn[2 * g][k];
        float4 i1 = *(const float4*)&sIn[2 * g + 1][k];
        a0 = fmaf(w4.x, i0.x, a0); a0 = fmaf(w4.y, i0.y, a0);
        a0 = fmaf(w4.z, i0.z, a0); a0 = fmaf(w4.w, i0.w, a0);
        a1 = fmaf(w4.x, i1.x, a1); a1 = fmaf(w4.y, i1.y, a1);
        a1 = fmaf(w4.z, i1.z, a1); a1 = fmaf(w4.w, i1.w, a1);
    }
    T[n0 * H + f] = (a0 + b1r) * c0;
    T[n1 * H + f] = (a1 + b1r) * c1;
}

// ---- NE w-table build (proven r12 fixed version), mode 0: T=(C*g+b)*C ----
__global__ __launch_bounds__(256) void k_build_table2(const void* means, const void* betas,
                                                      const void* W, int woff,
                                                      const void* B, int boff,
                                                      float* __restrict__ T,
                                                      const int* flagp) {
    __shared__ float sW[H * 53];
    __shared__ float sM[NRBF], sBe[NRBF];
    __shared__ float sR[2][56];
    int tid = threadIdx.x;
    int bf = *flagp;
    for (int i = tid; i < H * NRBF; i += 256) {
        int f2 = i / NRBF, k = i - f2 * NRBF;
        sW[f2 * 53 + k] = ldf(W, woff + i, bf);
    }
    if (tid < NRBF) { sM[tid] = ldf(means, tid, bf); sBe[tid] = ldf(betas, tid, bf); }
    __syncthreads();
    int g = tid >> 7, f = tid & 127;
    float bv = ldf(B, boff + f, bf);
    int base = blockIdx.x * 16;
    #pragma unroll 1
    for (int r = 0; r < 8; ++r) {
        int row = base + g * 8 + r;
        float w = (float)row * (5.0f / (NT - 1));
        if (f < NRBF) {
            float t = expf(-w) - sM[f];
            sR[g][f] = expf(-sBe[f] * t * t);
        }
        __syncthreads();
        float acc = 0.f;
        #pragma unroll
        for (int k = 0; k < NRBF; ++k)
            acc = fmaf(sW[f * 53 + k], sR[g][k], acc);
        float c = 0.5f * (cosf(w * 0.62831853071795864f) + 1.f);
        if (!(w < 5.f)) c = 0.f;
        T[row * H + f] = (c * acc + bv) * c;
        __syncthreads();
    }
}

// ---- counting sort by src (proven) ----
__global__ __launch_bounds__(256) void k_hist(const int* __restrict__ src, int* __restrict__ deg) {
    int e = blockIdx.x * 256 + threadIdx.x;
    if (e < NEDGES) atomicAdd(&deg[src[e]], 1);
}

__global__ __launch_bounds__(1024) void k_scan(const int* __restrict__ deg, int* __restrict__ rs) {
    __shared__ int buf[1024];
    __shared__ int carry;
    int tid = threadIdx.x;
    if (tid == 0) carry = 0;
    __syncthreads();
    for (int c = 0; c < 10; ++c) {
        int i = c * 1024 + tid;
        int v = (i < NATOMS) ? deg[i] : 0;
        buf[tid] = v;
        __syncthreads();
        for (int off = 1; off < 1024; off <<= 1) {
            int t = (tid >= off) ? buf[tid - off] : 0;
            __syncthreads();
            buf[tid] += t;
            __syncthreads();
        }
        int base = carry;
        if (i < NATOMS) rs[i] = base + buf[tid] - v;
        __syncthreads();
        if (tid == 0) carry = base + buf[1023];
        __syncthreads();
    }
}

__global__ __launch_bounds__(256) void k_scatter_perm(const int* __restrict__ src,
                                                      const int* __restrict__ dst,
                                                      const void* ew,
                                                      const int* __restrict__ rs,
                                                      int* __restrict__ cnt,
                                                      int* __restrict__ srcs,
                                                      int* __restrict__ dsts,
                                                      float* __restrict__ ews,
                                                      const int* flagp) {
    int e = blockIdx.x * 256 + threadIdx.x;
    if (e < NEDGES) {
        int s = src[e];
        int p = rs[s] + atomicAdd(&cnt[s], 1);
        srcs[p] = s;
        dsts[p] = dst[e];
        ews[p] = ldf(ew, e, *flagp);
    }
}

// ---- edge apply over SORTED edges, one WAVE per edge (float2 lanes),
// chunk 20 (r13: was 40 — 2x wave oversubscription for latency hiding),
// run-accumulate, one atomic flush per src-run ----
__global__ __launch_bounds__(256) void k_edge_apply2(const int* __restrict__ srcs,
                                                     const int* __restrict__ dsts,
                                                     const float* __restrict__ ews,
                                                     const float* __restrict__ T,
                                                     const float* __restrict__ vin,
                                                     float* __restrict__ acc,
                                                     int mask_self) {
    int tid = threadIdx.x;
    int g = tid >> 6;                 // 4 waves per block
    int lane = tid & 63;
    int gid = blockIdx.x * 4 + g;     // 4000 blocks -> 16000 groups x 20 edges
    int r0 = gid * 20;
    int rEnd = min(r0 + 20, NEDGES);
    const float2* T2 = (const float2*)T;
    const float2* v2 = (const float2*)vin;
    int cur = -1;
    float rx = 0.f, ry = 0.f;
    for (int e = r0; e < rEnd; ++e) {     // e wave-uniform
        int s = srcs[e], d = dsts[e];
        if (mask_self && s == d) continue;
        float u = ews[e] * ((float)(NT - 1) / 5.0f);
        int ix = (int)u; ix = min(ix, NT - 2);
        float fr = u - (float)ix;
        float2 ta = T2[ix * 64 + lane];
        float2 tb = T2[ix * 64 + 64 + lane];
        float wx = fmaf(fr, tb.x - ta.x, ta.x);
        float wy = fmaf(fr, tb.y - ta.y, ta.y);
        if (s != cur) {
            if (cur >= 0) {
                atomicAdd(&acc[cur * H + 2 * lane], rx);
                atomicAdd(&acc[cur * H + 2 * lane + 1], ry);
            }
            cur = s; rx = 0.f; ry = 0.f;
        }
        float2 hv = v2[d * 64 + lane];
        rx = fmaf(wx, hv.x, rx);
        ry = fmaf(wy, hv.y, ry);
    }
    if (cur >= 0) {
        atomicAdd(&acc[cur * H + 2 * lane], rx);
        atomicAdd(&acc[cur * H + 2 * lane + 1], ry);
    }
}

extern "C" void kernel_launch(void* const* d_in, const int* in_sizes, int n_in,
                              void* d_out, int out_size, void* d_ws, size_t ws_size,
                              hipStream_t stream) {
    const int* z  = (const int*)d_in[0];
    const int* ei = (const int*)d_in[1];
    const void* ew        = d_in[2];
    const void* emb       = d_in[3];
    const void* means     = d_in[4];
    const void* betas     = d_in[5];
    const void* ne_proj_w = d_in[6];
    const void* ne_proj_b = d_in[7];
    const void* ne_comb_w = d_in[8];
    const void* ne_comb_b = d_in[9];
    const void* mlp_w0    = d_in[10];
    const void* mlp_b0    = d_in[11];
    const void* mlp_w1    = d_in[12];
    const void* mlp_b1    = d_in[13];
    const void* lin1_w    = d_in[14];
    const void* lin2_w    = d_in[15];
    const void* lin2_b    = d_in[16];
    const void* lin_w     = d_in[17];
    const void* lin_b     = d_in[18];

    const int* srcp = ei;
    const int* dstp = ei + NEDGES;

    float* buf0 = (float*)d_ws;            // x0, then h
    float* buf1 = buf0 + NELEM;            // scatter accumulator
    float* x    = buf1 + NELEM;            // persistent fp32 node state
    int*   flag = (int*)(x + NELEM);
    int*   deg  = flag + 16;
    int*   cnt  = deg + 10240;
    int*   rs   = cnt + 10240;
    int*   srcs = rs + 10240;
    int*   dsts = srcs + NEDGES;
    float* ews  = (float*)(dsts + NEDGES);
    float* T    = ews + NEDGES;            // NT x 128 fp32 table

    const int gElem = (NELEM + 255) / 256;
    const int gEdge = (NEDGES + 255) / 256;

    k_detect<<<1, 64, 0, stream>>>(means, flag);
    k_embed<<<gElem, 256, 0, stream>>>(z, emb, buf0, flag);

    // counting sort by src (once, reused by all 4 edge passes)
    hipMemsetAsync(deg, 0, 2 * 10240 * sizeof(int), stream);
    k_hist<<<gEdge, 256, 0, stream>>>(srcp, deg);
    k_scan<<<1, 1024, 0, stream>>>(deg, rs);
    k_scatter_perm<<<gEdge, 256, 0, stream>>>(srcp, dstp, ew, rs, cnt,
                                              srcs, dsts, ews, flag);

    // NeighborEmbedding: fully-baked table + sorted run-accumulate apply
    hipMemsetAsync(buf1, 0, (size_t)NELEM * sizeof(float), stream);
    k_build_table2<<<NT / 16, 256, 0, stream>>>(means, betas, ne_proj_w, 0,
                                                ne_proj_b, 0, T, flag);
    k_edge_apply2<<<4000, 256, 0, stream>>>(srcs, dsts, ews, T, buf0, buf1, 1);
    k_node_gemm<<<512, 1024, 0, stream>>>(buf0, ne_comb_w, 0,   256, ne_comb_b, x, 0, flag);
    k_node_gemm<<<512, 1024, 0, stream>>>(buf1, ne_comb_w, 128, 256, nullptr,   x, 2, flag);

    for (int L = 0; L < 3; ++L) {
        // h = x @ l1w.T
        k_node_gemm<<<512, 1024, 0, stream>>>(x, lin1_w, L * H * H, 128, nullptr, buf0, 0, flag);
        hipMemsetAsync(buf1, 0, (size_t)NELEM * sizeof(float), stream);
        // fused filter table: silu-RBF row + w1 GEMM in one pass
        k_filter_table<<<NT / 16, 1024, 0, stream>>>(means, betas,
                                                     mlp_w0, L * H * NRBF, mlp_b0, L * H,
                                                     mlp_w1, L * H * H,    mlp_b1, L * H,
                                                     T, flag);
        // edge pass: a[src] += T(w) ⊙ h[dst], sorted + run-accumulated
        k_edge_apply2<<<4000, 256, 0, stream>>>(srcs, dsts, ews, T, buf0, buf1, 0);
        // h = silu(a @ l2w.T + b2);  x += h @ lw.T + lb
        k_node_gemm<<<512, 1024, 0, stream>>>(buf1, lin2_w, L * H * H, 128, lin2_b, buf0, 1, flag);
        k_node_gemm<<<512, 1024, 0, stream>>>(buf0, lin_w,  L * H * H, 128, lin_b,  x,    2, flag);
    }

    k_store<<<gElem, 256, 0, stream>>>(x, d_out, flag);
}

// Round 14
// 596.380 us; speedup vs baseline: 2.1698x; 1.1576x over previous
//
#include <hip/hip_runtime.h>
#include <hip/hip_bf16.h>

#define NATOMS 10000
#define NEDGES 320000
#define H 128
#define NRBF 50
#define NELEM (NATOMS * H)
#define NT 4096

typedef unsigned short u16;
typedef unsigned int u32;

__device__ __forceinline__ float bfu(u16 u) { return __uint_as_float(((u32)u) << 16); }
__device__ __forceinline__ float ldf(const void* p, int i, int bf) {
    return bf ? bfu(((const u16*)p)[i]) : ((const float*)p)[i];
}
__device__ __forceinline__ float silu_f(float v) { return v / (1.f + __expf(-v)); }
__device__ __forceinline__ float cutoff_f(float w) {
    float c = 0.5f * (__cosf(w * 0.62831853072f) + 1.f);
    return (w < 5.f) ? c : 0.f;
}

// ---- dtype detect: means[49]==1.0 by construction.
__global__ void k_detect(const void* means, int* flag) {
    if (threadIdx.x == 0) {
        u32 w = ((const u32*)means)[24];
        *flag = ((w >> 16) == 0x3F80u) ? 1 : 0;
    }
}

__global__ __launch_bounds__(256) void k_embed(const int* __restrict__ z, const void* emb,
                                               float* __restrict__ x0, const int* flagp) {
    int bf = *flagp;
    int i = blockIdx.x * 256 + threadIdx.x;
    if (i < NELEM) {
        int n = i >> 7, f = i & 127;
        x0[i] = ldf(emb, z[n] * H + f, bf);
    }
}

__global__ __launch_bounds__(256) void k_store(const float* __restrict__ x, void* out,
                                               const int* flagp) {
    int bf = *flagp;
    int i = blockIdx.x * 256 + threadIdx.x;
    if (i < NELEM) {
        float v = x[i];
        if (bf) {
            u32 u = __float_as_uint(v);
            ((u16*)out)[i] = (u16)((u + 0x7FFFu + ((u >> 16) & 1u)) >> 16);
        } else {
            ((float*)out)[i] = v;
        }
    }
}

// ---- staging helper (proven r10): W row-major into sW padded 132, vectorized.
__device__ __forceinline__ void stage_weights(const void* W, int woff, int wstride,
                                              float* sW, int tid, int nthr, int bf) {
    if (bf) {
        const u32* W32 = (const u32*)W;
        for (int i = tid; i < (H * H) / 2; i += nthr) {
            int f2 = i >> 6, kk = i & 63;
            u32 wp = W32[((woff + f2 * wstride) >> 1) + kk];
            sW[f2 * 132 + 2 * kk]     = bfu((u16)(wp & 0xffffu));
            sW[f2 * 132 + 2 * kk + 1] = bfu((u16)(wp >> 16));
        }
    } else {
        const float2* Wf = (const float2*)W;
        for (int i = tid; i < (H * H) / 2; i += nthr) {
            int f2 = i >> 6, kk = i & 63;
            float2 v = Wf[((woff + f2 * wstride) >> 1) + kk];
            sW[f2 * 132 + 2 * kk]     = v.x;
            sW[f2 * 132 + 2 * kk + 1] = v.y;
        }
    }
}

// k-loop helper: dot of sW row f with sIn rows p0,p1 (acc pair)
__device__ __forceinline__ void dot2(const float* sW, const float* r0, const float* r1,
                                     int f, float& a0, float& a1) {
    #pragma unroll
    for (int k = 0; k < H; k += 4) {
        float4 w4 = *(const float4*)&sW[f * 132 + k];
        float4 i0 = *(const float4*)&r0[k];
        float4 i1 = *(const float4*)&r1[k];
        a0 = fmaf(w4.x, i0.x, a0); a0 = fmaf(w4.y, i0.y, a0);
        a0 = fmaf(w4.z, i0.z, a0); a0 = fmaf(w4.w, i0.w, a0);
        a1 = fmaf(w4.x, i1.x, a1); a1 = fmaf(w4.y, i1.y, a1);
        a1 = fmaf(w4.z, i1.z, a1); a1 = fmaf(w4.w, i1.w, a1);
    }
}

// ---- node GEMM, K=128 (proven rounds 3-13; used for lin1) ----
__global__ __launch_bounds__(1024) void k_node_gemm(const float* __restrict__ in,
                                                    const void* W, int woff, int wstride,
                                                    const void* bias, float* __restrict__ out,
                                                    int mode, const int* flagp) {
    __shared__ __align__(16) float sW[H * 132];
    __shared__ __align__(16) float sIn[16][132];
    __shared__ float sB[H];
    int tid = threadIdx.x;
    int bf = *flagp;
    stage_weights(W, woff, wstride, sW, tid, 1024, bf);
    if (tid < H) sB[tid] = bias ? ldf(bias, tid, bf) : 0.f;
    __syncthreads();
    int g = tid >> 7, f = tid & 127;
    for (int base = blockIdx.x * 16; base < NATOMS; base += gridDim.x * 16) {
        int n0 = base + 2 * g, n1 = n0 + 1;
        sIn[2 * g][f] = in[n0 * H + f];
        sIn[2 * g + 1][f] = in[n1 * H + f];
        __syncthreads();
        float a0 = 0.f, a1 = 0.f;
        dot2(sW, sIn[2 * g], sIn[2 * g + 1], f, a0, a1);
        float v0 = a0 + sB[f], v1 = a1 + sB[f];
        if (mode == 1) { v0 = silu_f(v0); v1 = silu_f(v1); }
        if (mode == 2) { out[n0 * H + f] += v0; out[n1 * H + f] += v1; }
        else           { out[n0 * H + f] = v0;  out[n1 * H + f] = v1; }
        __syncthreads();
    }
}

// ---- FUSED lin2+lin: x[n] += silu(a@W2.T+b2) @ Wl.T + bl  (r3 phase1/2 shape) ----
__global__ __launch_bounds__(1024) void k_fused_lin(const float* __restrict__ a,
                                                    const void* W2, int w2off,
                                                    const void* B2, int b2off,
                                                    const void* Wl, int wloff,
                                                    const void* Bl, int bloff,
                                                    float* __restrict__ x,
                                                    const int* flagp) {
    __shared__ __align__(16) float sW2[H * 132];
    __shared__ __align__(16) float sWl[H * 132];
    __shared__ __align__(16) float sIn[16][132];
    __shared__ float sB2[H], sBl[H];
    int tid = threadIdx.x;
    int bf = *flagp;
    stage_weights(W2, w2off, H, sW2, tid, 1024, bf);
    stage_weights(Wl, wloff, H, sWl, tid, 1024, bf);
    if (tid < H) { sB2[tid] = ldf(B2, b2off + tid, bf); sBl[tid] = ldf(Bl, bloff + tid, bf); }
    __syncthreads();
    int g = tid >> 7, f = tid & 127;
    for (int base = blockIdx.x * 16; base < NATOMS; base += gridDim.x * 16) {
        int n0 = base + 2 * g, n1 = n0 + 1;
        sIn[2 * g][f] = a[n0 * H + f];
        sIn[2 * g + 1][f] = a[n1 * H + f];
        __syncthreads();
        float a0 = 0.f, a1 = 0.f;
        dot2(sW2, sIn[2 * g], sIn[2 * g + 1], f, a0, a1);
        float t0 = silu_f(a0 + sB2[f]), t1 = silu_f(a1 + sB2[f]);
        __syncthreads();
        sIn[2 * g][f] = t0;
        sIn[2 * g + 1][f] = t1;
        __syncthreads();
        float c0 = 0.f, c1 = 0.f;
        dot2(sWl, sIn[2 * g], sIn[2 * g + 1], f, c0, c1);
        x[n0 * H + f] += c0 + sBl[f];
        x[n1 * H + f] += c1 + sBl[f];
        __syncthreads();
    }
}

// ---- FUSED NE combine: x = buf0@W[:, :128].T + buf1@W[:, 128:].T + b ----
__global__ __launch_bounds__(1024) void k_ne_comb(const float* __restrict__ in0,
                                                  const float* __restrict__ in1,
                                                  const void* W, const void* B,
                                                  float* __restrict__ x,
                                                  const int* flagp) {
    __shared__ __align__(16) float sWa[H * 132];
    __shared__ __align__(16) float sWb[H * 132];
    __shared__ __align__(16) float sIn[16][132];
    __shared__ float sB[H];
    int tid = threadIdx.x;
    int bf = *flagp;
    stage_weights(W, 0,   256, sWa, tid, 1024, bf);   // cols 0..127
    stage_weights(W, 128, 256, sWb, tid, 1024, bf);   // cols 128..255
    if (tid < H) sB[tid] = ldf(B, tid, bf);
    __syncthreads();
    int g = tid >> 7, f = tid & 127;
    for (int base = blockIdx.x * 16; base < NATOMS; base += gridDim.x * 16) {
        int n0 = base + 2 * g, n1 = n0 + 1;
        sIn[2 * g][f] = in0[n0 * H + f];
        sIn[2 * g + 1][f] = in0[n1 * H + f];
        __syncthreads();
        float a0 = 0.f, a1 = 0.f;
        dot2(sWa, sIn[2 * g], sIn[2 * g + 1], f, a0, a1);
        __syncthreads();
        sIn[2 * g][f] = in1[n0 * H + f];
        sIn[2 * g + 1][f] = in1[n1 * H + f];
        __syncthreads();
        dot2(sWb, sIn[2 * g], sIn[2 * g + 1], f, a0, a1);
        x[n0 * H + f] = a0 + sB[f];
        x[n1 * H + f] = a1 + sB[f];
        __syncthreads();
    }
}

// ---- FUSED filter table (proven r13) ----
__global__ __launch_bounds__(1024) void k_filter_table(const void* means, const void* betas,
                                                       const void* W0, int w0off,
                                                       const void* B0, int b0off,
                                                       const void* W1, int w1off,
                                                       const void* B1, int b1off,
                                                       float* __restrict__ T,
                                                       const int* flagp) {
    __shared__ __align__(16) float sW1[H * 132];
    __shared__ float sW0[H * 53];
    __shared__ __align__(16) float sIn[16][132];
    __shared__ float sR[16][56];
    __shared__ float sM[NRBF], sBe[NRBF];
    int tid = threadIdx.x;
    int bf = *flagp;
    stage_weights(W1, w1off, H, sW1, tid, 1024, bf);
    for (int i = tid; i < H * NRBF; i += 1024) {
        int f2 = i / NRBF, k = i - f2 * NRBF;
        sW0[f2 * 53 + k] = ldf(W0, w0off + i, bf);
    }
    if (tid < NRBF) { sM[tid] = ldf(means, tid, bf); sBe[tid] = ldf(betas, tid, bf); }
    __syncthreads();
    int g = tid >> 7, f = tid & 127;
    float b0r = ldf(B0, b0off + f, bf);
    float b1r = ldf(B1, b1off + f, bf);
    int base = blockIdx.x * 16;
    int n0 = base + 2 * g, n1 = n0 + 1;
    float wv0 = (float)n0 * (5.0f / (NT - 1));
    float wv1 = (float)n1 * (5.0f / (NT - 1));
    if (f < NRBF) {
        float t = expf(-wv0) - sM[f];
        sR[2 * g][f] = expf(-sBe[f] * t * t);
    } else if (f >= 64 && f < 64 + NRBF) {
        float t = expf(-wv1) - sM[f - 64];
        sR[2 * g + 1][f - 64] = expf(-sBe[f - 64] * t * t);
    }
    __syncthreads();
    float c0 = 0.5f * (cosf(wv0 * 0.62831853071795864f) + 1.f); if (!(wv0 < 5.f)) c0 = 0.f;
    float c1 = 0.5f * (cosf(wv1 * 0.62831853071795864f) + 1.f); if (!(wv1 < 5.f)) c1 = 0.f;
    float s0 = 0.f, s1 = 0.f;
    #pragma unroll
    for (int k = 0; k < NRBF; ++k) {
        float wk = sW0[f * 53 + k];
        s0 = fmaf(wk, sR[2 * g][k], s0);
        s1 = fmaf(wk, sR[2 * g + 1][k], s1);
    }
    sIn[2 * g][f] = silu_f(fmaf(c0, s0, b0r));
    sIn[2 * g + 1][f] = silu_f(fmaf(c1, s1, b0r));
    __syncthreads();
    float a0 = 0.f, a1 = 0.f;
    dot2(sW1, sIn[2 * g], sIn[2 * g + 1], f, a0, a1);
    T[n0 * H + f] = (a0 + b1r) * c0;
    T[n1 * H + f] = (a1 + b1r) * c1;
}

// ---- NE w-table build (proven r12) ----
__global__ __launch_bounds__(256) void k_build_table2(const void* means, const void* betas,
                                                      const void* W, int woff,
                                                      const void* B, int boff,
                                                      float* __restrict__ T,
                                                      const int* flagp) {
    __shared__ float sW[H * 53];
    __shared__ float sM[NRBF], sBe[NRBF];
    __shared__ float sR[2][56];
    int tid = threadIdx.x;
    int bf = *flagp;
    for (int i = tid; i < H * NRBF; i += 256) {
        int f2 = i / NRBF, k = i - f2 * NRBF;
        sW[f2 * 53 + k] = ldf(W, woff + i, bf);
    }
    if (tid < NRBF) { sM[tid] = ldf(means, tid, bf); sBe[tid] = ldf(betas, tid, bf); }
    __syncthreads();
    int g = tid >> 7, f = tid & 127;
    float bv = ldf(B, boff + f, bf);
    int base = blockIdx.x * 16;
    #pragma unroll 1
    for (int r = 0; r < 8; ++r) {
        int row = base + g * 8 + r;
        float w = (float)row * (5.0f / (NT - 1));
        if (f < NRBF) {
            float t = expf(-w) - sM[f];
            sR[g][f] = expf(-sBe[f] * t * t);
        }
        __syncthreads();
        float acc = 0.f;
        #pragma unroll
        for (int k = 0; k < NRBF; ++k)
            acc = fmaf(sW[f * 53 + k], sR[g][k], acc);
        float c = 0.5f * (cosf(w * 0.62831853071795864f) + 1.f);
        if (!(w < 5.f)) c = 0.f;
        T[row * H + f] = (c * acc + bv) * c;
        __syncthreads();
    }
}

// ---- counting sort by src (proven) ----
__global__ __launch_bounds__(256) void k_hist(const int* __restrict__ src, int* __restrict__ deg) {
    int e = blockIdx.x * 256 + threadIdx.x;
    if (e < NEDGES) atomicAdd(&deg[src[e]], 1);
}

__global__ __launch_bounds__(1024) void k_scan(const int* __restrict__ deg, int* __restrict__ rs) {
    __shared__ int buf[1024];
    __shared__ int carry;
    int tid = threadIdx.x;
    if (tid == 0) carry = 0;
    __syncthreads();
    for (int c = 0; c < 10; ++c) {
        int i = c * 1024 + tid;
        int v = (i < NATOMS) ? deg[i] : 0;
        buf[tid] = v;
        __syncthreads();
        for (int off = 1; off < 1024; off <<= 1) {
            int t = (tid >= off) ? buf[tid - off] : 0;
            __syncthreads();
            buf[tid] += t;
            __syncthreads();
        }
        int base = carry;
        if (i < NATOMS) rs[i] = base + buf[tid] - v;
        __syncthreads();
        if (tid == 0) carry = base + buf[1023];
        __syncthreads();
    }
}

__global__ __launch_bounds__(256) void k_scatter_perm(const int* __restrict__ src,
                                                      const int* __restrict__ dst,
                                                      const void* ew,
                                                      const int* __restrict__ rs,
                                                      int* __restrict__ cnt,
                                                      int* __restrict__ srcs,
                                                      int* __restrict__ dsts,
                                                      float* __restrict__ ews,
                                                      const int* flagp) {
    int e = blockIdx.x * 256 + threadIdx.x;
    if (e < NEDGES) {
        int s = src[e];
        int p = rs[s] + atomicAdd(&cnt[s], 1);
        srcs[p] = s;
        dsts[p] = dst[e];
        ews[p] = ldf(ew, e, *flagp);
    }
}

// ---- edge apply, sorted, one WAVE per edge, 2-EDGE ILP (r14):
// independent load chains for edge pairs, run-combine scalar logic after.
// chunk 40 (NEDGES % 40 == 0 -> no tail), 2000 blocks x 4 waves.
__global__ __launch_bounds__(256) void k_edge_apply2(const int* __restrict__ srcs,
                                                     const int* __restrict__ dsts,
                                                     const float* __restrict__ ews,
                                                     const float* __restrict__ T,
                                                     const float* __restrict__ vin,
                                                     float* __restrict__ acc,
                                                     int mask_self) {
    int tid = threadIdx.x;
    int g = tid >> 6;
    int lane = tid & 63;
    int gid = blockIdx.x * 4 + g;     // 8000 groups x 40 edges
    int r0 = gid * 40;
    const float2* T2 = (const float2*)T;
    const float2* v2 = (const float2*)vin;
    int cur = -1;
    float rx = 0.f, ry = 0.f;
    for (int e = r0; e < r0 + 40; e += 2) {
        // --- issue both edges' loads up front (independent chains) ---
        int s0 = srcs[e], d0 = dsts[e];
        int s1 = srcs[e + 1], d1 = dsts[e + 1];
        float u0 = ews[e] * ((float)(NT - 1) / 5.0f);
        float u1 = ews[e + 1] * ((float)(NT - 1) / 5.0f);
        int ix0 = min((int)u0, NT - 2); float fr0 = u0 - (float)ix0;
        int ix1 = min((int)u1, NT - 2); float fr1 = u1 - (float)ix1;
        float2 ta0 = T2[ix0 * 64 + lane];
        float2 tb0 = T2[ix0 * 64 + 64 + lane];
        float2 ta1 = T2[ix1 * 64 + lane];
        float2 tb1 = T2[ix1 * 64 + 64 + lane];
        float2 h0 = v2[d0 * 64 + lane];
        float2 h1 = v2[d1 * 64 + lane];
        float vx0 = fmaf(fr0, tb0.x - ta0.x, ta0.x) * h0.x;
        float vy0 = fmaf(fr0, tb0.y - ta0.y, ta0.y) * h0.y;
        float vx1 = fmaf(fr1, tb1.x - ta1.x, ta1.x) * h1.x;
        float vy1 = fmaf(fr1, tb1.y - ta1.y, ta1.y) * h1.y;
        // --- run-combine (cheap VALU) ---
        if (!(mask_self && s0 == d0)) {
            if (s0 != cur) {
                if (cur >= 0) {
                    atomicAdd(&acc[cur * H + 2 * lane], rx);
                    atomicAdd(&acc[cur * H + 2 * lane + 1], ry);
                }
                cur = s0; rx = 0.f; ry = 0.f;
            }
            rx += vx0; ry += vy0;
        }
        if (!(mask_self && s1 == d1)) {
            if (s1 != cur) {
                if (cur >= 0) {
                    atomicAdd(&acc[cur * H + 2 * lane], rx);
                    atomicAdd(&acc[cur * H + 2 * lane + 1], ry);
                }
                cur = s1; rx = 0.f; ry = 0.f;
            }
            rx += vx1; ry += vy1;
        }
    }
    if (cur >= 0) {
        atomicAdd(&acc[cur * H + 2 * lane], rx);
        atomicAdd(&acc[cur * H + 2 * lane + 1], ry);
    }
}

extern "C" void kernel_launch(void* const* d_in, const int* in_sizes, int n_in,
                              void* d_out, int out_size, void* d_ws, size_t ws_size,
                              hipStream_t stream) {
    const int* z  = (const int*)d_in[0];
    const int* ei = (const int*)d_in[1];
    const void* ew        = d_in[2];
    const void* emb       = d_in[3];
    const void* means     = d_in[4];
    const void* betas     = d_in[5];
    const void* ne_proj_w = d_in[6];
    const void* ne_proj_b = d_in[7];
    const void* ne_comb_w = d_in[8];
    const void* ne_comb_b = d_in[9];
    const void* mlp_w0    = d_in[10];
    const void* mlp_b0    = d_in[11];
    const void* mlp_w1    = d_in[12];
    const void* mlp_b1    = d_in[13];
    const void* lin1_w    = d_in[14];
    const void* lin2_w    = d_in[15];
    const void* lin2_b    = d_in[16];
    const void* lin_w     = d_in[17];
    const void* lin_b     = d_in[18];

    const int* srcp = ei;
    const int* dstp = ei + NEDGES;

    float* buf0 = (float*)d_ws;            // x0, then h
    float* buf1 = buf0 + NELEM;            // scatter accumulator
    float* x    = buf1 + NELEM;            // persistent fp32 node state
    int*   flag = (int*)(x + NELEM);
    int*   deg  = flag + 16;
    int*   cnt  = deg + 10240;
    int*   rs   = cnt + 10240;
    int*   srcs = rs + 10240;
    int*   dsts = srcs + NEDGES;
    float* ews  = (float*)(dsts + NEDGES);
    float* T    = ews + NEDGES;            // NT x 128 fp32 table

    const int gElem = (NELEM + 255) / 256;
    const int gEdge = (NEDGES + 255) / 256;

    k_detect<<<1, 64, 0, stream>>>(means, flag);
    k_embed<<<gElem, 256, 0, stream>>>(z, emb, buf0, flag);

    // counting sort by src (once, reused by all 4 edge passes)
    hipMemsetAsync(deg, 0, 2 * 10240 * sizeof(int), stream);
    k_hist<<<gEdge, 256, 0, stream>>>(srcp, deg);
    k_scan<<<1, 1024, 0, stream>>>(deg, rs);
    k_scatter_perm<<<gEdge, 256, 0, stream>>>(srcp, dstp, ew, rs, cnt,
                                              srcs, dsts, ews, flag);

    // NeighborEmbedding
    hipMemsetAsync(buf1, 0, (size_t)NELEM * sizeof(float), stream);
    k_build_table2<<<NT / 16, 256, 0, stream>>>(means, betas, ne_proj_w, 0,
                                                ne_proj_b, 0, T, flag);
    k_edge_apply2<<<2000, 256, 0, stream>>>(srcs, dsts, ews, T, buf0, buf1, 1);
    k_ne_comb<<<512, 1024, 0, stream>>>(buf0, buf1, ne_comb_w, ne_comb_b, x, flag);

    for (int L = 0; L < 3; ++L) {
        // h = x @ l1w.T
        k_node_gemm<<<512, 1024, 0, stream>>>(x, lin1_w, L * H * H, 128, nullptr, buf0, 0, flag);
        hipMemsetAsync(buf1, 0, (size_t)NELEM * sizeof(float), stream);
        // fused filter table
        k_filter_table<<<NT / 16, 1024, 0, stream>>>(means, betas,
                                                     mlp_w0, L * H * NRBF, mlp_b0, L * H,
                                                     mlp_w1, L * H * H,    mlp_b1, L * H,
                                                     T, flag);
        // edge pass
        k_edge_apply2<<<2000, 256, 0, stream>>>(srcs, dsts, ews, T, buf0, buf1, 0);
        // fused: x += silu(a@l2w.T+b2)@lw.T + lb
        k_fused_lin<<<512, 1024, 0, stream>>>(buf1, lin2_w, L * H * H, lin2_b, L * H,
                                              lin_w, L * H * H, lin_b, L * H, x, flag);
    }

    k_store<<<gElem, 256, 0, stream>>>(x, d_out, flag);
}

// Round 15
// 499.030 us; speedup vs baseline: 2.5931x; 1.1951x over previous
//
#include <hip/hip_runtime.h>
#include <hip/hip_bf16.h>

#define NATOMS 10000
#define NEDGES 320000
#define H 128
#define NRBF 50
#define NELEM (NATOMS * H)
#define NT 4096

typedef unsigned short u16;
typedef unsigned int u32;

__device__ __forceinline__ float bfu(u16 u) { return __uint_as_float(((u32)u) << 16); }
__device__ __forceinline__ u16 bf16r(float v) {   // RNE
    u32 u = __float_as_uint(v);
    return (u16)((u + 0x7FFFu + ((u >> 16) & 1u)) >> 16);
}
__device__ __forceinline__ float ldf(const void* p, int i, int bf) {
    return bf ? bfu(((const u16*)p)[i]) : ((const float*)p)[i];
}
__device__ __forceinline__ float silu_f(float v) { return v / (1.f + __expf(-v)); }
__device__ __forceinline__ float cutoff_f(float w) {
    float c = 0.5f * (__cosf(w * 0.62831853072f) + 1.f);
    return (w < 5.f) ? c : 0.f;
}

// ---- dtype detect: means[49]==1.0 by construction.
__global__ void k_detect(const void* means, int* flag) {
    if (threadIdx.x == 0) {
        u32 w = ((const u32*)means)[24];
        *flag = ((w >> 16) == 0x3F80u) ? 1 : 0;
    }
}

// embed: x0 fp32 (for ne_comb) + bf16 mirror (for NE edge gather)
__global__ __launch_bounds__(256) void k_embed(const int* __restrict__ z, const void* emb,
                                               float* __restrict__ x0, u16* __restrict__ xh,
                                               const int* flagp) {
    int bf = *flagp;
    int i = blockIdx.x * 256 + threadIdx.x;
    if (i < NELEM) {
        int n = i >> 7, f = i & 127;
        float v = ldf(emb, z[n] * H + f, bf);
        x0[i] = v;
        xh[i] = bf16r(v);
    }
}

__global__ __launch_bounds__(256) void k_store(const float* __restrict__ x, void* out,
                                               const int* flagp) {
    int bf = *flagp;
    int i = blockIdx.x * 256 + threadIdx.x;
    if (i < NELEM) {
        float v = x[i];
        if (bf) ((u16*)out)[i] = bf16r(v);
        else    ((float*)out)[i] = v;
    }
}

// ---- staging helper (proven r10) ----
__device__ __forceinline__ void stage_weights(const void* W, int woff, int wstride,
                                              float* sW, int tid, int nthr, int bf) {
    if (bf) {
        const u32* W32 = (const u32*)W;
        for (int i = tid; i < (H * H) / 2; i += nthr) {
            int f2 = i >> 6, kk = i & 63;
            u32 wp = W32[((woff + f2 * wstride) >> 1) + kk];
            sW[f2 * 132 + 2 * kk]     = bfu((u16)(wp & 0xffffu));
            sW[f2 * 132 + 2 * kk + 1] = bfu((u16)(wp >> 16));
        }
    } else {
        const float2* Wf = (const float2*)W;
        for (int i = tid; i < (H * H) / 2; i += nthr) {
            int f2 = i >> 6, kk = i & 63;
            float2 v = Wf[((woff + f2 * wstride) >> 1) + kk];
            sW[f2 * 132 + 2 * kk]     = v.x;
            sW[f2 * 132 + 2 * kk + 1] = v.y;
        }
    }
}

__device__ __forceinline__ void dot2(const float* sW, const float* r0, const float* r1,
                                     int f, float& a0, float& a1) {
    #pragma unroll
    for (int k = 0; k < H; k += 4) {
        float4 w4 = *(const float4*)&sW[f * 132 + k];
        float4 i0 = *(const float4*)&r0[k];
        float4 i1 = *(const float4*)&r1[k];
        a0 = fmaf(w4.x, i0.x, a0); a0 = fmaf(w4.y, i0.y, a0);
        a0 = fmaf(w4.z, i0.z, a0); a0 = fmaf(w4.w, i0.w, a0);
        a1 = fmaf(w4.x, i1.x, a1); a1 = fmaf(w4.y, i1.y, a1);
        a1 = fmaf(w4.z, i1.z, a1); a1 = fmaf(w4.w, i1.w, a1);
    }
}

// ---- node GEMM (proven); mode 3 = write bf16 to out (h buffer) ----
__global__ __launch_bounds__(1024) void k_node_gemm(const float* __restrict__ in,
                                                    const void* W, int woff, int wstride,
                                                    const void* bias, void* __restrict__ out,
                                                    int mode, const int* flagp) {
    __shared__ __align__(16) float sW[H * 132];
    __shared__ __align__(16) float sIn[16][132];
    __shared__ float sB[H];
    int tid = threadIdx.x;
    int bf = *flagp;
    stage_weights(W, woff, wstride, sW, tid, 1024, bf);
    if (tid < H) sB[tid] = bias ? ldf(bias, tid, bf) : 0.f;
    __syncthreads();
    int g = tid >> 7, f = tid & 127;
    for (int base = blockIdx.x * 16; base < NATOMS; base += gridDim.x * 16) {
        int n0 = base + 2 * g, n1 = n0 + 1;
        sIn[2 * g][f] = in[n0 * H + f];
        sIn[2 * g + 1][f] = in[n1 * H + f];
        __syncthreads();
        float a0 = 0.f, a1 = 0.f;
        dot2(sW, sIn[2 * g], sIn[2 * g + 1], f, a0, a1);
        float v0 = a0 + sB[f], v1 = a1 + sB[f];
        if (mode == 1) { v0 = silu_f(v0); v1 = silu_f(v1); }
        if (mode == 3) {
            ((u16*)out)[n0 * H + f] = bf16r(v0);
            ((u16*)out)[n1 * H + f] = bf16r(v1);
        } else if (mode == 2) {
            ((float*)out)[n0 * H + f] += v0; ((float*)out)[n1 * H + f] += v1;
        } else {
            ((float*)out)[n0 * H + f] = v0;  ((float*)out)[n1 * H + f] = v1;
        }
        __syncthreads();
    }
}

// ---- FUSED lin2+lin (proven r14) ----
__global__ __launch_bounds__(1024) void k_fused_lin(const float* __restrict__ a,
                                                    const void* W2, int w2off,
                                                    const void* B2, int b2off,
                                                    const void* Wl, int wloff,
                                                    const void* Bl, int bloff,
                                                    float* __restrict__ x,
                                                    const int* flagp) {
    __shared__ __align__(16) float sW2[H * 132];
    __shared__ __align__(16) float sWl[H * 132];
    __shared__ __align__(16) float sIn[16][132];
    __shared__ float sB2[H], sBl[H];
    int tid = threadIdx.x;
    int bf = *flagp;
    stage_weights(W2, w2off, H, sW2, tid, 1024, bf);
    stage_weights(Wl, wloff, H, sWl, tid, 1024, bf);
    if (tid < H) { sB2[tid] = ldf(B2, b2off + tid, bf); sBl[tid] = ldf(Bl, bloff + tid, bf); }
    __syncthreads();
    int g = tid >> 7, f = tid & 127;
    for (int base = blockIdx.x * 16; base < NATOMS; base += gridDim.x * 16) {
        int n0 = base + 2 * g, n1 = n0 + 1;
        sIn[2 * g][f] = a[n0 * H + f];
        sIn[2 * g + 1][f] = a[n1 * H + f];
        __syncthreads();
        float a0 = 0.f, a1 = 0.f;
        dot2(sW2, sIn[2 * g], sIn[2 * g + 1], f, a0, a1);
        float t0 = silu_f(a0 + sB2[f]), t1 = silu_f(a1 + sB2[f]);
        __syncthreads();
        sIn[2 * g][f] = t0;
        sIn[2 * g + 1][f] = t1;
        __syncthreads();
        float c0 = 0.f, c1 = 0.f;
        dot2(sWl, sIn[2 * g], sIn[2 * g + 1], f, c0, c1);
        x[n0 * H + f] += c0 + sBl[f];
        x[n1 * H + f] += c1 + sBl[f];
        __syncthreads();
    }
}

// ---- FUSED NE combine (proven r14) ----
__global__ __launch_bounds__(1024) void k_ne_comb(const float* __restrict__ in0,
                                                  const float* __restrict__ in1,
                                                  const void* W, const void* B,
                                                  float* __restrict__ x,
                                                  const int* flagp) {
    __shared__ __align__(16) float sWa[H * 132];
    __shared__ __align__(16) float sWb[H * 132];
    __shared__ __align__(16) float sIn[16][132];
    __shared__ float sB[H];
    int tid = threadIdx.x;
    int bf = *flagp;
    stage_weights(W, 0,   256, sWa, tid, 1024, bf);
    stage_weights(W, 128, 256, sWb, tid, 1024, bf);
    if (tid < H) sB[tid] = ldf(B, tid, bf);
    __syncthreads();
    int g = tid >> 7, f = tid & 127;
    for (int base = blockIdx.x * 16; base < NATOMS; base += gridDim.x * 16) {
        int n0 = base + 2 * g, n1 = n0 + 1;
        sIn[2 * g][f] = in0[n0 * H + f];
        sIn[2 * g + 1][f] = in0[n1 * H + f];
        __syncthreads();
        float a0 = 0.f, a1 = 0.f;
        dot2(sWa, sIn[2 * g], sIn[2 * g + 1], f, a0, a1);
        __syncthreads();
        sIn[2 * g][f] = in1[n0 * H + f];
        sIn[2 * g + 1][f] = in1[n1 * H + f];
        __syncthreads();
        dot2(sWb, sIn[2 * g], sIn[2 * g + 1], f, a0, a1);
        x[n0 * H + f] = a0 + sB[f];
        x[n1 * H + f] = a1 + sB[f];
        __syncthreads();
    }
}

// ---- FUSED filter table (proven r13), now writes bf16 T ----
__global__ __launch_bounds__(1024) void k_filter_table(const void* means, const void* betas,
                                                       const void* W0, int w0off,
                                                       const void* B0, int b0off,
                                                       const void* W1, int w1off,
                                                       const void* B1, int b1off,
                                                       u16* __restrict__ T,
                                                       const int* flagp) {
    __shared__ __align__(16) float sW1[H * 132];
    __shared__ float sW0[H * 53];
    __shared__ __align__(16) float sIn[16][132];
    __shared__ float sR[16][56];
    __shared__ float sM[NRBF], sBe[NRBF];
    int tid = threadIdx.x;
    int bf = *flagp;
    stage_weights(W1, w1off, H, sW1, tid, 1024, bf);
    for (int i = tid; i < H * NRBF; i += 1024) {
        int f2 = i / NRBF, k = i - f2 * NRBF;
        sW0[f2 * 53 + k] = ldf(W0, w0off + i, bf);
    }
    if (tid < NRBF) { sM[tid] = ldf(means, tid, bf); sBe[tid] = ldf(betas, tid, bf); }
    __syncthreads();
    int g = tid >> 7, f = tid & 127;
    float b0r = ldf(B0, b0off + f, bf);
    float b1r = ldf(B1, b1off + f, bf);
    int base = blockIdx.x * 16;
    int n0 = base + 2 * g, n1 = n0 + 1;
    float wv0 = (float)n0 * (5.0f / (NT - 1));
    float wv1 = (float)n1 * (5.0f / (NT - 1));
    if (f < NRBF) {
        float t = expf(-wv0) - sM[f];
        sR[2 * g][f] = expf(-sBe[f] * t * t);
    } else if (f >= 64 && f < 64 + NRBF) {
        float t = expf(-wv1) - sM[f - 64];
        sR[2 * g + 1][f - 64] = expf(-sBe[f - 64] * t * t);
    }
    __syncthreads();
    float c0 = 0.5f * (cosf(wv0 * 0.62831853071795864f) + 1.f); if (!(wv0 < 5.f)) c0 = 0.f;
    float c1 = 0.5f * (cosf(wv1 * 0.62831853071795864f) + 1.f); if (!(wv1 < 5.f)) c1 = 0.f;
    float s0 = 0.f, s1 = 0.f;
    #pragma unroll
    for (int k = 0; k < NRBF; ++k) {
        float wk = sW0[f * 53 + k];
        s0 = fmaf(wk, sR[2 * g][k], s0);
        s1 = fmaf(wk, sR[2 * g + 1][k], s1);
    }
    sIn[2 * g][f] = silu_f(fmaf(c0, s0, b0r));
    sIn[2 * g + 1][f] = silu_f(fmaf(c1, s1, b0r));
    __syncthreads();
    float a0 = 0.f, a1 = 0.f;
    dot2(sW1, sIn[2 * g], sIn[2 * g + 1], f, a0, a1);
    T[n0 * H + f] = bf16r((a0 + b1r) * c0);
    T[n1 * H + f] = bf16r((a1 + b1r) * c1);
}

// ---- NE w-table build (proven r12), bf16 output ----
__global__ __launch_bounds__(256) void k_build_table2(const void* means, const void* betas,
                                                      const void* W, int woff,
                                                      const void* B, int boff,
                                                      u16* __restrict__ T,
                                                      const int* flagp) {
    __shared__ float sW[H * 53];
    __shared__ float sM[NRBF], sBe[NRBF];
    __shared__ float sR[2][56];
    int tid = threadIdx.x;
    int bf = *flagp;
    for (int i = tid; i < H * NRBF; i += 256) {
        int f2 = i / NRBF, k = i - f2 * NRBF;
        sW[f2 * 53 + k] = ldf(W, woff + i, bf);
    }
    if (tid < NRBF) { sM[tid] = ldf(means, tid, bf); sBe[tid] = ldf(betas, tid, bf); }
    __syncthreads();
    int g = tid >> 7, f = tid & 127;
    float bv = ldf(B, boff + f, bf);
    int base = blockIdx.x * 16;
    #pragma unroll 1
    for (int r = 0; r < 8; ++r) {
        int row = base + g * 8 + r;
        float w = (float)row * (5.0f / (NT - 1));
        if (f < NRBF) {
            float t = expf(-w) - sM[f];
            sR[g][f] = expf(-sBe[f] * t * t);
        }
        __syncthreads();
        float acc = 0.f;
        #pragma unroll
        for (int k = 0; k < NRBF; ++k)
            acc = fmaf(sW[f * 53 + k], sR[g][k], acc);
        float c = 0.5f * (cosf(w * 0.62831853071795864f) + 1.f);
        if (!(w < 5.f)) c = 0.f;
        T[row * H + f] = bf16r((c * acc + bv) * c);
        __syncthreads();
    }
}

// ---- counting sort by src (proven) ----
__global__ __launch_bounds__(256) void k_hist(const int* __restrict__ src, int* __restrict__ deg) {
    int e = blockIdx.x * 256 + threadIdx.x;
    if (e < NEDGES) atomicAdd(&deg[src[e]], 1);
}

__global__ __launch_bounds__(1024) void k_scan(const int* __restrict__ deg, int* __restrict__ rs) {
    __shared__ int buf[1024];
    __shared__ int carry;
    int tid = threadIdx.x;
    if (tid == 0) carry = 0;
    __syncthreads();
    for (int c = 0; c < 10; ++c) {
        int i = c * 1024 + tid;
        int v = (i < NATOMS) ? deg[i] : 0;
        buf[tid] = v;
        __syncthreads();
        for (int off = 1; off < 1024; off <<= 1) {
            int t = (tid >= off) ? buf[tid - off] : 0;
            __syncthreads();
            buf[tid] += t;
            __syncthreads();
        }
        int base = carry;
        if (i < NATOMS) rs[i] = base + buf[tid] - v;
        __syncthreads();
        if (tid == 0) carry = base + buf[1023];
        __syncthreads();
    }
}

__global__ __launch_bounds__(256) void k_scatter_perm(const int* __restrict__ src,
                                                      const int* __restrict__ dst,
                                                      const void* ew,
                                                      const int* __restrict__ rs,
                                                      int* __restrict__ cnt,
                                                      int* __restrict__ srcs,
                                                      int* __restrict__ dsts,
                                                      float* __restrict__ ews,
                                                      const int* flagp) {
    int e = blockIdx.x * 256 + threadIdx.x;
    if (e < NEDGES) {
        int s = src[e];
        int p = rs[s] + atomicAdd(&cnt[s], 1);
        srcs[p] = s;
        dsts[p] = dst[e];
        ews[p] = ldf(ew, e, *flagp);
    }
}

// ---- edge apply, sorted, one WAVE per edge, 4-EDGE ILP, bf16-packed T & h.
// Per lane: 3 u32 loads per edge (was 6x4B). Named scalars only; no LDS.
__global__ __launch_bounds__(256) void k_edge_apply3(const int* __restrict__ srcs,
                                                     const int* __restrict__ dsts,
                                                     const float* __restrict__ ews,
                                                     const u32* __restrict__ Tb,
                                                     const u32* __restrict__ vh,
                                                     float* __restrict__ acc,
                                                     int mask_self) {
    int tid = threadIdx.x;
    int g = tid >> 6;
    int lane = tid & 63;
    int gid = blockIdx.x * 4 + g;     // 8000 groups x 40 edges, 40%4==0
    int r0 = gid * 40;
    int cur = -1;
    float rx = 0.f, ry = 0.f;
    for (int e = r0; e < r0 + 40; e += 4) {
        int s0 = srcs[e],     d0 = dsts[e];
        int s1 = srcs[e + 1], d1 = dsts[e + 1];
        int s2 = srcs[e + 2], d2 = dsts[e + 2];
        int s3 = srcs[e + 3], d3 = dsts[e + 3];
        float u0 = ews[e]     * ((float)(NT - 1) / 5.0f);
        float u1 = ews[e + 1] * ((float)(NT - 1) / 5.0f);
        float u2 = ews[e + 2] * ((float)(NT - 1) / 5.0f);
        float u3 = ews[e + 3] * ((float)(NT - 1) / 5.0f);
        int ix0 = min((int)u0, NT - 2); float fr0 = u0 - (float)ix0;
        int ix1 = min((int)u1, NT - 2); float fr1 = u1 - (float)ix1;
        int ix2 = min((int)u2, NT - 2); float fr2 = u2 - (float)ix2;
        int ix3 = min((int)u3, NT - 2); float fr3 = u3 - (float)ix3;
        u32 ta0 = Tb[ix0 * 64 + lane], tb0 = Tb[ix0 * 64 + 64 + lane];
        u32 ta1 = Tb[ix1 * 64 + lane], tb1 = Tb[ix1 * 64 + 64 + lane];
        u32 ta2 = Tb[ix2 * 64 + lane], tb2 = Tb[ix2 * 64 + 64 + lane];
        u32 ta3 = Tb[ix3 * 64 + lane], tb3 = Tb[ix3 * 64 + 64 + lane];
        u32 h0 = vh[d0 * 64 + lane];
        u32 h1 = vh[d1 * 64 + lane];
        u32 h2 = vh[d2 * 64 + lane];
        u32 h3 = vh[d3 * 64 + lane];
        float vx0 = fmaf(fr0, bfu((u16)(tb0 & 0xffff)) - bfu((u16)(ta0 & 0xffff)), bfu((u16)(ta0 & 0xffff))) * bfu((u16)(h0 & 0xffff));
        float vy0 = fmaf(fr0, bfu((u16)(tb0 >> 16))    - bfu((u16)(ta0 >> 16)),    bfu((u16)(ta0 >> 16)))    * bfu((u16)(h0 >> 16));
        float vx1 = fmaf(fr1, bfu((u16)(tb1 & 0xffff)) - bfu((u16)(ta1 & 0xffff)), bfu((u16)(ta1 & 0xffff))) * bfu((u16)(h1 & 0xffff));
        float vy1 = fmaf(fr1, bfu((u16)(tb1 >> 16))    - bfu((u16)(ta1 >> 16)),    bfu((u16)(ta1 >> 16)))    * bfu((u16)(h1 >> 16));
        float vx2 = fmaf(fr2, bfu((u16)(tb2 & 0xffff)) - bfu((u16)(ta2 & 0xffff)), bfu((u16)(ta2 & 0xffff))) * bfu((u16)(h2 & 0xffff));
        float vy2 = fmaf(fr2, bfu((u16)(tb2 >> 16))    - bfu((u16)(ta2 >> 16)),    bfu((u16)(ta2 >> 16)))    * bfu((u16)(h2 >> 16));
        float vx3 = fmaf(fr3, bfu((u16)(tb3 & 0xffff)) - bfu((u16)(ta3 & 0xffff)), bfu((u16)(ta3 & 0xffff))) * bfu((u16)(h3 & 0xffff));
        float vy3 = fmaf(fr3, bfu((u16)(tb3 >> 16))    - bfu((u16)(ta3 >> 16)),    bfu((u16)(ta3 >> 16)))    * bfu((u16)(h3 >> 16));
        if (!(mask_self && s0 == d0)) {
            if (s0 != cur) {
                if (cur >= 0) { atomicAdd(&acc[cur * H + 2 * lane], rx); atomicAdd(&acc[cur * H + 2 * lane + 1], ry); }
                cur = s0; rx = 0.f; ry = 0.f;
            }
            rx += vx0; ry += vy0;
        }
        if (!(mask_self && s1 == d1)) {
            if (s1 != cur) {
                if (cur >= 0) { atomicAdd(&acc[cur * H + 2 * lane], rx); atomicAdd(&acc[cur * H + 2 * lane + 1], ry); }
                cur = s1; rx = 0.f; ry = 0.f;
            }
            rx += vx1; ry += vy1;
        }
        if (!(mask_self && s2 == d2)) {
            if (s2 != cur) {
                if (cur >= 0) { atomicAdd(&acc[cur * H + 2 * lane], rx); atomicAdd(&acc[cur * H + 2 * lane + 1], ry); }
                cur = s2; rx = 0.f; ry = 0.f;
            }
            rx += vx2; ry += vy2;
        }
        if (!(mask_self && s3 == d3)) {
            if (s3 != cur) {
                if (cur >= 0) { atomicAdd(&acc[cur * H + 2 * lane], rx); atomicAdd(&acc[cur * H + 2 * lane + 1], ry); }
                cur = s3; rx = 0.f; ry = 0.f;
            }
            rx += vx3; ry += vy3;
        }
    }
    if (cur >= 0) {
        atomicAdd(&acc[cur * H + 2 * lane], rx);
        atomicAdd(&acc[cur * H + 2 * lane + 1], ry);
    }
}

extern "C" void kernel_launch(void* const* d_in, const int* in_sizes, int n_in,
                              void* d_out, int out_size, void* d_ws, size_t ws_size,
                              hipStream_t stream) {
    const int* z  = (const int*)d_in[0];
    const int* ei = (const int*)d_in[1];
    const void* ew        = d_in[2];
    const void* emb       = d_in[3];
    const void* means     = d_in[4];
    const void* betas     = d_in[5];
    const void* ne_proj_w = d_in[6];
    const void* ne_proj_b = d_in[7];
    const void* ne_comb_w = d_in[8];
    const void* ne_comb_b = d_in[9];
    const void* mlp_w0    = d_in[10];
    const void* mlp_b0    = d_in[11];
    const void* mlp_w1    = d_in[12];
    const void* mlp_b1    = d_in[13];
    const void* lin1_w    = d_in[14];
    const void* lin2_w    = d_in[15];
    const void* lin2_b    = d_in[16];
    const void* lin_w     = d_in[17];
    const void* lin_b     = d_in[18];

    const int* srcp = ei;
    const int* dstp = ei + NEDGES;

    // layout ~22.9 MB (< proven 23.52 MB)
    float* buf0 = (float*)d_ws;            // x0 / a-scratch unused in layers
    float* buf1 = buf0 + NELEM;            // scatter accumulator
    float* x    = buf1 + NELEM;            // persistent fp32 node state
    int*   flag = (int*)(x + NELEM);
    int*   deg  = flag + 16;
    int*   cnt  = deg + 10240;
    int*   rs   = cnt + 10240;
    int*   srcs = rs + 10240;
    int*   dsts = srcs + NEDGES;
    float* ews  = (float*)(dsts + NEDGES);
    u16*   Tb   = (u16*)(ews + NEDGES);    // NT x 128 bf16 table (1 MB)
    u16*   hb   = Tb + NT * H;             // bf16 h / x0 mirror (2.56 MB)

    const int gElem = (NELEM + 255) / 256;
    const int gEdge = (NEDGES + 255) / 256;

    k_detect<<<1, 64, 0, stream>>>(means, flag);
    k_embed<<<gElem, 256, 0, stream>>>(z, emb, buf0, hb, flag);

    // counting sort by src
    hipMemsetAsync(deg, 0, 2 * 10240 * sizeof(int), stream);
    k_hist<<<gEdge, 256, 0, stream>>>(srcp, deg);
    k_scan<<<1, 1024, 0, stream>>>(deg, rs);
    k_scatter_perm<<<gEdge, 256, 0, stream>>>(srcp, dstp, ew, rs, cnt,
                                              srcs, dsts, ews, flag);

    // NeighborEmbedding
    hipMemsetAsync(buf1, 0, (size_t)NELEM * sizeof(float), stream);
    k_build_table2<<<NT / 16, 256, 0, stream>>>(means, betas, ne_proj_w, 0,
                                                ne_proj_b, 0, Tb, flag);
    k_edge_apply3<<<2000, 256, 0, stream>>>(srcs, dsts, ews, (const u32*)Tb,
                                            (const u32*)hb, buf1, 1);
    k_ne_comb<<<512, 1024, 0, stream>>>(buf0, buf1, ne_comb_w, ne_comb_b, x, flag);

    for (int L = 0; L < 3; ++L) {
        // h = x @ l1w.T  (bf16 output, only consumed by edge gather)
        k_node_gemm<<<512, 1024, 0, stream>>>(x, lin1_w, L * H * H, 128, nullptr, hb, 3, flag);
        hipMemsetAsync(buf1, 0, (size_t)NELEM * sizeof(float), stream);
        k_filter_table<<<NT / 16, 1024, 0, stream>>>(means, betas,
                                                     mlp_w0, L * H * NRBF, mlp_b0, L * H,
                                                     mlp_w1, L * H * H,    mlp_b1, L * H,
                                                     Tb, flag);
        k_edge_apply3<<<2000, 256, 0, stream>>>(srcs, dsts, ews, (const u32*)Tb,
                                                (const u32*)hb, buf1, 0);
        // x += silu(a@l2w.T+b2)@lw.T + lb
        k_fused_lin<<<512, 1024, 0, stream>>>(buf1, lin2_w, L * H * H, lin2_b, L * H,
                                              lin_w, L * H * H, lin_b, L * H, x, flag);
    }

    k_store<<<gElem, 256, 0, stream>>>(x, d_out, flag);
}

// Round 16
// 435.013 us; speedup vs baseline: 2.9747x; 1.1472x over previous
//
#include <hip/hip_runtime.h>
#include <hip/hip_bf16.h>

#define NATOMS 10000
#define NEDGES 320000
#define H 128
#define NRBF 50
#define NELEM (NATOMS * H)
#define NT 4096

typedef unsigned short u16;
typedef unsigned int u32;
typedef __attribute__((ext_vector_type(8))) short short8;
typedef __attribute__((ext_vector_type(4))) float float4v;

__device__ __forceinline__ float bfu(u16 u) { return __uint_as_float(((u32)u) << 16); }
__device__ __forceinline__ u16 bf16r(float v) {   // RNE
    u32 u = __float_as_uint(v);
    return (u16)((u + 0x7FFFu + ((u >> 16) & 1u)) >> 16);
}
__device__ __forceinline__ float ldf(const void* p, int i, int bf) {
    return bf ? bfu(((const u16*)p)[i]) : ((const float*)p)[i];
}
__device__ __forceinline__ float silu_f(float v) { return v / (1.f + __expf(-v)); }

// ---- dtype detect: means[49]==1.0 by construction.
__global__ void k_detect(const void* means, int* flag) {
    if (threadIdx.x == 0) {
        u32 w = ((const u32*)means)[24];
        *flag = ((w >> 16) == 0x3F80u) ? 1 : 0;
    }
}

// embed: x0 fp32 (for ne_comb) + bf16 mirror (for NE edge gather)
__global__ __launch_bounds__(256) void k_embed(const int* __restrict__ z, const void* emb,
                                               float* __restrict__ x0, u16* __restrict__ xh,
                                               const int* flagp) {
    int bf = *flagp;
    int i = blockIdx.x * 256 + threadIdx.x;
    if (i < NELEM) {
        int n = i >> 7, f = i & 127;
        float v = ldf(emb, z[n] * H + f, bf);
        x0[i] = v;
        xh[i] = bf16r(v);
    }
}

__global__ __launch_bounds__(256) void k_store(const float* __restrict__ x, void* out,
                                               const int* flagp) {
    int bf = *flagp;
    int i = blockIdx.x * 256 + threadIdx.x;
    if (i < NELEM) {
        float v = x[i];
        if (bf) ((u16*)out)[i] = bf16r(v);
        else    ((float*)out)[i] = v;
    }
}

// ---- fp32 staging (for k_ne_comb, proven) ----
__device__ __forceinline__ void stage_weights(const void* W, int woff, int wstride,
                                              float* sW, int tid, int nthr, int bf) {
    if (bf) {
        const u32* W32 = (const u32*)W;
        for (int i = tid; i < (H * H) / 2; i += nthr) {
            int f2 = i >> 6, kk = i & 63;
            u32 wp = W32[((woff + f2 * wstride) >> 1) + kk];
            sW[f2 * 132 + 2 * kk]     = bfu((u16)(wp & 0xffffu));
            sW[f2 * 132 + 2 * kk + 1] = bfu((u16)(wp >> 16));
        }
    } else {
        const float2* Wf = (const float2*)W;
        for (int i = tid; i < (H * H) / 2; i += nthr) {
            int f2 = i >> 6, kk = i & 63;
            float2 v = Wf[((woff + f2 * wstride) >> 1) + kk];
            sW[f2 * 132 + 2 * kk]     = v.x;
            sW[f2 * 132 + 2 * kk + 1] = v.y;
        }
    }
}

__device__ __forceinline__ void dot2(const float* sW, const float* r0, const float* r1,
                                     int f, float& a0, float& a1) {
    #pragma unroll
    for (int k = 0; k < H; k += 4) {
        float4 w4 = *(const float4*)&sW[f * 132 + k];
        float4 i0 = *(const float4*)&r0[k];
        float4 i1 = *(const float4*)&r1[k];
        a0 = fmaf(w4.x, i0.x, a0); a0 = fmaf(w4.y, i0.y, a0);
        a0 = fmaf(w4.z, i0.z, a0); a0 = fmaf(w4.w, i0.w, a0);
        a1 = fmaf(w4.x, i1.x, a1); a1 = fmaf(w4.y, i1.y, a1);
        a1 = fmaf(w4.z, i1.z, a1); a1 = fmaf(w4.w, i1.w, a1);
    }
}

// ---- bf16 LDS weight staging for MFMA: row stride 136 u16 (68 u32) ----
__device__ __forceinline__ void stage_w16(const void* W, int woff, u16* sW, int tid, int bf) {
    u32* sW32 = (u32*)sW;
    if (bf) {
        const u32* W32 = (const u32*)W;
        for (int i = tid; i < 128 * 64; i += 256) {
            int f2 = i >> 6, kk = i & 63;
            sW32[f2 * 68 + kk] = W32[((woff + f2 * H) >> 1) + kk];
        }
    } else {
        const float2* Wf = (const float2*)W;
        for (int i = tid; i < 128 * 64; i += 256) {
            int f2 = i >> 6, kk = i & 63;
            float2 v = Wf[((woff + f2 * H) >> 1) + kk];
            sW32[f2 * 68 + kk] = (u32)bf16r(v.x) | ((u32)bf16r(v.y) << 16);
        }
    }
}

// ---- MFMA node GEMM. mode 0: hb = bf16(in @ W2.T) (lin1, no bias)
//      mode 1: x += silu(in @ W2.T + b2) @ Wl.T + bl   (fused lin2+lin)
// Layouts (verified m89/m91/m120): A[m=lane&15][k=quad*8+j]; B same with n=lane&15;
// C/D row=quad*4+reg, col=lane&15. One wave per 16-atom tile; no barriers in loop.
__global__ __launch_bounds__(256) void k_mfma_lin(const float* __restrict__ in,
                                                  const void* W2, int w2off,
                                                  const void* B2, int b2off,
                                                  const void* Wl, int wloff,
                                                  const void* Bl, int bloff,
                                                  float* __restrict__ x,
                                                  u16* __restrict__ hb,
                                                  int mode, const int* flagp) {
    __shared__ u16 sW2[128 * 136];
    __shared__ u16 sWl[128 * 136];
    __shared__ u16 sA[4][16 * 136];
    __shared__ float sB2v[128], sBlv[128];
    int tid = threadIdx.x;
    int bf = *flagp;
    stage_w16(W2, w2off, sW2, tid, bf);
    if (mode == 1) stage_w16(Wl, wloff, sWl, tid, bf);
    if (tid < 128) {
        sB2v[tid] = B2 ? ldf(B2, b2off + tid, bf) : 0.f;
        sBlv[tid] = (mode == 1) ? ldf(Bl, bloff + tid, bf) : 0.f;
    }
    __syncthreads();
    int w = tid >> 6, lane = tid & 63;
    int quad = lane >> 4, l16 = lane & 15;
    u16* myA = sA[w];
    u32* myA32 = (u32*)myA;
    for (int tile = blockIdx.x * 4 + w; tile < NATOMS / 16; tile += gridDim.x * 4) {
        int abase = tile * 16;
        // stage 16x128 fp32 -> bf16 wave-private LDS (row stride 136)
        const float2* in2 = (const float2*)in + (size_t)abase * 64;
        #pragma unroll 4
        for (int j = 0; j < 16; ++j) {
            float2 v = in2[j * 64 + lane];
            myA32[j * 68 + lane] = (u32)bf16r(v.x) | ((u32)bf16r(v.y) << 16);
        }
        __asm__ volatile("s_waitcnt lgkmcnt(0)" ::: "memory");
        short8 af0 = *(const short8*)&myA[l16 * 136 +   0 + quad * 8];
        short8 af1 = *(const short8*)&myA[l16 * 136 +  32 + quad * 8];
        short8 af2 = *(const short8*)&myA[l16 * 136 +  64 + quad * 8];
        short8 af3 = *(const short8*)&myA[l16 * 136 +  96 + quad * 8];
        #pragma unroll 1
        for (int nt = 0; nt < 8; ++nt) {
            const u16* wrow = &sW2[(nt * 16 + l16) * 136];
            short8 b0 = *(const short8*)&wrow[0  + quad * 8];
            short8 b1 = *(const short8*)&wrow[32 + quad * 8];
            short8 b2 = *(const short8*)&wrow[64 + quad * 8];
            short8 b3 = *(const short8*)&wrow[96 + quad * 8];
            float4v acc = {0.f, 0.f, 0.f, 0.f};
            acc = __builtin_amdgcn_mfma_f32_16x16x32_bf16(af0, b0, acc, 0, 0, 0);
            acc = __builtin_amdgcn_mfma_f32_16x16x32_bf16(af1, b1, acc, 0, 0, 0);
            acc = __builtin_amdgcn_mfma_f32_16x16x32_bf16(af2, b2, acc, 0, 0, 0);
            acc = __builtin_amdgcn_mfma_f32_16x16x32_bf16(af3, b3, acc, 0, 0, 0);
            int col = nt * 16 + l16;
            float bias = sB2v[col];
            if (mode == 0) {
                hb[(size_t)(abase + quad * 4 + 0) * H + col] = bf16r(acc[0] + bias);
                hb[(size_t)(abase + quad * 4 + 1) * H + col] = bf16r(acc[1] + bias);
                hb[(size_t)(abase + quad * 4 + 2) * H + col] = bf16r(acc[2] + bias);
                hb[(size_t)(abase + quad * 4 + 3) * H + col] = bf16r(acc[3] + bias);
            } else {
                myA[(quad * 4 + 0) * 136 + col] = bf16r(silu_f(acc[0] + bias));
                myA[(quad * 4 + 1) * 136 + col] = bf16r(silu_f(acc[1] + bias));
                myA[(quad * 4 + 2) * 136 + col] = bf16r(silu_f(acc[2] + bias));
                myA[(quad * 4 + 3) * 136 + col] = bf16r(silu_f(acc[3] + bias));
            }
        }
        if (mode == 1) {
            __asm__ volatile("s_waitcnt lgkmcnt(0)" ::: "memory");
            short8 t0 = *(const short8*)&myA[l16 * 136 +   0 + quad * 8];
            short8 t1 = *(const short8*)&myA[l16 * 136 +  32 + quad * 8];
            short8 t2 = *(const short8*)&myA[l16 * 136 +  64 + quad * 8];
            short8 t3 = *(const short8*)&myA[l16 * 136 +  96 + quad * 8];
            #pragma unroll 1
            for (int nt = 0; nt < 8; ++nt) {
                const u16* wrow = &sWl[(nt * 16 + l16) * 136];
                short8 b0 = *(const short8*)&wrow[0  + quad * 8];
                short8 b1 = *(const short8*)&wrow[32 + quad * 8];
                short8 b2 = *(const short8*)&wrow[64 + quad * 8];
                short8 b3 = *(const short8*)&wrow[96 + quad * 8];
                int col = nt * 16 + l16;
                float bias = sBlv[col];
                float4v acc;
                acc[0] = x[(size_t)(abase + quad * 4 + 0) * H + col] + bias;
                acc[1] = x[(size_t)(abase + quad * 4 + 1) * H + col] + bias;
                acc[2] = x[(size_t)(abase + quad * 4 + 2) * H + col] + bias;
                acc[3] = x[(size_t)(abase + quad * 4 + 3) * H + col] + bias;
                acc = __builtin_amdgcn_mfma_f32_16x16x32_bf16(t0, b0, acc, 0, 0, 0);
                acc = __builtin_amdgcn_mfma_f32_16x16x32_bf16(t1, b1, acc, 0, 0, 0);
                acc = __builtin_amdgcn_mfma_f32_16x16x32_bf16(t2, b2, acc, 0, 0, 0);
                acc = __builtin_amdgcn_mfma_f32_16x16x32_bf16(t3, b3, acc, 0, 0, 0);
                x[(size_t)(abase + quad * 4 + 0) * H + col] = acc[0];
                x[(size_t)(abase + quad * 4 + 1) * H + col] = acc[1];
                x[(size_t)(abase + quad * 4 + 2) * H + col] = acc[2];
                x[(size_t)(abase + quad * 4 + 3) * H + col] = acc[3];
            }
        }
    }
}

// ---- FUSED NE combine (proven r14, VALU) ----
__global__ __launch_bounds__(1024) void k_ne_comb(const float* __restrict__ in0,
                                                  const float* __restrict__ in1,
                                                  const void* W, const void* B,
                                                  float* __restrict__ x,
                                                  const int* flagp) {
    __shared__ __align__(16) float sWa[H * 132];
    __shared__ __align__(16) float sWb[H * 132];
    __shared__ __align__(16) float sIn[16][132];
    __shared__ float sB[H];
    int tid = threadIdx.x;
    int bf = *flagp;
    stage_weights(W, 0,   256, sWa, tid, 1024, bf);
    stage_weights(W, 128, 256, sWb, tid, 1024, bf);
    if (tid < H) sB[tid] = ldf(B, tid, bf);
    __syncthreads();
    int g = tid >> 7, f = tid & 127;
    for (int base = blockIdx.x * 16; base < NATOMS; base += gridDim.x * 16) {
        int n0 = base + 2 * g, n1 = n0 + 1;
        sIn[2 * g][f] = in0[n0 * H + f];
        sIn[2 * g + 1][f] = in0[n1 * H + f];
        __syncthreads();
        float a0 = 0.f, a1 = 0.f;
        dot2(sWa, sIn[2 * g], sIn[2 * g + 1], f, a0, a1);
        __syncthreads();
        sIn[2 * g][f] = in1[n0 * H + f];
        sIn[2 * g + 1][f] = in1[n1 * H + f];
        __syncthreads();
        dot2(sWb, sIn[2 * g], sIn[2 * g + 1], f, a0, a1);
        x[n0 * H + f] = a0 + sB[f];
        x[n1 * H + f] = a1 + sB[f];
        __syncthreads();
    }
}

// ---- FUSED filter table (proven r13/r15), bf16 T ----
__global__ __launch_bounds__(1024) void k_filter_table(const void* means, const void* betas,
                                                       const void* W0, int w0off,
                                                       const void* B0, int b0off,
                                                       const void* W1, int w1off,
                                                       const void* B1, int b1off,
                                                       u16* __restrict__ T,
                                                       const int* flagp) {
    __shared__ __align__(16) float sW1[H * 132];
    __shared__ float sW0[H * 53];
    __shared__ __align__(16) float sIn[16][132];
    __shared__ float sR[16][56];
    __shared__ float sM[NRBF], sBe[NRBF];
    int tid = threadIdx.x;
    int bf = *flagp;
    stage_weights(W1, w1off, H, sW1, tid, 1024, bf);
    for (int i = tid; i < H * NRBF; i += 1024) {
        int f2 = i / NRBF, k = i - f2 * NRBF;
        sW0[f2 * 53 + k] = ldf(W0, w0off + i, bf);
    }
    if (tid < NRBF) { sM[tid] = ldf(means, tid, bf); sBe[tid] = ldf(betas, tid, bf); }
    __syncthreads();
    int g = tid >> 7, f = tid & 127;
    float b0r = ldf(B0, b0off + f, bf);
    float b1r = ldf(B1, b1off + f, bf);
    int base = blockIdx.x * 16;
    int n0 = base + 2 * g, n1 = n0 + 1;
    float wv0 = (float)n0 * (5.0f / (NT - 1));
    float wv1 = (float)n1 * (5.0f / (NT - 1));
    if (f < NRBF) {
        float t = expf(-wv0) - sM[f];
        sR[2 * g][f] = expf(-sBe[f] * t * t);
    } else if (f >= 64 && f < 64 + NRBF) {
        float t = expf(-wv1) - sM[f - 64];
        sR[2 * g + 1][f - 64] = expf(-sBe[f - 64] * t * t);
    }
    __syncthreads();
    float c0 = 0.5f * (cosf(wv0 * 0.62831853071795864f) + 1.f); if (!(wv0 < 5.f)) c0 = 0.f;
    float c1 = 0.5f * (cosf(wv1 * 0.62831853071795864f) + 1.f); if (!(wv1 < 5.f)) c1 = 0.f;
    float s0 = 0.f, s1 = 0.f;
    #pragma unroll
    for (int k = 0; k < NRBF; ++k) {
        float wk = sW0[f * 53 + k];
        s0 = fmaf(wk, sR[2 * g][k], s0);
        s1 = fmaf(wk, sR[2 * g + 1][k], s1);
    }
    sIn[2 * g][f] = silu_f(fmaf(c0, s0, b0r));
    sIn[2 * g + 1][f] = silu_f(fmaf(c1, s1, b0r));
    __syncthreads();
    float a0 = 0.f, a1 = 0.f;
    dot2(sW1, sIn[2 * g], sIn[2 * g + 1], f, a0, a1);
    T[n0 * H + f] = bf16r((a0 + b1r) * c0);
    T[n1 * H + f] = bf16r((a1 + b1r) * c1);
}

// ---- NE w-table build (proven r12), bf16 output ----
__global__ __launch_bounds__(256) void k_build_table2(const void* means, const void* betas,
                                                      const void* W, int woff,
                                                      const void* B, int boff,
                                                      u16* __restrict__ T,
                                                      const int* flagp) {
    __shared__ float sW[H * 53];
    __shared__ float sM[NRBF], sBe[NRBF];
    __shared__ float sR[2][56];
    int tid = threadIdx.x;
    int bf = *flagp;
    for (int i = tid; i < H * NRBF; i += 256) {
        int f2 = i / NRBF, k = i - f2 * NRBF;
        sW[f2 * 53 + k] = ldf(W, woff + i, bf);
    }
    if (tid < NRBF) { sM[tid] = ldf(means, tid, bf); sBe[tid] = ldf(betas, tid, bf); }
    __syncthreads();
    int g = tid >> 7, f = tid & 127;
    float bv = ldf(B, boff + f, bf);
    int base = blockIdx.x * 16;
    #pragma unroll 1
    for (int r = 0; r < 8; ++r) {
        int row = base + g * 8 + r;
        float w = (float)row * (5.0f / (NT - 1));
        if (f < NRBF) {
            float t = expf(-w) - sM[f];
            sR[g][f] = expf(-sBe[f] * t * t);
        }
        __syncthreads();
        float acc = 0.f;
        #pragma unroll
        for (int k = 0; k < NRBF; ++k)
            acc = fmaf(sW[f * 53 + k], sR[g][k], acc);
        float c = 0.5f * (cosf(w * 0.62831853071795864f) + 1.f);
        if (!(w < 5.f)) c = 0.f;
        T[row * H + f] = bf16r((c * acc + bv) * c);
        __syncthreads();
    }
}

// ---- counting sort by src (proven) ----
__global__ __launch_bounds__(256) void k_hist(const int* __restrict__ src, int* __restrict__ deg) {
    int e = blockIdx.x * 256 + threadIdx.x;
    if (e < NEDGES) atomicAdd(&deg[src[e]], 1);
}

__global__ __launch_bounds__(1024) void k_scan(const int* __restrict__ deg, int* __restrict__ rs) {
    __shared__ int buf[1024];
    __shared__ int carry;
    int tid = threadIdx.x;
    if (tid == 0) carry = 0;
    __syncthreads();
    for (int c = 0; c < 10; ++c) {
        int i = c * 1024 + tid;
        int v = (i < NATOMS) ? deg[i] : 0;
        buf[tid] = v;
        __syncthreads();
        for (int off = 1; off < 1024; off <<= 1) {
            int t = (tid >= off) ? buf[tid - off] : 0;
            __syncthreads();
            buf[tid] += t;
            __syncthreads();
        }
        int base = carry;
        if (i < NATOMS) rs[i] = base + buf[tid] - v;
        __syncthreads();
        if (tid == 0) carry = base + buf[1023];
        __syncthreads();
    }
}

__global__ __launch_bounds__(256) void k_scatter_perm(const int* __restrict__ src,
                                                      const int* __restrict__ dst,
                                                      const void* ew,
                                                      const int* __restrict__ rs,
                                                      int* __restrict__ cnt,
                                                      int* __restrict__ srcs,
                                                      int* __restrict__ dsts,
                                                      float* __restrict__ ews,
                                                      const int* flagp) {
    int e = blockIdx.x * 256 + threadIdx.x;
    if (e < NEDGES) {
        int s = src[e];
        int p = rs[s] + atomicAdd(&cnt[s], 1);
        srcs[p] = s;
        dsts[p] = dst[e];
        ews[p] = ldf(ew, e, *flagp);
    }
}

// ---- edge apply (proven r15): sorted, wave/edge, 4-edge ILP, bf16 T & h ----
__global__ __launch_bounds__(256) void k_edge_apply3(const int* __restrict__ srcs,
                                                     const int* __restrict__ dsts,
                                                     const float* __restrict__ ews,
                                                     const u32* __restrict__ Tb,
                                                     const u32* __restrict__ vh,
                                                     float* __restrict__ acc,
                                                     int mask_self) {
    int tid = threadIdx.x;
    int g = tid >> 6;
    int lane = tid & 63;
    int gid = blockIdx.x * 4 + g;
    int r0 = gid * 40;
    int cur = -1;
    float rx = 0.f, ry = 0.f;
    for (int e = r0; e < r0 + 40; e += 4) {
        int s0 = srcs[e],     d0 = dsts[e];
        int s1 = srcs[e + 1], d1 = dsts[e + 1];
        int s2 = srcs[e + 2], d2 = dsts[e + 2];
        int s3 = srcs[e + 3], d3 = dsts[e + 3];
        float u0 = ews[e]     * ((float)(NT - 1) / 5.0f);
        float u1 = ews[e + 1] * ((float)(NT - 1) / 5.0f);
        float u2 = ews[e + 2] * ((float)(NT - 1) / 5.0f);
        float u3 = ews[e + 3] * ((float)(NT - 1) / 5.0f);
        int ix0 = min((int)u0, NT - 2); float fr0 = u0 - (float)ix0;
        int ix1 = min((int)u1, NT - 2); float fr1 = u1 - (float)ix1;
        int ix2 = min((int)u2, NT - 2); float fr2 = u2 - (float)ix2;
        int ix3 = min((int)u3, NT - 2); float fr3 = u3 - (float)ix3;
        u32 ta0 = Tb[ix0 * 64 + lane], tb0 = Tb[ix0 * 64 + 64 + lane];
        u32 ta1 = Tb[ix1 * 64 + lane], tb1 = Tb[ix1 * 64 + 64 + lane];
        u32 ta2 = Tb[ix2 * 64 + lane], tb2 = Tb[ix2 * 64 + 64 + lane];
        u32 ta3 = Tb[ix3 * 64 + lane], tb3 = Tb[ix3 * 64 + 64 + lane];
        u32 h0 = vh[d0 * 64 + lane];
        u32 h1 = vh[d1 * 64 + lane];
        u32 h2 = vh[d2 * 64 + lane];
        u32 h3 = vh[d3 * 64 + lane];
        float vx0 = fmaf(fr0, bfu((u16)(tb0 & 0xffff)) - bfu((u16)(ta0 & 0xffff)), bfu((u16)(ta0 & 0xffff))) * bfu((u16)(h0 & 0xffff));
        float vy0 = fmaf(fr0, bfu((u16)(tb0 >> 16))    - bfu((u16)(ta0 >> 16)),    bfu((u16)(ta0 >> 16)))    * bfu((u16)(h0 >> 16));
        float vx1 = fmaf(fr1, bfu((u16)(tb1 & 0xffff)) - bfu((u16)(ta1 & 0xffff)), bfu((u16)(ta1 & 0xffff))) * bfu((u16)(h1 & 0xffff));
        float vy1 = fmaf(fr1, bfu((u16)(tb1 >> 16))    - bfu((u16)(ta1 >> 16)),    bfu((u16)(ta1 >> 16)))    * bfu((u16)(h1 >> 16));
        float vx2 = fmaf(fr2, bfu((u16)(tb2 & 0xffff)) - bfu((u16)(ta2 & 0xffff)), bfu((u16)(ta2 & 0xffff))) * bfu((u16)(h2 & 0xffff));
        float vy2 = fmaf(fr2, bfu((u16)(tb2 >> 16))    - bfu((u16)(ta2 >> 16)),    bfu((u16)(ta2 >> 16)))    * bfu((u16)(h2 >> 16));
        float vx3 = fmaf(fr3, bfu((u16)(tb3 & 0xffff)) - bfu((u16)(ta3 & 0xffff)), bfu((u16)(ta3 & 0xffff))) * bfu((u16)(h3 & 0xffff));
        float vy3 = fmaf(fr3, bfu((u16)(tb3 >> 16))    - bfu((u16)(ta3 >> 16)),    bfu((u16)(ta3 >> 16)))    * bfu((u16)(h3 >> 16));
        if (!(mask_self && s0 == d0)) {
            if (s0 != cur) {
                if (cur >= 0) { atomicAdd(&acc[cur * H + 2 * lane], rx); atomicAdd(&acc[cur * H + 2 * lane + 1], ry); }
                cur = s0; rx = 0.f; ry = 0.f;
            }
            rx += vx0; ry += vy0;
        }
        if (!(mask_self && s1 == d1)) {
            if (s1 != cur) {
                if (cur >= 0) { atomicAdd(&acc[cur * H + 2 * lane], rx); atomicAdd(&acc[cur * H + 2 * lane + 1], ry); }
                cur = s1; rx = 0.f; ry = 0.f;
            }
            rx += vx1; ry += vy1;
        }
        if (!(mask_self && s2 == d2)) {
            if (s2 != cur) {
                if (cur >= 0) { atomicAdd(&acc[cur * H + 2 * lane], rx); atomicAdd(&acc[cur * H + 2 * lane + 1], ry); }
                cur = s2; rx = 0.f; ry = 0.f;
            }
            rx += vx2; ry += vy2;
        }
        if (!(mask_self && s3 == d3)) {
            if (s3 != cur) {
                if (cur >= 0) { atomicAdd(&acc[cur * H + 2 * lane], rx); atomicAdd(&acc[cur * H + 2 * lane + 1], ry); }
                cur = s3; rx = 0.f; ry = 0.f;
            }
            rx += vx3; ry += vy3;
        }
    }
    if (cur >= 0) {
        atomicAdd(&acc[cur * H + 2 * lane], rx);
        atomicAdd(&acc[cur * H + 2 * lane + 1], ry);
    }
}

extern "C" void kernel_launch(void* const* d_in, const int* in_sizes, int n_in,
                              void* d_out, int out_size, void* d_ws, size_t ws_size,
                              hipStream_t stream) {
    const int* z  = (const int*)d_in[0];
    const int* ei = (const int*)d_in[1];
    const void* ew        = d_in[2];
    const void* emb       = d_in[3];
    const void* means     = d_in[4];
    const void* betas     = d_in[5];
    const void* ne_proj_w = d_in[6];
    const void* ne_proj_b = d_in[7];
    const void* ne_comb_w = d_in[8];
    const void* ne_comb_b = d_in[9];
    const void* mlp_w0    = d_in[10];
    const void* mlp_b0    = d_in[11];
    const void* mlp_w1    = d_in[12];
    const void* mlp_b1    = d_in[13];
    const void* lin1_w    = d_in[14];
    const void* lin2_w    = d_in[15];
    const void* lin2_b    = d_in[16];
    const void* lin_w     = d_in[17];
    const void* lin_b     = d_in[18];

    const int* srcp = ei;
    const int* dstp = ei + NEDGES;

    float* buf0 = (float*)d_ws;            // x0
    float* buf1 = buf0 + NELEM;            // scatter accumulator
    float* x    = buf1 + NELEM;            // persistent fp32 node state
    int*   flag = (int*)(x + NELEM);
    int*   deg  = flag + 16;
    int*   cnt  = deg + 10240;
    int*   rs   = cnt + 10240;
    int*   srcs = rs + 10240;
    int*   dsts = srcs + NEDGES;
    float* ews  = (float*)(dsts + NEDGES);
    u16*   Tb   = (u16*)(ews + NEDGES);    // NT x 128 bf16 table
    u16*   hb   = Tb + NT * H;             // bf16 h / x0 mirror

    const int gElem = (NELEM + 255) / 256;
    const int gEdge = (NEDGES + 255) / 256;

    k_detect<<<1, 64, 0, stream>>>(means, flag);
    k_embed<<<gElem, 256, 0, stream>>>(z, emb, buf0, hb, flag);

    // counting sort by src
    hipMemsetAsync(deg, 0, 2 * 10240 * sizeof(int), stream);
    k_hist<<<gEdge, 256, 0, stream>>>(srcp, deg);
    k_scan<<<1, 1024, 0, stream>>>(deg, rs);
    k_scatter_perm<<<gEdge, 256, 0, stream>>>(srcp, dstp, ew, rs, cnt,
                                              srcs, dsts, ews, flag);

    // NeighborEmbedding
    hipMemsetAsync(buf1, 0, (size_t)NELEM * sizeof(float), stream);
    k_build_table2<<<NT / 16, 256, 0, stream>>>(means, betas, ne_proj_w, 0,
                                                ne_proj_b, 0, Tb, flag);
    k_edge_apply3<<<2000, 256, 0, stream>>>(srcs, dsts, ews, (const u32*)Tb,
                                            (const u32*)hb, buf1, 1);
    k_ne_comb<<<512, 1024, 0, stream>>>(buf0, buf1, ne_comb_w, ne_comb_b, x, flag);

    for (int L = 0; L < 3; ++L) {
        // h = bf16(x @ l1w.T)  — MFMA mode 0
        k_mfma_lin<<<157, 256, 0, stream>>>(x, lin1_w, L * H * H, nullptr, 0,
                                            nullptr, 0, nullptr, 0, x, hb, 0, flag);
        hipMemsetAsync(buf1, 0, (size_t)NELEM * sizeof(float), stream);
        k_filter_table<<<NT / 16, 1024, 0, stream>>>(means, betas,
                                                     mlp_w0, L * H * NRBF, mlp_b0, L * H,
                                                     mlp_w1, L * H * H,    mlp_b1, L * H,
                                                     Tb, flag);
        k_edge_apply3<<<2000, 256, 0, stream>>>(srcs, dsts, ews, (const u32*)Tb,
                                                (const u32*)hb, buf1, 0);
        // x += silu(a@l2w.T+b2)@lw.T + lb — MFMA mode 1
        k_mfma_lin<<<157, 256, 0, stream>>>(buf1, lin2_w, L * H * H, lin2_b, L * H,
                                            lin_w, L * H * H, lin_b, L * H, x, hb, 1, flag);
    }

    k_store<<<gElem, 256, 0, stream>>>(x, d_out, flag);
}

// Round 17
// 429.354 us; speedup vs baseline: 3.0139x; 1.0132x over previous
//
#include <hip/hip_runtime.h>
#include <hip/hip_bf16.h>

#define NATOMS 10000
#define NEDGES 320000
#define H 128
#define NRBF 50
#define NELEM (NATOMS * H)
#define NT 4096

typedef unsigned short u16;
typedef unsigned int u32;
typedef __attribute__((ext_vector_type(8))) short short8;
typedef __attribute__((ext_vector_type(4))) float float4v;

__device__ __forceinline__ float bfu(u16 u) { return __uint_as_float(((u32)u) << 16); }
__device__ __forceinline__ u16 bf16r(float v) {   // RNE
    u32 u = __float_as_uint(v);
    return (u16)((u + 0x7FFFu + ((u >> 16) & 1u)) >> 16);
}
__device__ __forceinline__ float ldf(const void* p, int i, int bf) {
    return bf ? bfu(((const u16*)p)[i]) : ((const float*)p)[i];
}
__device__ __forceinline__ float silu_f(float v) { return v / (1.f + __expf(-v)); }

// ---- dtype detect: means[49]==1.0 by construction.
__global__ void k_detect(const void* means, int* flag) {
    if (threadIdx.x == 0) {
        u32 w = ((const u32*)means)[24];
        *flag = ((w >> 16) == 0x3F80u) ? 1 : 0;
    }
}

// embed: x0 fp32 + bf16 mirror
__global__ __launch_bounds__(256) void k_embed(const int* __restrict__ z, const void* emb,
                                               float* __restrict__ x0, u16* __restrict__ xh,
                                               const int* flagp) {
    int bf = *flagp;
    int i = blockIdx.x * 256 + threadIdx.x;
    if (i < NELEM) {
        int n = i >> 7, f = i & 127;
        float v = ldf(emb, z[n] * H + f, bf);
        x0[i] = v;
        xh[i] = bf16r(v);
    }
}

__global__ __launch_bounds__(256) void k_store(const float* __restrict__ x, void* out,
                                               const int* flagp) {
    int bf = *flagp;
    int i = blockIdx.x * 256 + threadIdx.x;
    if (i < NELEM) {
        float v = x[i];
        if (bf) ((u16*)out)[i] = bf16r(v);
        else    ((float*)out)[i] = v;
    }
}

// ---- bf16 LDS weight staging for MFMA: row stride 136 u16 (68 u32) ----
__device__ __forceinline__ void stage_w16(const void* W, int woff, int wstride,
                                          u16* sW, int tid, int nthr, int bf) {
    u32* sW32 = (u32*)sW;
    if (bf) {
        const u32* W32 = (const u32*)W;
        for (int i = tid; i < 128 * 64; i += nthr) {
            int f2 = i >> 6, kk = i & 63;
            sW32[f2 * 68 + kk] = W32[((woff + f2 * wstride) >> 1) + kk];
        }
    } else {
        const float2* Wf = (const float2*)W;
        for (int i = tid; i < 128 * 64; i += nthr) {
            int f2 = i >> 6, kk = i & 63;
            float2 v = Wf[((woff + f2 * wstride) >> 1) + kk];
            sW32[f2 * 68 + kk] = (u32)bf16r(v.x) | ((u32)bf16r(v.y) << 16);
        }
    }
}

// ---- MFMA node GEMM (proven r16). mode 0: hb = bf16(in @ W2.T)
//      mode 1: x += silu(in @ W2.T + b2) @ Wl.T + bl
__global__ __launch_bounds__(256) void k_mfma_lin(const float* __restrict__ in,
                                                  const void* W2, int w2off,
                                                  const void* B2, int b2off,
                                                  const void* Wl, int wloff,
                                                  const void* Bl, int bloff,
                                                  float* __restrict__ x,
                                                  u16* __restrict__ hb,
                                                  int mode, const int* flagp) {
    __shared__ u16 sW2[128 * 136];
    __shared__ u16 sWl[128 * 136];
    __shared__ u16 sA[4][16 * 136];
    __shared__ float sB2v[128], sBlv[128];
    int tid = threadIdx.x;
    int bf = *flagp;
    stage_w16(W2, w2off, H, sW2, tid, 256, bf);
    if (mode == 1) stage_w16(Wl, wloff, H, sWl, tid, 256, bf);
    if (tid < 128) {
        sB2v[tid] = B2 ? ldf(B2, b2off + tid, bf) : 0.f;
        sBlv[tid] = (mode == 1) ? ldf(Bl, bloff + tid, bf) : 0.f;
    }
    __syncthreads();
    int w = tid >> 6, lane = tid & 63;
    int quad = lane >> 4, l16 = lane & 15;
    u16* myA = sA[w];
    u32* myA32 = (u32*)myA;
    for (int tile = blockIdx.x * 4 + w; tile < NATOMS / 16; tile += gridDim.x * 4) {
        int abase = tile * 16;
        const float2* in2 = (const float2*)in + (size_t)abase * 64;
        #pragma unroll 4
        for (int j = 0; j < 16; ++j) {
            float2 v = in2[j * 64 + lane];
            myA32[j * 68 + lane] = (u32)bf16r(v.x) | ((u32)bf16r(v.y) << 16);
        }
        __asm__ volatile("s_waitcnt lgkmcnt(0)" ::: "memory");
        short8 af0 = *(const short8*)&myA[l16 * 136 +   0 + quad * 8];
        short8 af1 = *(const short8*)&myA[l16 * 136 +  32 + quad * 8];
        short8 af2 = *(const short8*)&myA[l16 * 136 +  64 + quad * 8];
        short8 af3 = *(const short8*)&myA[l16 * 136 +  96 + quad * 8];
        #pragma unroll 1
        for (int nt = 0; nt < 8; ++nt) {
            const u16* wrow = &sW2[(nt * 16 + l16) * 136];
            short8 b0 = *(const short8*)&wrow[0  + quad * 8];
            short8 b1 = *(const short8*)&wrow[32 + quad * 8];
            short8 b2 = *(const short8*)&wrow[64 + quad * 8];
            short8 b3 = *(const short8*)&wrow[96 + quad * 8];
            float4v acc = {0.f, 0.f, 0.f, 0.f};
            acc = __builtin_amdgcn_mfma_f32_16x16x32_bf16(af0, b0, acc, 0, 0, 0);
            acc = __builtin_amdgcn_mfma_f32_16x16x32_bf16(af1, b1, acc, 0, 0, 0);
            acc = __builtin_amdgcn_mfma_f32_16x16x32_bf16(af2, b2, acc, 0, 0, 0);
            acc = __builtin_amdgcn_mfma_f32_16x16x32_bf16(af3, b3, acc, 0, 0, 0);
            int col = nt * 16 + l16;
            float bias = sB2v[col];
            if (mode == 0) {
                hb[(size_t)(abase + quad * 4 + 0) * H + col] = bf16r(acc[0] + bias);
                hb[(size_t)(abase + quad * 4 + 1) * H + col] = bf16r(acc[1] + bias);
                hb[(size_t)(abase + quad * 4 + 2) * H + col] = bf16r(acc[2] + bias);
                hb[(size_t)(abase + quad * 4 + 3) * H + col] = bf16r(acc[3] + bias);
            } else {
                myA[(quad * 4 + 0) * 136 + col] = bf16r(silu_f(acc[0] + bias));
                myA[(quad * 4 + 1) * 136 + col] = bf16r(silu_f(acc[1] + bias));
                myA[(quad * 4 + 2) * 136 + col] = bf16r(silu_f(acc[2] + bias));
                myA[(quad * 4 + 3) * 136 + col] = bf16r(silu_f(acc[3] + bias));
            }
        }
        if (mode == 1) {
            __asm__ volatile("s_waitcnt lgkmcnt(0)" ::: "memory");
            short8 t0 = *(const short8*)&myA[l16 * 136 +   0 + quad * 8];
            short8 t1 = *(const short8*)&myA[l16 * 136 +  32 + quad * 8];
            short8 t2 = *(const short8*)&myA[l16 * 136 +  64 + quad * 8];
            short8 t3 = *(const short8*)&myA[l16 * 136 +  96 + quad * 8];
            #pragma unroll 1
            for (int nt = 0; nt < 8; ++nt) {
                const u16* wrow = &sWl[(nt * 16 + l16) * 136];
                short8 b0 = *(const short8*)&wrow[0  + quad * 8];
                short8 b1 = *(const short8*)&wrow[32 + quad * 8];
                short8 b2 = *(const short8*)&wrow[64 + quad * 8];
                short8 b3 = *(const short8*)&wrow[96 + quad * 8];
                int col = nt * 16 + l16;
                float bias = sBlv[col];
                float4v acc;
                acc[0] = x[(size_t)(abase + quad * 4 + 0) * H + col] + bias;
                acc[1] = x[(size_t)(abase + quad * 4 + 1) * H + col] + bias;
                acc[2] = x[(size_t)(abase + quad * 4 + 2) * H + col] + bias;
                acc[3] = x[(size_t)(abase + quad * 4 + 3) * H + col] + bias;
                acc = __builtin_amdgcn_mfma_f32_16x16x32_bf16(t0, b0, acc, 0, 0, 0);
                acc = __builtin_amdgcn_mfma_f32_16x16x32_bf16(t1, b1, acc, 0, 0, 0);
                acc = __builtin_amdgcn_mfma_f32_16x16x32_bf16(t2, b2, acc, 0, 0, 0);
                acc = __builtin_amdgcn_mfma_f32_16x16x32_bf16(t3, b3, acc, 0, 0, 0);
                x[(size_t)(abase + quad * 4 + 0) * H + col] = acc[0];
                x[(size_t)(abase + quad * 4 + 1) * H + col] = acc[1];
                x[(size_t)(abase + quad * 4 + 2) * H + col] = acc[2];
                x[(size_t)(abase + quad * 4 + 3) * H + col] = acc[3];
            }
        }
    }
}

// ---- MFMA NE combine: x = x0 @ Wa.T + agg @ Wb.T + b  (mfma_lin structure) ----
__global__ __launch_bounds__(256) void k_mfma_comb(const float* __restrict__ in0,
                                                   const float* __restrict__ in1,
                                                   const void* W, const void* B,
                                                   float* __restrict__ x,
                                                   const int* flagp) {
    __shared__ u16 sWa[128 * 136];
    __shared__ u16 sWb[128 * 136];
    __shared__ u16 sA[4][16 * 136];
    __shared__ float sBv[128];
    int tid = threadIdx.x;
    int bf = *flagp;
    stage_w16(W, 0,   256, sWa, tid, 256, bf);   // cols 0..127 of [128][256]
    stage_w16(W, 128, 256, sWb, tid, 256, bf);   // cols 128..255
    if (tid < 128) sBv[tid] = ldf(B, tid, bf);
    __syncthreads();
    int w = tid >> 6, lane = tid & 63;
    int quad = lane >> 4, l16 = lane & 15;
    u16* myA = sA[w];
    u32* myA32 = (u32*)myA;
    for (int tile = blockIdx.x * 4 + w; tile < NATOMS / 16; tile += gridDim.x * 4) {
        int abase = tile * 16;
        const float2* i0 = (const float2*)in0 + (size_t)abase * 64;
        const float2* i1 = (const float2*)in1 + (size_t)abase * 64;
        #pragma unroll 4
        for (int j = 0; j < 16; ++j) {
            float2 v = i0[j * 64 + lane];
            myA32[j * 68 + lane] = (u32)bf16r(v.x) | ((u32)bf16r(v.y) << 16);
        }
        __asm__ volatile("s_waitcnt lgkmcnt(0)" ::: "memory");
        short8 af0 = *(const short8*)&myA[l16 * 136 +   0 + quad * 8];
        short8 af1 = *(const short8*)&myA[l16 * 136 +  32 + quad * 8];
        short8 af2 = *(const short8*)&myA[l16 * 136 +  64 + quad * 8];
        short8 af3 = *(const short8*)&myA[l16 * 136 +  96 + quad * 8];
        #pragma unroll 4
        for (int j = 0; j < 16; ++j) {
            float2 v = i1[j * 64 + lane];
            myA32[j * 68 + lane] = (u32)bf16r(v.x) | ((u32)bf16r(v.y) << 16);
        }
        __asm__ volatile("s_waitcnt lgkmcnt(0)" ::: "memory");
        short8 ag0 = *(const short8*)&myA[l16 * 136 +   0 + quad * 8];
        short8 ag1 = *(const short8*)&myA[l16 * 136 +  32 + quad * 8];
        short8 ag2 = *(const short8*)&myA[l16 * 136 +  64 + quad * 8];
        short8 ag3 = *(const short8*)&myA[l16 * 136 +  96 + quad * 8];
        #pragma unroll 1
        for (int nt = 0; nt < 8; ++nt) {
            const u16* wra = &sWa[(nt * 16 + l16) * 136];
            const u16* wrb = &sWb[(nt * 16 + l16) * 136];
            int col = nt * 16 + l16;
            float bias = sBv[col];
            float4v acc = {bias, bias, bias, bias};
            acc = __builtin_amdgcn_mfma_f32_16x16x32_bf16(af0, *(const short8*)&wra[0  + quad * 8], acc, 0, 0, 0);
            acc = __builtin_amdgcn_mfma_f32_16x16x32_bf16(af1, *(const short8*)&wra[32 + quad * 8], acc, 0, 0, 0);
            acc = __builtin_amdgcn_mfma_f32_16x16x32_bf16(af2, *(const short8*)&wra[64 + quad * 8], acc, 0, 0, 0);
            acc = __builtin_amdgcn_mfma_f32_16x16x32_bf16(af3, *(const short8*)&wra[96 + quad * 8], acc, 0, 0, 0);
            acc = __builtin_amdgcn_mfma_f32_16x16x32_bf16(ag0, *(const short8*)&wrb[0  + quad * 8], acc, 0, 0, 0);
            acc = __builtin_amdgcn_mfma_f32_16x16x32_bf16(ag1, *(const short8*)&wrb[32 + quad * 8], acc, 0, 0, 0);
            acc = __builtin_amdgcn_mfma_f32_16x16x32_bf16(ag2, *(const short8*)&wrb[64 + quad * 8], acc, 0, 0, 0);
            acc = __builtin_amdgcn_mfma_f32_16x16x32_bf16(ag3, *(const short8*)&wrb[96 + quad * 8], acc, 0, 0, 0);
            x[(size_t)(abase + quad * 4 + 0) * H + col] = acc[0];
            x[(size_t)(abase + quad * 4 + 1) * H + col] = acc[1];
            x[(size_t)(abase + quad * 4 + 2) * H + col] = acc[2];
            x[(size_t)(abase + quad * 4 + 3) * H + col] = acc[3];
        }
    }
}

// ---- FUSED filter table: VALU silu-RBF rows (proven) + MFMA w1 GEMM (r16 pattern).
// Also zeroes buf1 (consumer launches after). 1024 thr, grid NT/16 = 256.
__global__ __launch_bounds__(1024) void k_filter_table(const void* means, const void* betas,
                                                       const void* W0, int w0off,
                                                       const void* B0, int b0off,
                                                       const void* W1, int w1off,
                                                       const void* B1, int b1off,
                                                       u16* __restrict__ T,
                                                       float* __restrict__ zbuf,
                                                       const int* flagp) {
    __shared__ float sW0[H * 53];
    __shared__ u16 sW1b[128 * 136];
    __shared__ u16 sA16[16 * 136];
    __shared__ float sR[16][56];
    __shared__ float sM[NRBF], sBe[NRBF], sB1v[128], sC[16];
    int tid = threadIdx.x;
    int bf = *flagp;
    // zero the scatter accumulator (grid-stride)
    {
        float4* z4 = (float4*)zbuf;
        for (int i = blockIdx.x * 1024 + tid; i < NELEM / 4; i += gridDim.x * 1024)
            z4[i] = make_float4(0.f, 0.f, 0.f, 0.f);
    }
    stage_w16(W1, w1off, H, sW1b, tid, 1024, bf);
    for (int i = tid; i < H * NRBF; i += 1024) {
        int f2 = i / NRBF, k = i - f2 * NRBF;
        sW0[f2 * 53 + k] = ldf(W0, w0off + i, bf);
    }
    if (tid < NRBF) { sM[tid] = ldf(means, tid, bf); sBe[tid] = ldf(betas, tid, bf); }
    if (tid < 128) sB1v[tid] = ldf(B1, b1off + tid, bf);
    __syncthreads();
    int g = tid >> 7, f = tid & 127;
    float b0r = ldf(B0, b0off + f, bf);
    int base = blockIdx.x * 16;
    int n0 = base + 2 * g, n1 = n0 + 1;
    float wv0 = (float)n0 * (5.0f / (NT - 1));
    float wv1 = (float)n1 * (5.0f / (NT - 1));
    if (f < NRBF) {
        float t = expf(-wv0) - sM[f];
        sR[2 * g][f] = expf(-sBe[f] * t * t);
    } else if (f >= 64 && f < 64 + NRBF) {
        float t = expf(-wv1) - sM[f - 64];
        sR[2 * g + 1][f - 64] = expf(-sBe[f - 64] * t * t);
    }
    __syncthreads();
    float c0 = 0.5f * (cosf(wv0 * 0.62831853071795864f) + 1.f); if (!(wv0 < 5.f)) c0 = 0.f;
    float c1 = 0.5f * (cosf(wv1 * 0.62831853071795864f) + 1.f); if (!(wv1 < 5.f)) c1 = 0.f;
    if (f == 0) { sC[2 * g] = c0; sC[2 * g + 1] = c1; }
    float s0 = 0.f, s1 = 0.f;
    #pragma unroll
    for (int k = 0; k < NRBF; ++k) {
        float wk = sW0[f * 53 + k];
        s0 = fmaf(wk, sR[2 * g][k], s0);
        s1 = fmaf(wk, sR[2 * g + 1][k], s1);
    }
    sA16[(2 * g) * 136 + f]     = bf16r(silu_f(fmaf(c0, s0, b0r)));
    sA16[(2 * g + 1) * 136 + f] = bf16r(silu_f(fmaf(c1, s1, b0r)));
    __syncthreads();
    // phase B: waves 0..7 each compute one 16-col tile via MFMA (r16-proven layout)
    int w = tid >> 6;
    if (w < 8) {
        int lane = tid & 63;
        int quad = lane >> 4, l16 = lane & 15;
        short8 a0 = *(const short8*)&sA16[l16 * 136 +   0 + quad * 8];
        short8 a1 = *(const short8*)&sA16[l16 * 136 +  32 + quad * 8];
        short8 a2 = *(const short8*)&sA16[l16 * 136 +  64 + quad * 8];
        short8 a3 = *(const short8*)&sA16[l16 * 136 +  96 + quad * 8];
        const u16* wrow = &sW1b[(w * 16 + l16) * 136];
        short8 b0 = *(const short8*)&wrow[0  + quad * 8];
        short8 b1 = *(const short8*)&wrow[32 + quad * 8];
        short8 b2 = *(const short8*)&wrow[64 + quad * 8];
        short8 b3 = *(const short8*)&wrow[96 + quad * 8];
        float4v acc = {0.f, 0.f, 0.f, 0.f};
        acc = __builtin_amdgcn_mfma_f32_16x16x32_bf16(a0, b0, acc, 0, 0, 0);
        acc = __builtin_amdgcn_mfma_f32_16x16x32_bf16(a1, b1, acc, 0, 0, 0);
        acc = __builtin_amdgcn_mfma_f32_16x16x32_bf16(a2, b2, acc, 0, 0, 0);
        acc = __builtin_amdgcn_mfma_f32_16x16x32_bf16(a3, b3, acc, 0, 0, 0);
        int col = w * 16 + l16;
        float bias = sB1v[col];
        #pragma unroll
        for (int r = 0; r < 4; ++r) {
            int row = quad * 4 + r;
            T[(size_t)(base + row) * H + col] = bf16r((acc[r] + bias) * sC[row]);
        }
    }
}

// ---- NE w-table build (proven r12), bf16 out; also zeroes buf1 ----
__global__ __launch_bounds__(256) void k_build_table2(const void* means, const void* betas,
                                                      const void* W, int woff,
                                                      const void* B, int boff,
                                                      u16* __restrict__ T,
                                                      float* __restrict__ zbuf,
                                                      const int* flagp) {
    __shared__ float sW[H * 53];
    __shared__ float sM[NRBF], sBe[NRBF];
    __shared__ float sR[2][56];
    int tid = threadIdx.x;
    int bf = *flagp;
    {
        float4* z4 = (float4*)zbuf;
        for (int i = blockIdx.x * 256 + tid; i < NELEM / 4; i += gridDim.x * 256)
            z4[i] = make_float4(0.f, 0.f, 0.f, 0.f);
    }
    for (int i = tid; i < H * NRBF; i += 256) {
        int f2 = i / NRBF, k = i - f2 * NRBF;
        sW[f2 * 53 + k] = ldf(W, woff + i, bf);
    }
    if (tid < NRBF) { sM[tid] = ldf(means, tid, bf); sBe[tid] = ldf(betas, tid, bf); }
    __syncthreads();
    int g = tid >> 7, f = tid & 127;
    float bv = ldf(B, boff + f, bf);
    int base = blockIdx.x * 16;
    #pragma unroll 1
    for (int r = 0; r < 8; ++r) {
        int row = base + g * 8 + r;
        float w = (float)row * (5.0f / (NT - 1));
        if (f < NRBF) {
            float t = expf(-w) - sM[f];
            sR[g][f] = expf(-sBe[f] * t * t);
        }
        __syncthreads();
        float acc = 0.f;
        #pragma unroll
        for (int k = 0; k < NRBF; ++k)
            acc = fmaf(sW[f * 53 + k], sR[g][k], acc);
        float c = 0.5f * (cosf(w * 0.62831853071795864f) + 1.f);
        if (!(w < 5.f)) c = 0.f;
        T[row * H + f] = bf16r((c * acc + bv) * c);
        __syncthreads();
    }
}

// ---- counting sort by src (proven) ----
__global__ __launch_bounds__(256) void k_hist(const int* __restrict__ src, int* __restrict__ deg) {
    int e = blockIdx.x * 256 + threadIdx.x;
    if (e < NEDGES) atomicAdd(&deg[src[e]], 1);
}

__global__ __launch_bounds__(1024) void k_scan(const int* __restrict__ deg, int* __restrict__ rs) {
    __shared__ int buf[1024];
    __shared__ int carry;
    int tid = threadIdx.x;
    if (tid == 0) carry = 0;
    __syncthreads();
    for (int c = 0; c < 10; ++c) {
        int i = c * 1024 + tid;
        int v = (i < NATOMS) ? deg[i] : 0;
        buf[tid] = v;
        __syncthreads();
        for (int off = 1; off < 1024; off <<= 1) {
            int t = (tid >= off) ? buf[tid - off] : 0;
            __syncthreads();
            buf[tid] += t;
            __syncthreads();
        }
        int base = carry;
        if (i < NATOMS) rs[i] = base + buf[tid] - v;
        __syncthreads();
        if (tid == 0) carry = base + buf[1023];
        __syncthreads();
    }
}

__global__ __launch_bounds__(256) void k_scatter_perm(const int* __restrict__ src,
                                                      const int* __restrict__ dst,
                                                      const void* ew,
                                                      const int* __restrict__ rs,
                                                      int* __restrict__ cnt,
                                                      int* __restrict__ srcs,
                                                      int* __restrict__ dsts,
                                                      float* __restrict__ ews,
                                                      const int* flagp) {
    int e = blockIdx.x * 256 + threadIdx.x;
    if (e < NEDGES) {
        int s = src[e];
        int p = rs[s] + atomicAdd(&cnt[s], 1);
        srcs[p] = s;
        dsts[p] = dst[e];
        ews[p] = ldf(ew, e, *flagp);
    }
}

// ---- edge apply (proven r15/r16): sorted, wave/edge, 4-edge ILP, bf16 T & h.
// r17: chunk 20, 4000 blocks (2x TLP on top of ILP).
__global__ __launch_bounds__(256) void k_edge_apply3(const int* __restrict__ srcs,
                                                     const int* __restrict__ dsts,
                                                     const float* __restrict__ ews,
                                                     const u32* __restrict__ Tb,
                                                     const u32* __restrict__ vh,
                                                     float* __restrict__ acc,
                                                     int mask_self) {
    int tid = threadIdx.x;
    int g = tid >> 6;
    int lane = tid & 63;
    int gid = blockIdx.x * 4 + g;     // 16000 groups x 20 edges
    int r0 = gid * 20;
    int cur = -1;
    float rx = 0.f, ry = 0.f;
    for (int e = r0; e < r0 + 20; e += 4) {
        int s0 = srcs[e],     d0 = dsts[e];
        int s1 = srcs[e + 1], d1 = dsts[e + 1];
        int s2 = srcs[e + 2], d2 = dsts[e + 2];
        int s3 = srcs[e + 3], d3 = dsts[e + 3];
        float u0 = ews[e]     * ((float)(NT - 1) / 5.0f);
        float u1 = ews[e + 1] * ((float)(NT - 1) / 5.0f);
        float u2 = ews[e + 2] * ((float)(NT - 1) / 5.0f);
        float u3 = ews[e + 3] * ((float)(NT - 1) / 5.0f);
        int ix0 = min((int)u0, NT - 2); float fr0 = u0 - (float)ix0;
        int ix1 = min((int)u1, NT - 2); float fr1 = u1 - (float)ix1;
        int ix2 = min((int)u2, NT - 2); float fr2 = u2 - (float)ix2;
        int ix3 = min((int)u3, NT - 2); float fr3 = u3 - (float)ix3;
        u32 ta0 = Tb[ix0 * 64 + lane], tb0 = Tb[ix0 * 64 + 64 + lane];
        u32 ta1 = Tb[ix1 * 64 + lane], tb1 = Tb[ix1 * 64 + 64 + lane];
        u32 ta2 = Tb[ix2 * 64 + lane], tb2 = Tb[ix2 * 64 + 64 + lane];
        u32 ta3 = Tb[ix3 * 64 + lane], tb3 = Tb[ix3 * 64 + 64 + lane];
        u32 h0 = vh[d0 * 64 + lane];
        u32 h1 = vh[d1 * 64 + lane];
        u32 h2 = vh[d2 * 64 + lane];
        u32 h3 = vh[d3 * 64 + lane];
        float vx0 = fmaf(fr0, bfu((u16)(tb0 & 0xffff)) - bfu((u16)(ta0 & 0xffff)), bfu((u16)(ta0 & 0xffff))) * bfu((u16)(h0 & 0xffff));
        float vy0 = fmaf(fr0, bfu((u16)(tb0 >> 16))    - bfu((u16)(ta0 >> 16)),    bfu((u16)(ta0 >> 16)))    * bfu((u16)(h0 >> 16));
        float vx1 = fmaf(fr1, bfu((u16)(tb1 & 0xffff)) - bfu((u16)(ta1 & 0xffff)), bfu((u16)(ta1 & 0xffff))) * bfu((u16)(h1 & 0xffff));
        float vy1 = fmaf(fr1, bfu((u16)(tb1 >> 16))    - bfu((u16)(ta1 >> 16)),    bfu((u16)(ta1 >> 16)))    * bfu((u16)(h1 >> 16));
        float vx2 = fmaf(fr2, bfu((u16)(tb2 & 0xffff)) - bfu((u16)(ta2 & 0xffff)), bfu((u16)(ta2 & 0xffff))) * bfu((u16)(h2 & 0xffff));
        float vy2 = fmaf(fr2, bfu((u16)(tb2 >> 16))    - bfu((u16)(ta2 >> 16)),    bfu((u16)(ta2 >> 16)))    * bfu((u16)(h2 >> 16));
        float vx3 = fmaf(fr3, bfu((u16)(tb3 & 0xffff)) - bfu((u16)(ta3 & 0xffff)), bfu((u16)(ta3 & 0xffff))) * bfu((u16)(h3 & 0xffff));
        float vy3 = fmaf(fr3, bfu((u16)(tb3 >> 16))    - bfu((u16)(ta3 >> 16)),    bfu((u16)(ta3 >> 16)))    * bfu((u16)(h3 >> 16));
        if (!(mask_self && s0 == d0)) {
            if (s0 != cur) {
                if (cur >= 0) { atomicAdd(&acc[cur * H + 2 * lane], rx); atomicAdd(&acc[cur * H + 2 * lane + 1], ry); }
                cur = s0; rx = 0.f; ry = 0.f;
            }
            rx += vx0; ry += vy0;
        }
        if (!(mask_self && s1 == d1)) {
            if (s1 != cur) {
                if (cur >= 0) { atomicAdd(&acc[cur * H + 2 * lane], rx); atomicAdd(&acc[cur * H + 2 * lane + 1], ry); }
                cur = s1; rx = 0.f; ry = 0.f;
            }
            rx += vx1; ry += vy1;
        }
        if (!(mask_self && s2 == d2)) {
            if (s2 != cur) {
                if (cur >= 0) { atomicAdd(&acc[cur * H + 2 * lane], rx); atomicAdd(&acc[cur * H + 2 * lane + 1], ry); }
                cur = s2; rx = 0.f; ry = 0.f;
            }
            rx += vx2; ry += vy2;
        }
        if (!(mask_self && s3 == d3)) {
            if (s3 != cur) {
                if (cur >= 0) { atomicAdd(&acc[cur * H + 2 * lane], rx); atomicAdd(&acc[cur * H + 2 * lane + 1], ry); }
                cur = s3; rx = 0.f; ry = 0.f;
            }
            rx += vx3; ry += vy3;
        }
    }
    if (cur >= 0) {
        atomicAdd(&acc[cur * H + 2 * lane], rx);
        atomicAdd(&acc[cur * H + 2 * lane + 1], ry);
    }
}

extern "C" void kernel_launch(void* const* d_in, const int* in_sizes, int n_in,
                              void* d_out, int out_size, void* d_ws, size_t ws_size,
                              hipStream_t stream) {
    const int* z  = (const int*)d_in[0];
    const int* ei = (const int*)d_in[1];
    const void* ew        = d_in[2];
    const void* emb       = d_in[3];
    const void* means     = d_in[4];
    const void* betas     = d_in[5];
    const void* ne_proj_w = d_in[6];
    const void* ne_proj_b = d_in[7];
    const void* ne_comb_w = d_in[8];
    const void* ne_comb_b = d_in[9];
    const void* mlp_w0    = d_in[10];
    const void* mlp_b0    = d_in[11];
    const void* mlp_w1    = d_in[12];
    const void* mlp_b1    = d_in[13];
    const void* lin1_w    = d_in[14];
    const void* lin2_w    = d_in[15];
    const void* lin2_b    = d_in[16];
    const void* lin_w     = d_in[17];
    const void* lin_b     = d_in[18];

    const int* srcp = ei;
    const int* dstp = ei + NEDGES;

    float* buf0 = (float*)d_ws;            // x0
    float* buf1 = buf0 + NELEM;            // scatter accumulator
    float* x    = buf1 + NELEM;            // persistent fp32 node state
    int*   flag = (int*)(x + NELEM);
    int*   deg  = flag + 16;
    int*   cnt  = deg + 10240;
    int*   rs   = cnt + 10240;
    int*   srcs = rs + 10240;
    int*   dsts = srcs + NEDGES;
    float* ews  = (float*)(dsts + NEDGES);
    u16*   Tb   = (u16*)(ews + NEDGES);    // NT x 128 bf16 table
    u16*   hb   = Tb + NT * H;             // bf16 h / x0 mirror

    const int gElem = (NELEM + 255) / 256;
    const int gEdge = (NEDGES + 255) / 256;

    k_detect<<<1, 64, 0, stream>>>(means, flag);
    k_embed<<<gElem, 256, 0, stream>>>(z, emb, buf0, hb, flag);

    // counting sort by src
    hipMemsetAsync(deg, 0, 2 * 10240 * sizeof(int), stream);
    k_hist<<<gEdge, 256, 0, stream>>>(srcp, deg);
    k_scan<<<1, 1024, 0, stream>>>(deg, rs);
    k_scatter_perm<<<gEdge, 256, 0, stream>>>(srcp, dstp, ew, rs, cnt,
                                              srcs, dsts, ews, flag);

    // NeighborEmbedding (build_table2 also zeroes buf1)
    k_build_table2<<<NT / 16, 256, 0, stream>>>(means, betas, ne_proj_w, 0,
                                                ne_proj_b, 0, Tb, buf1, flag);
    k_edge_apply3<<<4000, 256, 0, stream>>>(srcs, dsts, ews, (const u32*)Tb,
                                            (const u32*)hb, buf1, 1);
    k_mfma_comb<<<157, 256, 0, stream>>>(buf0, buf1, ne_comb_w, ne_comb_b, x, flag);

    for (int L = 0; L < 3; ++L) {
        // h = bf16(x @ l1w.T)  — MFMA
        k_mfma_lin<<<157, 256, 0, stream>>>(x, lin1_w, L * H * H, nullptr, 0,
                                            nullptr, 0, nullptr, 0, x, hb, 0, flag);
        // filter table (also zeroes buf1)
        k_filter_table<<<NT / 16, 1024, 0, stream>>>(means, betas,
                                                     mlp_w0, L * H * NRBF, mlp_b0, L * H,
                                                     mlp_w1, L * H * H,    mlp_b1, L * H,
                                                     Tb, buf1, flag);
        k_edge_apply3<<<4000, 256, 0, stream>>>(srcs, dsts, ews, (const u32*)Tb,
                                                (const u32*)hb, buf1, 0);
        // x += silu(a@l2w.T+b2)@lw.T + lb — MFMA
        k_mfma_lin<<<157, 256, 0, stream>>>(buf1, lin2_w, L * H * H, lin2_b, L * H,
                                            lin_w, L * H * H, lin_b, L * H, x, hb, 1, flag);
    }

    k_store<<<gElem, 256, 0, stream>>>(x, d_out, flag);
}

// Round 18
// 392.173 us; speedup vs baseline: 3.2996x; 1.0948x over previous
//
#include <hip/hip_runtime.h>
#include <hip/hip_bf16.h>

#define NATOMS 10000
#define NEDGES 320000
#define H 128
#define NRBF 50
#define NELEM (NATOMS * H)
#define NT 4096

typedef unsigned short u16;
typedef unsigned int u32;
typedef __attribute__((ext_vector_type(8))) short short8;
typedef __attribute__((ext_vector_type(4))) float float4v;

__device__ __forceinline__ float bfu(u16 u) { return __uint_as_float(((u32)u) << 16); }
__device__ __forceinline__ u16 bf16r(float v) {   // RNE
    u32 u = __float_as_uint(v);
    return (u16)((u + 0x7FFFu + ((u >> 16) & 1u)) >> 16);
}
__device__ __forceinline__ float ldf(const void* p, int i, int bf) {
    return bf ? bfu(((const u16*)p)[i]) : ((const float*)p)[i];
}
__device__ __forceinline__ float silu_f(float v) { return v / (1.f + __expf(-v)); }
// inline dtype detect (proven logic r3-r17): means[49]==1.0 -> bf16 word24 hi = 0x3F80
__device__ __forceinline__ int bfflag(const void* means) {
    return ((((const u32*)means)[24] >> 16) == 0x3F80u) ? 1 : 0;
}

// ---- embed: x0 fp32 + bf16 mirror; also zeroes deg/cnt (sort runs after) ----
__global__ __launch_bounds__(256) void k_embed(const int* __restrict__ z, const void* emb,
                                               const void* means,
                                               float* __restrict__ x0, u16* __restrict__ xh,
                                               int* __restrict__ degz) {
    int bf = bfflag(means);
    int i = blockIdx.x * 256 + threadIdx.x;
    if (i < 20480) degz[i] = 0;
    if (i < NELEM) {
        int n = i >> 7, f = i & 127;
        float v = ldf(emb, z[n] * H + f, bf);
        x0[i] = v;
        xh[i] = bf16r(v);
    }
}

// ---- bf16 LDS weight staging for MFMA: row stride 136 u16 (68 u32) ----
__device__ __forceinline__ void stage_w16(const void* W, int woff, int wstride,
                                          u16* sW, int tid, int nthr, int bf) {
    u32* sW32 = (u32*)sW;
    if (bf) {
        const u32* W32 = (const u32*)W;
        for (int i = tid; i < 128 * 64; i += nthr) {
            int f2 = i >> 6, kk = i & 63;
            sW32[f2 * 68 + kk] = W32[((woff + f2 * wstride) >> 1) + kk];
        }
    } else {
        const float2* Wf = (const float2*)W;
        for (int i = tid; i < 128 * 64; i += nthr) {
            int f2 = i >> 6, kk = i & 63;
            float2 v = Wf[((woff + f2 * wstride) >> 1) + kk];
            sW32[f2 * 68 + kk] = (u32)bf16r(v.x) | ((u32)bf16r(v.y) << 16);
        }
    }
}

// ---- MFMA node GEMM (proven r16/r17).
// mode 0: hb = bf16(in @ W2.T)           (lin1)
// mode 1: x += silu(in@W2.T+b2)@Wl.T+bl  (fused lin2+lin); zeroes zrw tiles after
//         staging; if outp != null also writes final output (fp32 or bf16).
__global__ __launch_bounds__(256) void k_mfma_lin(const float* in,
                                                  const void* W2, int w2off,
                                                  const void* B2, int b2off,
                                                  const void* Wl, int wloff,
                                                  const void* Bl, int bloff,
                                                  float* x, u16* __restrict__ hb,
                                                  int mode, const void* means,
                                                  float* zrw, void* outp) {
    __shared__ u16 sW2[128 * 136];
    __shared__ u16 sWl[128 * 136];
    __shared__ u16 sA[4][16 * 136];
    __shared__ float sB2v[128], sBlv[128];
    int tid = threadIdx.x;
    int bf = bfflag(means);
    stage_w16(W2, w2off, H, sW2, tid, 256, bf);
    if (mode == 1) stage_w16(Wl, wloff, H, sWl, tid, 256, bf);
    if (tid < 128) {
        sB2v[tid] = B2 ? ldf(B2, b2off + tid, bf) : 0.f;
        sBlv[tid] = (mode == 1) ? ldf(Bl, bloff + tid, bf) : 0.f;
    }
    __syncthreads();
    int w = tid >> 6, lane = tid & 63;
    int quad = lane >> 4, l16 = lane & 15;
    u16* myA = sA[w];
    u32* myA32 = (u32*)myA;
    for (int tile = blockIdx.x * 4 + w; tile < NATOMS / 16; tile += gridDim.x * 4) {
        int abase = tile * 16;
        const float2* in2 = (const float2*)in + (size_t)abase * 64;
        #pragma unroll 4
        for (int j = 0; j < 16; ++j) {
            float2 v = in2[j * 64 + lane];
            myA32[j * 68 + lane] = (u32)bf16r(v.x) | ((u32)bf16r(v.y) << 16);
        }
        __asm__ volatile("s_waitcnt lgkmcnt(0)" ::: "memory");
        if (zrw) {   // consumer-side re-zero of the scatter accumulator
            float2* z2 = (float2*)zrw + (size_t)abase * 64;
            #pragma unroll 4
            for (int j = 0; j < 16; ++j) z2[j * 64 + lane] = make_float2(0.f, 0.f);
        }
        short8 af0 = *(const short8*)&myA[l16 * 136 +   0 + quad * 8];
        short8 af1 = *(const short8*)&myA[l16 * 136 +  32 + quad * 8];
        short8 af2 = *(const short8*)&myA[l16 * 136 +  64 + quad * 8];
        short8 af3 = *(const short8*)&myA[l16 * 136 +  96 + quad * 8];
        #pragma unroll 1
        for (int nt = 0; nt < 8; ++nt) {
            const u16* wrow = &sW2[(nt * 16 + l16) * 136];
            short8 b0 = *(const short8*)&wrow[0  + quad * 8];
            short8 b1 = *(const short8*)&wrow[32 + quad * 8];
            short8 b2 = *(const short8*)&wrow[64 + quad * 8];
            short8 b3 = *(const short8*)&wrow[96 + quad * 8];
            float4v acc = {0.f, 0.f, 0.f, 0.f};
            acc = __builtin_amdgcn_mfma_f32_16x16x32_bf16(af0, b0, acc, 0, 0, 0);
            acc = __builtin_amdgcn_mfma_f32_16x16x32_bf16(af1, b1, acc, 0, 0, 0);
            acc = __builtin_amdgcn_mfma_f32_16x16x32_bf16(af2, b2, acc, 0, 0, 0);
            acc = __builtin_amdgcn_mfma_f32_16x16x32_bf16(af3, b3, acc, 0, 0, 0);
            int col = nt * 16 + l16;
            float bias = sB2v[col];
            if (mode == 0) {
                hb[(size_t)(abase + quad * 4 + 0) * H + col] = bf16r(acc[0] + bias);
                hb[(size_t)(abase + quad * 4 + 1) * H + col] = bf16r(acc[1] + bias);
                hb[(size_t)(abase + quad * 4 + 2) * H + col] = bf16r(acc[2] + bias);
                hb[(size_t)(abase + quad * 4 + 3) * H + col] = bf16r(acc[3] + bias);
            } else {
                myA[(quad * 4 + 0) * 136 + col] = bf16r(silu_f(acc[0] + bias));
                myA[(quad * 4 + 1) * 136 + col] = bf16r(silu_f(acc[1] + bias));
                myA[(quad * 4 + 2) * 136 + col] = bf16r(silu_f(acc[2] + bias));
                myA[(quad * 4 + 3) * 136 + col] = bf16r(silu_f(acc[3] + bias));
            }
        }
        if (mode == 1) {
            __asm__ volatile("s_waitcnt lgkmcnt(0)" ::: "memory");
            short8 t0 = *(const short8*)&myA[l16 * 136 +   0 + quad * 8];
            short8 t1 = *(const short8*)&myA[l16 * 136 +  32 + quad * 8];
            short8 t2 = *(const short8*)&myA[l16 * 136 +  64 + quad * 8];
            short8 t3 = *(const short8*)&myA[l16 * 136 +  96 + quad * 8];
            #pragma unroll 1
            for (int nt = 0; nt < 8; ++nt) {
                const u16* wrow = &sWl[(nt * 16 + l16) * 136];
                short8 b0 = *(const short8*)&wrow[0  + quad * 8];
                short8 b1 = *(const short8*)&wrow[32 + quad * 8];
                short8 b2 = *(const short8*)&wrow[64 + quad * 8];
                short8 b3 = *(const short8*)&wrow[96 + quad * 8];
                int col = nt * 16 + l16;
                float bias = sBlv[col];
                float4v acc;
                acc[0] = x[(size_t)(abase + quad * 4 + 0) * H + col] + bias;
                acc[1] = x[(size_t)(abase + quad * 4 + 1) * H + col] + bias;
                acc[2] = x[(size_t)(abase + quad * 4 + 2) * H + col] + bias;
                acc[3] = x[(size_t)(abase + quad * 4 + 3) * H + col] + bias;
                acc = __builtin_amdgcn_mfma_f32_16x16x32_bf16(t0, b0, acc, 0, 0, 0);
                acc = __builtin_amdgcn_mfma_f32_16x16x32_bf16(t1, b1, acc, 0, 0, 0);
                acc = __builtin_amdgcn_mfma_f32_16x16x32_bf16(t2, b2, acc, 0, 0, 0);
                acc = __builtin_amdgcn_mfma_f32_16x16x32_bf16(t3, b3, acc, 0, 0, 0);
                #pragma unroll
                for (int r = 0; r < 4; ++r) {
                    size_t idx = (size_t)(abase + quad * 4 + r) * H + col;
                    x[idx] = acc[r];
                    if (outp) {
                        if (bf) ((u16*)outp)[idx] = bf16r(acc[r]);
                        else    ((float*)outp)[idx] = acc[r];
                    }
                }
            }
        }
    }
}

// ---- MFMA NE combine (proven r17); zeroes buf1 tiles after staging ----
__global__ __launch_bounds__(256) void k_mfma_comb(const float* in0, float* in1,
                                                   const void* W, const void* B,
                                                   float* x, const void* means) {
    __shared__ u16 sWa[128 * 136];
    __shared__ u16 sWb[128 * 136];
    __shared__ u16 sA[4][16 * 136];
    __shared__ float sBv[128];
    int tid = threadIdx.x;
    int bf = bfflag(means);
    stage_w16(W, 0,   256, sWa, tid, 256, bf);
    stage_w16(W, 128, 256, sWb, tid, 256, bf);
    if (tid < 128) sBv[tid] = ldf(B, tid, bf);
    __syncthreads();
    int w = tid >> 6, lane = tid & 63;
    int quad = lane >> 4, l16 = lane & 15;
    u16* myA = sA[w];
    u32* myA32 = (u32*)myA;
    for (int tile = blockIdx.x * 4 + w; tile < NATOMS / 16; tile += gridDim.x * 4) {
        int abase = tile * 16;
        const float2* i0 = (const float2*)in0 + (size_t)abase * 64;
        const float2* i1 = (const float2*)in1 + (size_t)abase * 64;
        #pragma unroll 4
        for (int j = 0; j < 16; ++j) {
            float2 v = i0[j * 64 + lane];
            myA32[j * 68 + lane] = (u32)bf16r(v.x) | ((u32)bf16r(v.y) << 16);
        }
        __asm__ volatile("s_waitcnt lgkmcnt(0)" ::: "memory");
        short8 af0 = *(const short8*)&myA[l16 * 136 +   0 + quad * 8];
        short8 af1 = *(const short8*)&myA[l16 * 136 +  32 + quad * 8];
        short8 af2 = *(const short8*)&myA[l16 * 136 +  64 + quad * 8];
        short8 af3 = *(const short8*)&myA[l16 * 136 +  96 + quad * 8];
        #pragma unroll 4
        for (int j = 0; j < 16; ++j) {
            float2 v = i1[j * 64 + lane];
            myA32[j * 68 + lane] = (u32)bf16r(v.x) | ((u32)bf16r(v.y) << 16);
        }
        __asm__ volatile("s_waitcnt lgkmcnt(0)" ::: "memory");
        {   // consumer-side zero of buf1 for the next edge pass
            float2* z2 = (float2*)in1 + (size_t)abase * 64;
            #pragma unroll 4
            for (int j = 0; j < 16; ++j) z2[j * 64 + lane] = make_float2(0.f, 0.f);
        }
        short8 ag0 = *(const short8*)&myA[l16 * 136 +   0 + quad * 8];
        short8 ag1 = *(const short8*)&myA[l16 * 136 +  32 + quad * 8];
        short8 ag2 = *(const short8*)&myA[l16 * 136 +  64 + quad * 8];
        short8 ag3 = *(const short8*)&myA[l16 * 136 +  96 + quad * 8];
        #pragma unroll 1
        for (int nt = 0; nt < 8; ++nt) {
            const u16* wra = &sWa[(nt * 16 + l16) * 136];
            const u16* wrb = &sWb[(nt * 16 + l16) * 136];
            int col = nt * 16 + l16;
            float bias = sBv[col];
            float4v acc = {bias, bias, bias, bias};
            acc = __builtin_amdgcn_mfma_f32_16x16x32_bf16(af0, *(const short8*)&wra[0  + quad * 8], acc, 0, 0, 0);
            acc = __builtin_amdgcn_mfma_f32_16x16x32_bf16(af1, *(const short8*)&wra[32 + quad * 8], acc, 0, 0, 0);
            acc = __builtin_amdgcn_mfma_f32_16x16x32_bf16(af2, *(const short8*)&wra[64 + quad * 8], acc, 0, 0, 0);
            acc = __builtin_amdgcn_mfma_f32_16x16x32_bf16(af3, *(const short8*)&wra[96 + quad * 8], acc, 0, 0, 0);
            acc = __builtin_amdgcn_mfma_f32_16x16x32_bf16(ag0, *(const short8*)&wrb[0  + quad * 8], acc, 0, 0, 0);
            acc = __builtin_amdgcn_mfma_f32_16x16x32_bf16(ag1, *(const short8*)&wrb[32 + quad * 8], acc, 0, 0, 0);
            acc = __builtin_amdgcn_mfma_f32_16x16x32_bf16(ag2, *(const short8*)&wrb[64 + quad * 8], acc, 0, 0, 0);
            acc = __builtin_amdgcn_mfma_f32_16x16x32_bf16(ag3, *(const short8*)&wrb[96 + quad * 8], acc, 0, 0, 0);
            x[(size_t)(abase + quad * 4 + 0) * H + col] = acc[0];
            x[(size_t)(abase + quad * 4 + 1) * H + col] = acc[1];
            x[(size_t)(abase + quad * 4 + 2) * H + col] = acc[2];
            x[(size_t)(abase + quad * 4 + 3) * H + col] = acc[3];
        }
    }
}

// ---- all 3 filter tables in one launch (r17 structure, table = blockIdx>>8) ----
__global__ __launch_bounds__(1024) void k_ft3(const void* means, const void* betas,
                                              const void* W0s, const void* B0s,
                                              const void* W1s, const void* B1s,
                                              u16* __restrict__ ftT) {
    __shared__ float sW0[H * 53];
    __shared__ u16 sW1b[128 * 136];
    __shared__ u16 sA16[16 * 136];
    __shared__ float sR[16][56];
    __shared__ float sM[NRBF], sBe[NRBF], sB1v[128], sC[16];
    int tid = threadIdx.x;
    int bf = bfflag(means);
    int t = blockIdx.x >> 8;                 // layer 0..2
    int bb = blockIdx.x & 255;
    int w0off = t * H * NRBF, b0off = t * H, w1off = t * H * H, b1off = t * H;
    u16* T = ftT + (size_t)t * NT * H;
    stage_w16(W1s, w1off, H, sW1b, tid, 1024, bf);
    for (int i = tid; i < H * NRBF; i += 1024) {
        int f2 = i / NRBF, k = i - f2 * NRBF;
        sW0[f2 * 53 + k] = ldf(W0s, w0off + i, bf);
    }
    if (tid < NRBF) { sM[tid] = ldf(means, tid, bf); sBe[tid] = ldf(betas, tid, bf); }
    if (tid < 128) sB1v[tid] = ldf(B1s, b1off + tid, bf);
    __syncthreads();
    int g = tid >> 7, f = tid & 127;
    float b0r = ldf(B0s, b0off + f, bf);
    int base = bb * 16;
    int n0 = base + 2 * g, n1 = n0 + 1;
    float wv0 = (float)n0 * (5.0f / (NT - 1));
    float wv1 = (float)n1 * (5.0f / (NT - 1));
    if (f < NRBF) {
        float tt = expf(-wv0) - sM[f];
        sR[2 * g][f] = expf(-sBe[f] * tt * tt);
    } else if (f >= 64 && f < 64 + NRBF) {
        float tt = expf(-wv1) - sM[f - 64];
        sR[2 * g + 1][f - 64] = expf(-sBe[f - 64] * tt * tt);
    }
    __syncthreads();
    float c0 = 0.5f * (cosf(wv0 * 0.62831853071795864f) + 1.f); if (!(wv0 < 5.f)) c0 = 0.f;
    float c1 = 0.5f * (cosf(wv1 * 0.62831853071795864f) + 1.f); if (!(wv1 < 5.f)) c1 = 0.f;
    if (f == 0) { sC[2 * g] = c0; sC[2 * g + 1] = c1; }
    float s0 = 0.f, s1 = 0.f;
    #pragma unroll
    for (int k = 0; k < NRBF; ++k) {
        float wk = sW0[f * 53 + k];
        s0 = fmaf(wk, sR[2 * g][k], s0);
        s1 = fmaf(wk, sR[2 * g + 1][k], s1);
    }
    sA16[(2 * g) * 136 + f]     = bf16r(silu_f(fmaf(c0, s0, b0r)));
    sA16[(2 * g + 1) * 136 + f] = bf16r(silu_f(fmaf(c1, s1, b0r)));
    __syncthreads();
    int w = tid >> 6;
    if (w < 8) {
        int lane = tid & 63;
        int quad = lane >> 4, l16 = lane & 15;
        short8 a0 = *(const short8*)&sA16[l16 * 136 +   0 + quad * 8];
        short8 a1 = *(const short8*)&sA16[l16 * 136 +  32 + quad * 8];
        short8 a2 = *(const short8*)&sA16[l16 * 136 +  64 + quad * 8];
        short8 a3 = *(const short8*)&sA16[l16 * 136 +  96 + quad * 8];
        const u16* wrow = &sW1b[(w * 16 + l16) * 136];
        short8 b0 = *(const short8*)&wrow[0  + quad * 8];
        short8 b1 = *(const short8*)&wrow[32 + quad * 8];
        short8 b2 = *(const short8*)&wrow[64 + quad * 8];
        short8 b3 = *(const short8*)&wrow[96 + quad * 8];
        float4v acc = {0.f, 0.f, 0.f, 0.f};
        acc = __builtin_amdgcn_mfma_f32_16x16x32_bf16(a0, b0, acc, 0, 0, 0);
        acc = __builtin_amdgcn_mfma_f32_16x16x32_bf16(a1, b1, acc, 0, 0, 0);
        acc = __builtin_amdgcn_mfma_f32_16x16x32_bf16(a2, b2, acc, 0, 0, 0);
        acc = __builtin_amdgcn_mfma_f32_16x16x32_bf16(a3, b3, acc, 0, 0, 0);
        int col = w * 16 + l16;
        float bias = sB1v[col];
        #pragma unroll
        for (int r = 0; r < 4; ++r) {
            int row = quad * 4 + r;
            T[(size_t)(base + row) * H + col] = bf16r((acc[r] + bias) * sC[row]);
        }
    }
}

// ---- NE w-table build (proven r12), bf16 out; zeroes buf1 ----
__global__ __launch_bounds__(256) void k_build_table2(const void* means, const void* betas,
                                                      const void* W, const void* B,
                                                      u16* __restrict__ T,
                                                      float* __restrict__ zbuf) {
    __shared__ float sW[H * 53];
    __shared__ float sM[NRBF], sBe[NRBF];
    __shared__ float sR[2][56];
    int tid = threadIdx.x;
    int bf = bfflag(means);
    {
        float4* z4 = (float4*)zbuf;
        for (int i = blockIdx.x * 256 + tid; i < NELEM / 4; i += gridDim.x * 256)
            z4[i] = make_float4(0.f, 0.f, 0.f, 0.f);
    }
    for (int i = tid; i < H * NRBF; i += 256) {
        int f2 = i / NRBF, k = i - f2 * NRBF;
        sW[f2 * 53 + k] = ldf(W, i, bf);
    }
    if (tid < NRBF) { sM[tid] = ldf(means, tid, bf); sBe[tid] = ldf(betas, tid, bf); }
    __syncthreads();
    int g = tid >> 7, f = tid & 127;
    float bv = ldf(B, f, bf);
    int base = blockIdx.x * 16;
    #pragma unroll 1
    for (int r = 0; r < 8; ++r) {
        int row = base + g * 8 + r;
        float w = (float)row * (5.0f / (NT - 1));
        if (f < NRBF) {
            float t = expf(-w) - sM[f];
            sR[g][f] = expf(-sBe[f] * t * t);
        }
        __syncthreads();
        float acc = 0.f;
        #pragma unroll
        for (int k = 0; k < NRBF; ++k)
            acc = fmaf(sW[f * 53 + k], sR[g][k], acc);
        float c = 0.5f * (cosf(w * 0.62831853071795864f) + 1.f);
        if (!(w < 5.f)) c = 0.f;
        T[row * H + f] = bf16r((c * acc + bv) * c);
        __syncthreads();
    }
}

// ---- counting sort by src (proven) ----
__global__ __launch_bounds__(256) void k_hist(const int* __restrict__ src, int* __restrict__ deg) {
    int e = blockIdx.x * 256 + threadIdx.x;
    if (e < NEDGES) atomicAdd(&deg[src[e]], 1);
}

__global__ __launch_bounds__(1024) void k_scan(const int* __restrict__ deg, int* __restrict__ rs) {
    __shared__ int buf[1024];
    __shared__ int carry;
    int tid = threadIdx.x;
    if (tid == 0) carry = 0;
    __syncthreads();
    for (int c = 0; c < 10; ++c) {
        int i = c * 1024 + tid;
        int v = (i < NATOMS) ? deg[i] : 0;
        buf[tid] = v;
        __syncthreads();
        for (int off = 1; off < 1024; off <<= 1) {
            int t = (tid >= off) ? buf[tid - off] : 0;
            __syncthreads();
            buf[tid] += t;
            __syncthreads();
        }
        int base = carry;
        if (i < NATOMS) rs[i] = base + buf[tid] - v;
        __syncthreads();
        if (tid == 0) carry = base + buf[1023];
        __syncthreads();
    }
}

__global__ __launch_bounds__(256) void k_scatter_perm(const int* __restrict__ src,
                                                      const int* __restrict__ dst,
                                                      const void* ew, const void* means,
                                                      const int* __restrict__ rs,
                                                      int* __restrict__ cnt,
                                                      int* __restrict__ srcs,
                                                      int* __restrict__ dsts,
                                                      float* __restrict__ ews) {
    int bf = bfflag(means);
    int e = blockIdx.x * 256 + threadIdx.x;
    if (e < NEDGES) {
        int s = src[e];
        int p = rs[s] + atomicAdd(&cnt[s], 1);
        srcs[p] = s;
        dsts[p] = dst[e];
        ews[p] = ldf(ew, e, bf);
    }
}

// ---- edge apply: sorted, wave/edge, 8-EDGE ILP, bf16 T & h (r18).
// chunk 40, 2000 blocks x 4 waves. Named scalars via macros — no arrays, no LDS.
#define ELOAD(i) \
    int s##i = srcs[e + i], d##i = dsts[e + i]; \
    float u##i = ews[e + i] * ((float)(NT - 1) / 5.0f); \
    int ix##i = min((int)u##i, NT - 2); float fr##i = u##i - (float)ix##i; \
    u32 ta##i = Tb[ix##i * 64 + lane], tb##i = Tb[ix##i * 64 + 64 + lane]; \
    u32 h##i = vh[d##i * 64 + lane];
#define EVAL(i) \
    float vx##i = fmaf(fr##i, bfu((u16)(tb##i & 0xffff)) - bfu((u16)(ta##i & 0xffff)), bfu((u16)(ta##i & 0xffff))) * bfu((u16)(h##i & 0xffff)); \
    float vy##i = fmaf(fr##i, bfu((u16)(tb##i >> 16))    - bfu((u16)(ta##i >> 16)),    bfu((u16)(ta##i >> 16)))    * bfu((u16)(h##i >> 16));
#define EACC(i) \
    if (!(mask_self && s##i == d##i)) { \
        if (s##i != cur) { \
            if (cur >= 0) { atomicAdd(&acc[cur * H + 2 * lane], rx); atomicAdd(&acc[cur * H + 2 * lane + 1], ry); } \
            cur = s##i; rx = 0.f; ry = 0.f; \
        } \
        rx += vx##i; ry += vy##i; \
    }

__global__ __launch_bounds__(256) void k_edge_apply4(const int* __restrict__ srcs,
                                                     const int* __restrict__ dsts,
                                                     const float* __restrict__ ews,
                                                     const u32* __restrict__ Tb,
                                                     const u32* __restrict__ vh,
                                                     float* __restrict__ acc,
                                                     int mask_self) {
    int tid = threadIdx.x;
    int g = tid >> 6;
    int lane = tid & 63;
    int gid = blockIdx.x * 4 + g;     // 8000 groups x 40 edges
    int r0 = gid * 40;
    int cur = -1;
    float rx = 0.f, ry = 0.f;
    for (int e = r0; e < r0 + 40; e += 8) {
        ELOAD(0) ELOAD(1) ELOAD(2) ELOAD(3) ELOAD(4) ELOAD(5) ELOAD(6) ELOAD(7)
        EVAL(0) EVAL(1) EVAL(2) EVAL(3) EVAL(4) EVAL(5) EVAL(6) EVAL(7)
        EACC(0) EACC(1) EACC(2) EACC(3) EACC(4) EACC(5) EACC(6) EACC(7)
    }
    if (cur >= 0) {
        atomicAdd(&acc[cur * H + 2 * lane], rx);
        atomicAdd(&acc[cur * H + 2 * lane + 1], ry);
    }
}

extern "C" void kernel_launch(void* const* d_in, const int* in_sizes, int n_in,
                              void* d_out, int out_size, void* d_ws, size_t ws_size,
                              hipStream_t stream) {
    const int* z  = (const int*)d_in[0];
    const int* ei = (const int*)d_in[1];
    const void* ew        = d_in[2];
    const void* emb       = d_in[3];
    const void* means     = d_in[4];
    const void* betas     = d_in[5];
    const void* ne_proj_w = d_in[6];
    const void* ne_proj_b = d_in[7];
    const void* ne_comb_w = d_in[8];
    const void* ne_comb_b = d_in[9];
    const void* mlp_w0    = d_in[10];
    const void* mlp_b0    = d_in[11];
    const void* mlp_w1    = d_in[12];
    const void* mlp_b1    = d_in[13];
    const void* lin1_w    = d_in[14];
    const void* lin2_w    = d_in[15];
    const void* lin2_b    = d_in[16];
    const void* lin_w     = d_in[17];
    const void* lin_b     = d_in[18];

    const int* srcp = ei;
    const int* dstp = ei + NEDGES;

    float* buf0 = (float*)d_ws;            // x0; after comb reused as ftT (3x1MB)
    float* buf1 = buf0 + NELEM;            // scatter accumulator
    float* x    = buf1 + NELEM;            // persistent fp32 node state
    int*   deg  = (int*)(x + NELEM);       // deg[10240] + cnt[10240]
    int*   cnt  = deg + 10240;
    int*   rs   = cnt + 10240;
    int*   srcs = rs + 10240;
    int*   dsts = srcs + NEDGES;
    float* ews  = (float*)(dsts + NEDGES);
    u16*   Tb   = (u16*)(ews + NEDGES);    // NE table, NT x 128 bf16
    u16*   hb   = Tb + NT * H;             // bf16 h / x0 mirror
    u16*   ftT  = (u16*)buf0;              // 3 filter tables (aliases x0, free post-comb)

    const int gElem = (NELEM + 255) / 256;
    const int gEdge = (NEDGES + 255) / 256;

    k_embed<<<gElem, 256, 0, stream>>>(z, emb, means, buf0, hb, deg);

    // counting sort by src
    k_hist<<<gEdge, 256, 0, stream>>>(srcp, deg);
    k_scan<<<1, 1024, 0, stream>>>(deg, rs);
    k_scatter_perm<<<gEdge, 256, 0, stream>>>(srcp, dstp, ew, means, rs, cnt,
                                              srcs, dsts, ews);

    // NeighborEmbedding (build_table2 zeroes buf1)
    k_build_table2<<<NT / 16, 256, 0, stream>>>(means, betas, ne_proj_w, ne_proj_b,
                                                Tb, buf1);
    k_edge_apply4<<<2000, 256, 0, stream>>>(srcs, dsts, ews, (const u32*)Tb,
                                            (const u32*)hb, buf1, 1);
    k_mfma_comb<<<157, 256, 0, stream>>>(buf0, buf1, ne_comb_w, ne_comb_b, x, means);

    // all 3 filter tables in one launch (into buf0 space, free after comb)
    k_ft3<<<768, 1024, 0, stream>>>(means, betas, mlp_w0, mlp_b0, mlp_w1, mlp_b1, ftT);

    for (int L = 0; L < 3; ++L) {
        // h = bf16(x @ l1w.T)
        k_mfma_lin<<<157, 256, 0, stream>>>(x, lin1_w, L * H * H, nullptr, 0,
                                            nullptr, 0, nullptr, 0, x, hb, 0, means,
                                            nullptr, nullptr);
        k_edge_apply4<<<2000, 256, 0, stream>>>(srcs, dsts, ews,
                                                (const u32*)(ftT + (size_t)L * NT * H),
                                                (const u32*)hb, buf1, 0);
        // x += silu(a@l2w.T+b2)@lw.T + lb ; zero buf1; last layer writes d_out
        k_mfma_lin<<<157, 256, 0, stream>>>(buf1, lin2_w, L * H * H, lin2_b, L * H,
                                            lin_w, L * H * H, lin_b, L * H, x, hb, 1, means,
                                            buf1, (L == 2) ? d_out : nullptr);
    }
}